// Round 1
// baseline (895.038 us; speedup 1.0000x reference)
//
#include <hip/hip_runtime.h>
#include <math.h>

#define TPB 256

// Cooperative global->LDS copy, float4 granularity. nfloats % 4 == 0,
// both pointers 16B-aligned.
__device__ __forceinline__ void cp_lds(float* dst, const float* src, int nfloats, int tid) {
  const float4* s4 = (const float4*)src;
  float4* d4 = (float4*)dst;
  const int n4 = nfloats >> 2;
  for (int i = tid; i < n4; i += TPB) d4[i] = s4[i];
}

__device__ __forceinline__ void ld4(float r[4], const float* p) {
  float4 v = *(const float4*)p;
  r[0] = v.x; r[1] = v.y; r[2] = v.z; r[3] = v.w;
}
__device__ __forceinline__ void ld2(float r[2], const float* p) {
  float2 v = *(const float2*)p;
  r[0] = v.x; r[1] = v.y;
}

// ---------------------------------------------------------------------------
// Kernel A: state encoder (h = relu(relu(s@W1+b1)@W2+b2)) -> hws,
// plus self_dyn = relu(h@sd_w1+sd_b1)@sd_w2+sd_b2 reduced over n -> out (atomic)
// One block = 32 rows (half of one b). 256 blocks.
// ---------------------------------------------------------------------------
__global__ __launch_bounds__(TPB, 3) void enc_self_kernel(
    const float* __restrict__ s_in,
    const float* __restrict__ se_w1, const float* __restrict__ se_b1,
    const float* __restrict__ se_w2, const float* __restrict__ se_b2,
    const float* __restrict__ sd_w1, const float* __restrict__ sd_b1,
    const float* __restrict__ sd_w2, const float* __restrict__ sd_b2,
    float* __restrict__ hws, float* __restrict__ out) {
  __shared__ __align__(16) float sX[2048];   // s rows -> later h rows (32x64)
  __shared__ __align__(16) float sH1[2048];  // h1 (32x64) -> later reduce scratch
  __shared__ __align__(16) float sT[4096];   // sd1 activations (32x128)
  __shared__ __align__(16) float sW[4096];   // weight stage (16KB)
  __shared__ float sb1[64], sb2[64], sdb1[128], sdb2[128];

  const int tid = threadIdx.x;
  const int lg = tid >> 5;   // 0..7 row group
  const int og = tid & 31;   // 0..31
  const int b = blockIdx.x >> 1;
  const int row0 = b * 64 + (blockIdx.x & 1) * 32;
  const int n0 = lg * 4;

  cp_lds(sX, s_in + row0 * 64, 2048, tid);
  cp_lds(sW, se_w1, 4096, tid);
  if (tid < 64) { sb1[tid] = se_b1[tid]; sb2[tid] = se_b2[tid]; }
  else if (tid < 192) { const int o = tid - 64; sdb1[o] = sd_b1[o]; sdb2[o] = sd_b2[o]; }
  __syncthreads();

  // ---- se layer 1: h1 = relu(s @ se_w1 + b1)  (32x64, tile 4n x 2o)
  float a2[4][2];
#pragma unroll
  for (int nn = 0; nn < 4; nn++) { a2[nn][0] = 0.f; a2[nn][1] = 0.f; }
  for (int kk = 0; kk < 64; kk += 4) {
    float xr[4][4], wr[4][2];
#pragma unroll
    for (int nn = 0; nn < 4; nn++) ld4(xr[nn], &sX[(n0 + nn) * 64 + kk]);
#pragma unroll
    for (int t = 0; t < 4; t++) ld2(wr[t], &sW[(kk + t) * 64 + og * 2]);
#pragma unroll
    for (int t = 0; t < 4; t++)
#pragma unroll
      for (int nn = 0; nn < 4; nn++) {
        a2[nn][0] = fmaf(xr[nn][t], wr[t][0], a2[nn][0]);
        a2[nn][1] = fmaf(xr[nn][t], wr[t][1], a2[nn][1]);
      }
  }
#pragma unroll
  for (int nn = 0; nn < 4; nn++) {
    float2 v;
    v.x = fmaxf(a2[nn][0] + sb1[og * 2 + 0], 0.f);
    v.y = fmaxf(a2[nn][1] + sb1[og * 2 + 1], 0.f);
    *(float2*)&sH1[(n0 + nn) * 64 + og * 2] = v;
  }
  __syncthreads();
  cp_lds(sW, se_w2, 4096, tid);
  __syncthreads();

  // ---- se layer 2: h = relu(h1 @ se_w2 + b2) -> sX (in place) + hws
#pragma unroll
  for (int nn = 0; nn < 4; nn++) { a2[nn][0] = 0.f; a2[nn][1] = 0.f; }
  for (int kk = 0; kk < 64; kk += 4) {
    float xr[4][4], wr[4][2];
#pragma unroll
    for (int nn = 0; nn < 4; nn++) ld4(xr[nn], &sH1[(n0 + nn) * 64 + kk]);
#pragma unroll
    for (int t = 0; t < 4; t++) ld2(wr[t], &sW[(kk + t) * 64 + og * 2]);
#pragma unroll
    for (int t = 0; t < 4; t++)
#pragma unroll
      for (int nn = 0; nn < 4; nn++) {
        a2[nn][0] = fmaf(xr[nn][t], wr[t][0], a2[nn][0]);
        a2[nn][1] = fmaf(xr[nn][t], wr[t][1], a2[nn][1]);
      }
  }
#pragma unroll
  for (int nn = 0; nn < 4; nn++) {
    float2 v;
    v.x = fmaxf(a2[nn][0] + sb2[og * 2 + 0], 0.f);
    v.y = fmaxf(a2[nn][1] + sb2[og * 2 + 1], 0.f);
    *(float2*)&sX[(n0 + nn) * 64 + og * 2] = v;
    *(float2*)&hws[(row0 + n0 + nn) * 64 + og * 2] = v;
  }
  __syncthreads();

  // ---- sd layer 1: T = relu(h @ sd_w1 + sdb1)  (32x128, tile 4n x 4o, k=64)
  float a4[4][4];
#pragma unroll
  for (int nn = 0; nn < 4; nn++)
#pragma unroll
    for (int oo = 0; oo < 4; oo++) a4[nn][oo] = 0.f;
  for (int c = 0; c < 2; c++) {
    cp_lds(sW, sd_w1 + c * 32 * 128, 4096, tid);
    __syncthreads();
    for (int kk = 0; kk < 32; kk += 4) {
      float xr[4][4], wr[4][4];
#pragma unroll
      for (int nn = 0; nn < 4; nn++) ld4(xr[nn], &sX[(n0 + nn) * 64 + c * 32 + kk]);
#pragma unroll
      for (int t = 0; t < 4; t++) ld4(wr[t], &sW[(kk + t) * 128 + og * 4]);
#pragma unroll
      for (int t = 0; t < 4; t++)
#pragma unroll
        for (int nn = 0; nn < 4; nn++)
#pragma unroll
          for (int oo = 0; oo < 4; oo++)
            a4[nn][oo] = fmaf(xr[nn][t], wr[t][oo], a4[nn][oo]);
    }
    __syncthreads();
  }
#pragma unroll
  for (int nn = 0; nn < 4; nn++) {
    float4 v;
    v.x = fmaxf(a4[nn][0] + sdb1[og * 4 + 0], 0.f);
    v.y = fmaxf(a4[nn][1] + sdb1[og * 4 + 1], 0.f);
    v.z = fmaxf(a4[nn][2] + sdb1[og * 4 + 2], 0.f);
    v.w = fmaxf(a4[nn][3] + sdb1[og * 4 + 3], 0.f);
    *(float4*)&sT[(n0 + nn) * 128 + og * 4] = v;
  }
  __syncthreads();

  // ---- sd layer 2 (no relu) + reduce over n
#pragma unroll
  for (int nn = 0; nn < 4; nn++)
#pragma unroll
    for (int oo = 0; oo < 4; oo++) a4[nn][oo] = 0.f;
  for (int c = 0; c < 4; c++) {
    cp_lds(sW, sd_w2 + c * 32 * 128, 4096, tid);
    __syncthreads();
    for (int kk = 0; kk < 32; kk += 4) {
      float xr[4][4], wr[4][4];
#pragma unroll
      for (int nn = 0; nn < 4; nn++) ld4(xr[nn], &sT[(n0 + nn) * 128 + c * 32 + kk]);
#pragma unroll
      for (int t = 0; t < 4; t++) ld4(wr[t], &sW[(kk + t) * 128 + og * 4]);
#pragma unroll
      for (int t = 0; t < 4; t++)
#pragma unroll
        for (int nn = 0; nn < 4; nn++)
#pragma unroll
          for (int oo = 0; oo < 4; oo++)
            a4[nn][oo] = fmaf(xr[nn][t], wr[t][oo], a4[nn][oo]);
    }
    __syncthreads();
  }
  float p[4];
#pragma unroll
  for (int oo = 0; oo < 4; oo++)
    p[oo] = a4[0][oo] + a4[1][oo] + a4[2][oo] + a4[3][oo] + 4.f * sdb2[og * 4 + oo];
  *(float4*)&sH1[lg * 128 + og * 4] = make_float4(p[0], p[1], p[2], p[3]);
  __syncthreads();
  if (tid < 128) {
    float ssum = 0.f;
#pragma unroll
    for (int g = 0; g < 8; g++) ssum += sH1[g * 128 + tid];
    atomicAdd(&out[b * 128 + tid], ssum * (1.0f / 64.0f));
  }
}

// ---------------------------------------------------------------------------
// Kernel B: all-pairs relational MLP. One block = (b, i, half-of-j) -> 32 j's.
// Grid 16384, 256 threads, ~51KB LDS -> 3 blocks/CU.
// feat = [h_i | h_j | dist]; the h_i half of layer 1 is factored into a
// per-block "base" vector (computed once), per-j work only covers h_j + dist.
// att is held entirely in registers (same (j,o) tiling in an-L2 and rc-L3).
// ---------------------------------------------------------------------------
__global__ __launch_bounds__(TPB, 3) void pair_kernel(
    const float* __restrict__ hws,
    const float* __restrict__ rc_w1, const float* __restrict__ rc_b1,
    const float* __restrict__ rc_w2, const float* __restrict__ rc_b2,
    const float* __restrict__ rc_w3, const float* __restrict__ rc_b3,
    const float* __restrict__ an_w1, const float* __restrict__ an_b1,
    const float* __restrict__ an_w2, const float* __restrict__ an_b2,
    float* __restrict__ out) {
  __shared__ __align__(16) float sHj[2048];   // 32 x 64 h_j rows
  __shared__ __align__(16) float sA[4096];    // 32 x 128 rc activations (in-place across layers)
  __shared__ __align__(16) float sAn1[2048];  // 32 x 64 an-L1 act; later reduce scratch (8x128)
  __shared__ __align__(16) float sW[4096];    // weight stage buffer (16KB)
  __shared__ __align__(16) float sHi[64];
  __shared__ __align__(16) float sBaseRc[128];
  __shared__ __align__(16) float sBaseAn[64];
  __shared__ float sDist[32];
  __shared__ __align__(16) float sW1d[128], sAn1d[64], sB2[128], sB3[128], sAb2[128];

  const int tid = threadIdx.x;
  const int jg = tid >> 5;   // 0..7
  const int og = tid & 31;   // 0..31
  const int blk = blockIdx.x;        // ((b*64 + i)*2 + jh)
  const int jh = blk & 1;
  const int i = (blk >> 1) & 63;
  const int b = blk >> 7;
  const int j0 = jg * 4;

  cp_lds(sHj, hws + (b * 64 + jh * 32) * 64, 2048, tid);
  if (tid < 16) ((float4*)sHi)[tid] = ((const float4*)(hws + (b * 64 + i) * 64))[tid];
  if (tid < 128) {
    sW1d[tid] = rc_w1[128 * 128 + tid];   // rc_w1 row 128 (dist row)
    sB2[tid] = rc_b2[tid];
    sB3[tid] = rc_b3[tid];
    sAb2[tid] = an_b2[tid];
  } else if (tid < 192) {
    sAn1d[tid - 128] = an_w1[128 * 64 + (tid - 128)];  // an_w1 dist row
  }
  __syncthreads();

  // base vectors (h_i contribution to layer 1) + dist
  if (tid < 128) {
    float acc = rc_b1[tid];
    for (int k = 0; k < 64; k++) acc = fmaf(sHi[k], rc_w1[k * 128 + tid], acc);
    sBaseRc[tid] = acc;
  } else if (tid < 192) {
    const int o = tid - 128;
    float acc = an_b1[o];
    for (int k = 0; k < 64; k++) acc = fmaf(sHi[k], an_w1[k * 64 + o], acc);
    sBaseAn[o] = acc;
  } else if (tid < 224) {
    const int j = tid - 192;
    const float d0 = sHi[0] - sHj[j * 64 + 0];
    const float d1 = sHi[1] - sHj[j * 64 + 1];
    sDist[j] = d0 * d0 + d1 * d1;
  }
  __syncthreads();

  // ---- P1: rc-L1 (4j x 4o) and an-L1 (4j x 2o) fused, k over h_j (64), 4 chunks of 16
  float aR[4][4], aA[4][2];
#pragma unroll
  for (int jj = 0; jj < 4; jj++) {
#pragma unroll
    for (int oo = 0; oo < 4; oo++) aR[jj][oo] = 0.f;
    aA[jj][0] = 0.f; aA[jj][1] = 0.f;
  }
  for (int c = 0; c < 4; c++) {
    cp_lds(sW, rc_w1 + (64 + c * 16) * 128, 2048, tid);        // rc rows (h_j part)
    cp_lds(sW + 2048, an_w1 + (64 + c * 16) * 64, 1024, tid);  // an rows (h_j part)
    __syncthreads();
    for (int kk = 0; kk < 16; kk += 4) {
      float xr[4][4], wr[4][4], wa[4][2];
#pragma unroll
      for (int jj = 0; jj < 4; jj++) ld4(xr[jj], &sHj[(j0 + jj) * 64 + c * 16 + kk]);
#pragma unroll
      for (int t = 0; t < 4; t++) ld4(wr[t], &sW[(kk + t) * 128 + og * 4]);
#pragma unroll
      for (int t = 0; t < 4; t++) ld2(wa[t], &sW[2048 + (kk + t) * 64 + og * 2]);
#pragma unroll
      for (int t = 0; t < 4; t++)
#pragma unroll
        for (int jj = 0; jj < 4; jj++) {
#pragma unroll
          for (int oo = 0; oo < 4; oo++)
            aR[jj][oo] = fmaf(xr[jj][t], wr[t][oo], aR[jj][oo]);
          aA[jj][0] = fmaf(xr[jj][t], wa[t][0], aA[jj][0]);
          aA[jj][1] = fmaf(xr[jj][t], wa[t][1], aA[jj][1]);
        }
    }
    __syncthreads();
  }
#pragma unroll
  for (int jj = 0; jj < 4; jj++) {
    const int j = j0 + jj;
    const float dj = sDist[j];
    float4 v;
    v.x = fmaxf(aR[jj][0] + sBaseRc[og * 4 + 0] + dj * sW1d[og * 4 + 0], 0.f);
    v.y = fmaxf(aR[jj][1] + sBaseRc[og * 4 + 1] + dj * sW1d[og * 4 + 1], 0.f);
    v.z = fmaxf(aR[jj][2] + sBaseRc[og * 4 + 2] + dj * sW1d[og * 4 + 2], 0.f);
    v.w = fmaxf(aR[jj][3] + sBaseRc[og * 4 + 3] + dj * sW1d[og * 4 + 3], 0.f);
    *(float4*)&sA[j * 128 + og * 4] = v;
    float2 u;
    u.x = fmaxf(aA[jj][0] + sBaseAn[og * 2 + 0] + dj * sAn1d[og * 2 + 0], 0.f);
    u.y = fmaxf(aA[jj][1] + sBaseAn[og * 2 + 1] + dj * sAn1d[og * 2 + 1], 0.f);
    *(float2*)&sAn1[j * 64 + og * 2] = u;
  }
  __syncthreads();

  // ---- P2: an-L2 -> att in registers (4j x 4o, k=64, 2 chunks of 32)
  float aT[4][4];
#pragma unroll
  for (int jj = 0; jj < 4; jj++)
#pragma unroll
    for (int oo = 0; oo < 4; oo++) aT[jj][oo] = 0.f;
  for (int c = 0; c < 2; c++) {
    cp_lds(sW, an_w2 + c * 32 * 128, 4096, tid);
    __syncthreads();
    for (int kk = 0; kk < 32; kk += 4) {
      float xr[4][4], wr[4][4];
#pragma unroll
      for (int jj = 0; jj < 4; jj++) ld4(xr[jj], &sAn1[(j0 + jj) * 64 + c * 32 + kk]);
#pragma unroll
      for (int t = 0; t < 4; t++) ld4(wr[t], &sW[(kk + t) * 128 + og * 4]);
#pragma unroll
      for (int t = 0; t < 4; t++)
#pragma unroll
        for (int jj = 0; jj < 4; jj++)
#pragma unroll
          for (int oo = 0; oo < 4; oo++)
            aT[jj][oo] = fmaf(xr[jj][t], wr[t][oo], aT[jj][oo]);
    }
    __syncthreads();
  }
  float att[4][4];
#pragma unroll
  for (int jj = 0; jj < 4; jj++)
#pragma unroll
    for (int oo = 0; oo < 4; oo++) {
      const float z = aT[jj][oo] + sAb2[og * 4 + oo];
      att[jj][oo] = 1.0f / (1.0f + __expf(-z));
    }

  // ---- P3: rc-L2 (k=128, 4 chunks of 32), in-place back into sA
#pragma unroll
  for (int jj = 0; jj < 4; jj++)
#pragma unroll
    for (int oo = 0; oo < 4; oo++) aT[jj][oo] = 0.f;
  for (int c = 0; c < 4; c++) {
    cp_lds(sW, rc_w2 + c * 32 * 128, 4096, tid);
    __syncthreads();
    for (int kk = 0; kk < 32; kk += 4) {
      float xr[4][4], wr[4][4];
#pragma unroll
      for (int jj = 0; jj < 4; jj++) ld4(xr[jj], &sA[(j0 + jj) * 128 + c * 32 + kk]);
#pragma unroll
      for (int t = 0; t < 4; t++) ld4(wr[t], &sW[(kk + t) * 128 + og * 4]);
#pragma unroll
      for (int t = 0; t < 4; t++)
#pragma unroll
        for (int jj = 0; jj < 4; jj++)
#pragma unroll
          for (int oo = 0; oo < 4; oo++)
            aT[jj][oo] = fmaf(xr[jj][t], wr[t][oo], aT[jj][oo]);
    }
    __syncthreads();
  }
#pragma unroll
  for (int jj = 0; jj < 4; jj++) {
    float4 v;
    v.x = fmaxf(aT[jj][0] + sB2[og * 4 + 0], 0.f);
    v.y = fmaxf(aT[jj][1] + sB2[og * 4 + 1], 0.f);
    v.z = fmaxf(aT[jj][2] + sB2[og * 4 + 2], 0.f);
    v.w = fmaxf(aT[jj][3] + sB2[og * 4 + 3], 0.f);
    *(float4*)&sA[(j0 + jj) * 128 + og * 4] = v;
  }
  __syncthreads();

  // ---- P4: rc-L3 + rel*att + reduce over j
#pragma unroll
  for (int jj = 0; jj < 4; jj++)
#pragma unroll
    for (int oo = 0; oo < 4; oo++) aT[jj][oo] = 0.f;
  for (int c = 0; c < 4; c++) {
    cp_lds(sW, rc_w3 + c * 32 * 128, 4096, tid);
    __syncthreads();
    for (int kk = 0; kk < 32; kk += 4) {
      float xr[4][4], wr[4][4];
#pragma unroll
      for (int jj = 0; jj < 4; jj++) ld4(xr[jj], &sA[(j0 + jj) * 128 + c * 32 + kk]);
#pragma unroll
      for (int t = 0; t < 4; t++) ld4(wr[t], &sW[(kk + t) * 128 + og * 4]);
#pragma unroll
      for (int t = 0; t < 4; t++)
#pragma unroll
        for (int jj = 0; jj < 4; jj++)
#pragma unroll
          for (int oo = 0; oo < 4; oo++)
            aT[jj][oo] = fmaf(xr[jj][t], wr[t][oo], aT[jj][oo]);
    }
    __syncthreads();
  }
  float p[4] = {0.f, 0.f, 0.f, 0.f};
#pragma unroll
  for (int jj = 0; jj < 4; jj++)
#pragma unroll
    for (int oo = 0; oo < 4; oo++) {
      const float rel = fmaxf(aT[jj][oo] + sB3[og * 4 + oo], 0.f);
      p[oo] = fmaf(rel, att[jj][oo], p[oo]);
    }
  // reduce partial j-sums across the 8 jg groups (reuse sAn1 as 8x128 scratch)
  *(float4*)&sAn1[jg * 128 + og * 4] = make_float4(p[0], p[1], p[2], p[3]);
  __syncthreads();
  if (tid < 128) {
    float ssum = 0.f;
#pragma unroll
    for (int g = 0; g < 8; g++) ssum += sAn1[g * 128 + tid];
    // mean over j (1/64) and mean over n (1/64)
    atomicAdd(&out[b * 128 + tid], ssum * (1.0f / 4096.0f));
  }
}

extern "C" void kernel_launch(void* const* d_in, const int* in_sizes, int n_in,
                              void* d_out, int out_size, void* d_ws, size_t ws_size,
                              hipStream_t stream) {
  const float* s     = (const float*)d_in[0];
  const float* se_w1 = (const float*)d_in[1];
  const float* se_b1 = (const float*)d_in[2];
  const float* se_w2 = (const float*)d_in[3];
  const float* se_b2 = (const float*)d_in[4];
  const float* sd_w1 = (const float*)d_in[5];
  const float* sd_b1 = (const float*)d_in[6];
  const float* sd_w2 = (const float*)d_in[7];
  const float* sd_b2 = (const float*)d_in[8];
  const float* rc_w1 = (const float*)d_in[9];
  const float* rc_b1 = (const float*)d_in[10];
  const float* rc_w2 = (const float*)d_in[11];
  const float* rc_b2 = (const float*)d_in[12];
  const float* rc_w3 = (const float*)d_in[13];
  const float* rc_b3 = (const float*)d_in[14];
  const float* an_w1 = (const float*)d_in[15];
  const float* an_b1 = (const float*)d_in[16];
  const float* an_w2 = (const float*)d_in[17];
  const float* an_b2 = (const float*)d_in[18];
  float* out = (float*)d_out;
  float* hws = (float*)d_ws;  // 128*64*64 floats = 2 MB

  hipMemsetAsync(d_out, 0, (size_t)out_size * sizeof(float), stream);
  enc_self_kernel<<<256, TPB, 0, stream>>>(s, se_w1, se_b1, se_w2, se_b2,
                                           sd_w1, sd_b1, sd_w2, sd_b2, hws, out);
  pair_kernel<<<16384, TPB, 0, stream>>>(hws, rc_w1, rc_b1, rc_w2, rc_b2,
                                         rc_w3, rc_b3, an_w1, an_b1, an_w2, an_b2, out);
}

// Round 2
// 441.217 us; speedup vs baseline: 2.0286x; 2.0286x over previous
//
#include <hip/hip_runtime.h>
#include <math.h>

#define TPB 256

typedef unsigned short u16;
typedef __attribute__((ext_vector_type(8))) short bf16x8;
typedef __attribute__((ext_vector_type(4))) float f32x4;

// ---------------- ws layout (u16 element offsets from d_ws) ----------------
// hwsH: u16[524288]           @ 0         (1 MB)   h as bf16-hi
// hwsL: u16[524288]           @ 524288    (1 MB)   h as bf16-lo
// blob: u16[106496]           @ 1048576   (208 KB) transposed chunked weights
#define HWSL_U16 524288
#define BLOB_U16 1048576
// blob-internal offsets (u16). Chunk image = [O][32] hi then [O][32] lo.
#define RC1T_OFF 0       // O=128, K=64  (rc_w1 rows 64..127, transposed)
#define RC2T_OFF 16384   // O=128, K=128
#define RC3T_OFF 49152   // O=128, K=128
#define AN1T_OFF 81920   // O=64,  K=64  (an_w1 rows 64..127, transposed)
#define AN2T_OFF 90112   // O=128, K=64
#define BLOB_TOT 106496
#define WS_NEED ((size_t)(BLOB_U16 + BLOB_TOT) * 2)

__device__ __forceinline__ float b2f(u16 h) {
  return __uint_as_float(((unsigned)h) << 16);
}
// truncation split: x ~= hi + lo with |err| ~ 2^-17 |x|
__device__ __forceinline__ void split_bf16(float x, u16& hi, u16& lo) {
  unsigned u = __float_as_uint(x);
  hi = (u16)(u >> 16);
  float hif = __uint_as_float(u & 0xFFFF0000u);
  lo = (u16)(__float_as_uint(x - hif) >> 16);
}

__device__ __forceinline__ void cp_lds(float* dst, const float* src, int nfloats, int tid) {
  const float4* s4 = (const float4*)src;
  float4* d4 = (float4*)dst;
  const int n4 = nfloats >> 2;
  for (int i = tid; i < n4; i += TPB) d4[i] = s4[i];
}
__device__ __forceinline__ void ld4(float r[4], const float* p) {
  float4 v = *(const float4*)p;
  r[0] = v.x; r[1] = v.y; r[2] = v.z; r[3] = v.w;
}
__device__ __forceinline__ void ld2(float r[2], const float* p) {
  float2 v = *(const float2*)p;
  r[0] = v.x; r[1] = v.y;
}

// ---------------------------------------------------------------------------
// Prep: split+transpose pair-MLP weights into bf16 hi/lo chunk images.
// idx space: rc1 8192 | rc2 16384 | rc3 16384 | an1 4096 | an2 8192 = 53248
// ---------------------------------------------------------------------------
__global__ void prep_weights(const float* __restrict__ rc_w1, const float* __restrict__ rc_w2,
                             const float* __restrict__ rc_w3, const float* __restrict__ an_w1,
                             const float* __restrict__ an_w2, u16* __restrict__ blob) {
  int idx = blockIdx.x * TPB + threadIdx.x;
  if (idx >= 53248) return;
  int O, k, o, base; float x;
  if (idx < 8192)       { O = 128; int r = idx;         k = r >> 7; o = r & 127; x = rc_w1[(64 + k) * 128 + o]; base = RC1T_OFF; }
  else if (idx < 24576) { O = 128; int r = idx - 8192;  k = r >> 7; o = r & 127; x = rc_w2[k * 128 + o];        base = RC2T_OFF; }
  else if (idx < 40960) { O = 128; int r = idx - 24576; k = r >> 7; o = r & 127; x = rc_w3[k * 128 + o];        base = RC3T_OFF; }
  else if (idx < 45056) { O = 64;  int r = idx - 40960; k = r >> 6; o = r & 63;  x = an_w1[(64 + k) * 64 + o];  base = AN1T_OFF; }
  else                  { O = 128; int r = idx - 45056; k = r >> 7; o = r & 127; x = an_w2[k * 128 + o];        base = AN2T_OFF; }
  u16 hi, lo; split_bf16(x, hi, lo);
  int c = k >> 5, kk = k & 31;
  int off = base + c * (O * 64) + o * 32 + kk;
  blob[off] = hi;
  blob[off + O * 32] = lo;
}

// ---------------------------------------------------------------------------
// Kernel A: state encoder -> hwsH/hwsL (bf16 hi/lo), fused self_dyn -> out.
// One block = 32 rows. 256 blocks. (Same structure as R1, bf16 h emit.)
// ---------------------------------------------------------------------------
__global__ __launch_bounds__(TPB, 3) void enc_self_kernel(
    const float* __restrict__ s_in,
    const float* __restrict__ se_w1, const float* __restrict__ se_b1,
    const float* __restrict__ se_w2, const float* __restrict__ se_b2,
    const float* __restrict__ sd_w1, const float* __restrict__ sd_b1,
    const float* __restrict__ sd_w2, const float* __restrict__ sd_b2,
    u16* __restrict__ hwsH, u16* __restrict__ hwsL, float* __restrict__ out) {
  __shared__ __align__(16) float sX[2048];
  __shared__ __align__(16) float sH1[2048];
  __shared__ __align__(16) float sT[4096];
  __shared__ __align__(16) float sW[4096];
  __shared__ float sb1[64], sb2[64], sdb1[128], sdb2[128];

  const int tid = threadIdx.x;
  const int lg = tid >> 5;
  const int og = tid & 31;
  const int b = blockIdx.x >> 1;
  const int row0 = b * 64 + (blockIdx.x & 1) * 32;
  const int n0 = lg * 4;

  cp_lds(sX, s_in + row0 * 64, 2048, tid);
  cp_lds(sW, se_w1, 4096, tid);
  if (tid < 64) { sb1[tid] = se_b1[tid]; sb2[tid] = se_b2[tid]; }
  else if (tid < 192) { const int o = tid - 64; sdb1[o] = sd_b1[o]; sdb2[o] = sd_b2[o]; }
  __syncthreads();

  float a2[4][2];
#pragma unroll
  for (int nn = 0; nn < 4; nn++) { a2[nn][0] = 0.f; a2[nn][1] = 0.f; }
  for (int kk = 0; kk < 64; kk += 4) {
    float xr[4][4], wr[4][2];
#pragma unroll
    for (int nn = 0; nn < 4; nn++) ld4(xr[nn], &sX[(n0 + nn) * 64 + kk]);
#pragma unroll
    for (int t = 0; t < 4; t++) ld2(wr[t], &sW[(kk + t) * 64 + og * 2]);
#pragma unroll
    for (int t = 0; t < 4; t++)
#pragma unroll
      for (int nn = 0; nn < 4; nn++) {
        a2[nn][0] = fmaf(xr[nn][t], wr[t][0], a2[nn][0]);
        a2[nn][1] = fmaf(xr[nn][t], wr[t][1], a2[nn][1]);
      }
  }
#pragma unroll
  for (int nn = 0; nn < 4; nn++) {
    float2 v;
    v.x = fmaxf(a2[nn][0] + sb1[og * 2 + 0], 0.f);
    v.y = fmaxf(a2[nn][1] + sb1[og * 2 + 1], 0.f);
    *(float2*)&sH1[(n0 + nn) * 64 + og * 2] = v;
  }
  __syncthreads();
  cp_lds(sW, se_w2, 4096, tid);
  __syncthreads();

#pragma unroll
  for (int nn = 0; nn < 4; nn++) { a2[nn][0] = 0.f; a2[nn][1] = 0.f; }
  for (int kk = 0; kk < 64; kk += 4) {
    float xr[4][4], wr[4][2];
#pragma unroll
    for (int nn = 0; nn < 4; nn++) ld4(xr[nn], &sH1[(n0 + nn) * 64 + kk]);
#pragma unroll
    for (int t = 0; t < 4; t++) ld2(wr[t], &sW[(kk + t) * 64 + og * 2]);
#pragma unroll
    for (int t = 0; t < 4; t++)
#pragma unroll
      for (int nn = 0; nn < 4; nn++) {
        a2[nn][0] = fmaf(xr[nn][t], wr[t][0], a2[nn][0]);
        a2[nn][1] = fmaf(xr[nn][t], wr[t][1], a2[nn][1]);
      }
  }
#pragma unroll
  for (int nn = 0; nn < 4; nn++) {
    float2 v;
    v.x = fmaxf(a2[nn][0] + sb2[og * 2 + 0], 0.f);
    v.y = fmaxf(a2[nn][1] + sb2[og * 2 + 1], 0.f);
    *(float2*)&sX[(n0 + nn) * 64 + og * 2] = v;
    u16 h0h, h0l, h1h, h1l;
    split_bf16(v.x, h0h, h0l);
    split_bf16(v.y, h1h, h1l);
    const int off = (row0 + n0 + nn) * 64 + og * 2;
    *(ushort2*)&hwsH[off] = make_ushort2(h0h, h1h);
    *(ushort2*)&hwsL[off] = make_ushort2(h0l, h1l);
  }
  __syncthreads();

  float a4[4][4];
#pragma unroll
  for (int nn = 0; nn < 4; nn++)
#pragma unroll
    for (int oo = 0; oo < 4; oo++) a4[nn][oo] = 0.f;
  for (int c = 0; c < 2; c++) {
    cp_lds(sW, sd_w1 + c * 32 * 128, 4096, tid);
    __syncthreads();
    for (int kk = 0; kk < 32; kk += 4) {
      float xr[4][4], wr[4][4];
#pragma unroll
      for (int nn = 0; nn < 4; nn++) ld4(xr[nn], &sX[(n0 + nn) * 64 + c * 32 + kk]);
#pragma unroll
      for (int t = 0; t < 4; t++) ld4(wr[t], &sW[(kk + t) * 128 + og * 4]);
#pragma unroll
      for (int t = 0; t < 4; t++)
#pragma unroll
        for (int nn = 0; nn < 4; nn++)
#pragma unroll
          for (int oo = 0; oo < 4; oo++)
            a4[nn][oo] = fmaf(xr[nn][t], wr[t][oo], a4[nn][oo]);
    }
    __syncthreads();
  }
#pragma unroll
  for (int nn = 0; nn < 4; nn++) {
    float4 v;
    v.x = fmaxf(a4[nn][0] + sdb1[og * 4 + 0], 0.f);
    v.y = fmaxf(a4[nn][1] + sdb1[og * 4 + 1], 0.f);
    v.z = fmaxf(a4[nn][2] + sdb1[og * 4 + 2], 0.f);
    v.w = fmaxf(a4[nn][3] + sdb1[og * 4 + 3], 0.f);
    *(float4*)&sT[(n0 + nn) * 128 + og * 4] = v;
  }
  __syncthreads();

#pragma unroll
  for (int nn = 0; nn < 4; nn++)
#pragma unroll
    for (int oo = 0; oo < 4; oo++) a4[nn][oo] = 0.f;
  for (int c = 0; c < 4; c++) {
    cp_lds(sW, sd_w2 + c * 32 * 128, 4096, tid);
    __syncthreads();
    for (int kk = 0; kk < 32; kk += 4) {
      float xr[4][4], wr[4][4];
#pragma unroll
      for (int nn = 0; nn < 4; nn++) ld4(xr[nn], &sT[(n0 + nn) * 128 + c * 32 + kk]);
#pragma unroll
      for (int t = 0; t < 4; t++) ld4(wr[t], &sW[(kk + t) * 128 + og * 4]);
#pragma unroll
      for (int t = 0; t < 4; t++)
#pragma unroll
        for (int nn = 0; nn < 4; nn++)
#pragma unroll
          for (int oo = 0; oo < 4; oo++)
            a4[nn][oo] = fmaf(xr[nn][t], wr[t][oo], a4[nn][oo]);
    }
    __syncthreads();
  }
  float p[4];
#pragma unroll
  for (int oo = 0; oo < 4; oo++)
    p[oo] = a4[0][oo] + a4[1][oo] + a4[2][oo] + a4[3][oo] + 4.f * sdb2[og * 4 + oo];
  *(float4*)&sH1[lg * 128 + og * 4] = make_float4(p[0], p[1], p[2], p[3]);
  __syncthreads();
  if (tid < 128) {
    float ssum = 0.f;
#pragma unroll
    for (int g = 0; g < 8; g++) ssum += sH1[g * 128 + tid];
    atomicAdd(&out[b * 128 + tid], ssum * (1.0f / 64.0f));
  }
}

// ---------------------------------------------------------------------------
// MFMA layer driver. A = W^T (m=o), B = acts (n=j). D[m=o][n=j].
// Frag layouts (gfx950 16x16x32 bf16, guide §3, m89-verified):
//   A[m=lane&15][k=quad*8+jj], B[n=lane&15][k=quad*8+jj],
//   C/D: n(col)=lane&15, m(row)=quad*4+reg.
// sW chunk image in LDS: hi rows [o][40-stride], lo at +5120 u16.
// ---------------------------------------------------------------------------
template<int MT, int NCHUNK, int RSB, int O16>
__device__ __forceinline__ void run_layer(f32x4 (&acc)[MT][4],
    const u16* __restrict__ wchunk0,
    const u16* __restrict__ sBH, const u16* __restrict__ sBL,
    u16* __restrict__ sW, int tid, int o0, int quad, int l15) {
  for (int c = 0; c < NCHUNK; ++c) {
    __syncthreads();  // sW free (prev compute done)
    const float4* src = (const float4*)(wchunk0 + c * (O16 * 8));
    for (int idx = tid; idx < O16; idx += TPB) {
      const int half = (idx >= O16 / 2) ? 1 : 0;
      const int id2 = idx - half * (O16 / 2);
      const int row = id2 >> 2, q = id2 & 3;
      *(float4*)&sW[half * 5120 + row * 40 + q * 8] = src[idx];
    }
    __syncthreads();
    const int kk = c * 32 + quad * 8;
    bf16x8 Bh[4], Bl[4];
#pragma unroll
    for (int s = 0; s < 4; ++s) {
      Bh[s] = *(const bf16x8*)&sBH[(16 * s + l15) * RSB + kk];
      Bl[s] = *(const bf16x8*)&sBL[(16 * s + l15) * RSB + kk];
    }
#pragma unroll
    for (int t = 0; t < MT; ++t) {
      const int o = o0 + 16 * t + l15;
      const bf16x8 Ah = *(const bf16x8*)&sW[o * 40 + quad * 8];
      const bf16x8 Al = *(const bf16x8*)&sW[5120 + o * 40 + quad * 8];
#pragma unroll
      for (int s = 0; s < 4; ++s) {
        f32x4 a = acc[t][s];
        a = __builtin_amdgcn_mfma_f32_16x16x32_bf16(Ah, Bh[s], a, 0, 0, 0);
        a = __builtin_amdgcn_mfma_f32_16x16x32_bf16(Al, Bh[s], a, 0, 0, 0);
        a = __builtin_amdgcn_mfma_f32_16x16x32_bf16(Ah, Bl[s], a, 0, 0, 0);
        acc[t][s] = a;
      }
    }
  }
}

// relu(+bias) -> split -> LDS act store (hi/lo), 4 consecutive o per lane (b64).
template<int MT, int RS>
__device__ __forceinline__ void store_acts(const f32x4 (&acc)[MT][4], const float* bias,
                                           u16* dH, u16* dL, int o0, int quad, int l15) {
#pragma unroll
  for (int t = 0; t < MT; ++t) {
    const int ob = o0 + 16 * t + quad * 4;
#pragma unroll
    for (int s = 0; s < 4; ++s) {
      const int j = 16 * s + l15;
      u16 hv[4], lv[4];
#pragma unroll
      for (int r = 0; r < 4; ++r) {
        float x = acc[t][s][r];
        if (bias) x += bias[ob + r];
        x = fmaxf(x, 0.f);
        split_bf16(x, hv[r], lv[r]);
      }
      *(ushort4*)&dH[j * RS + ob] = make_ushort4(hv[0], hv[1], hv[2], hv[3]);
      *(ushort4*)&dL[j * RS + ob] = make_ushort4(lv[0], lv[1], lv[2], lv[3]);
    }
  }
}

// ---------------------------------------------------------------------------
// Kernel B (MFMA): one block per (b,i). M=up-to-128 o, N=64 j. 77.8 KB LDS ->
// 2 blocks/CU. h_i half + dist column of layer-1 folded into acc init.
// ---------------------------------------------------------------------------
__global__ __launch_bounds__(TPB, 2) void pair_mfma_kernel(
    const u16* __restrict__ hwsH, const u16* __restrict__ hwsL,
    const u16* __restrict__ blob,
    const float* __restrict__ rc_w1, const float* __restrict__ rc_b1,
    const float* __restrict__ rc_b2, const float* __restrict__ rc_b3,
    const float* __restrict__ an_w1, const float* __restrict__ an_b1,
    const float* __restrict__ an_b2,
    float* __restrict__ out) {
  __shared__ __align__(16) u16 sActH[64 * 136];  // acts hi (row stride 136)
  __shared__ __align__(16) u16 sActL[64 * 136];
  __shared__ __align__(16) u16 sAnH[64 * 72];    // an-L1 acts (row stride 72)
  __shared__ __align__(16) u16 sAnL[64 * 72];
  __shared__ __align__(16) u16 sW[10240];        // weight chunk hi(0)/lo(5120)
  __shared__ float sHi[64], sDist[64];
  __shared__ float sBaseRc[128], sBaseAn[64], sW1d[128], sAnd[64];
  __shared__ float sB2[128], sB3[128], sAb2[128], sRed[128];

  const int tid = threadIdx.x;
  const int w = tid >> 6, lane = tid & 63;
  const int quad = lane >> 4, l15 = lane & 15;
  const int b = blockIdx.x >> 6, i = blockIdx.x & 63;
  const int o0 = w * 32;    // 128-o layers: 2 M-tiles per wave
  const int o0a = w * 16;   // an-L1 (64-o): 1 M-tile per wave

  // ---- init: stage h_j (bf16 hi/lo) into sAct cols 0..63; constants
  {
    const float4* srcH = (const float4*)(hwsH + b * 4096);
    const float4* srcL = (const float4*)(hwsL + b * 4096);
    for (int idx = tid; idx < 512; idx += TPB) {
      const int row = idx >> 3, q = idx & 7;
      *(float4*)&sActH[row * 136 + q * 8] = srcH[idx];
      *(float4*)&sActL[row * 136 + q * 8] = srcL[idx];
    }
  }
  if (tid < 64)
    sHi[tid] = b2f(hwsH[(b * 64 + i) * 64 + tid]) + b2f(hwsL[(b * 64 + i) * 64 + tid]);
  if (tid < 128) {
    sB2[tid] = rc_b2[tid]; sB3[tid] = rc_b3[tid]; sAb2[tid] = an_b2[tid];
    sW1d[tid] = rc_w1[128 * 128 + tid];
  } else if (tid < 192) {
    sAnd[tid - 128] = an_w1[128 * 64 + (tid - 128)];
  }
  __syncthreads();
  if (tid < 128) {
    float acc = rc_b1[tid];
    for (int k = 0; k < 64; ++k) acc = fmaf(sHi[k], rc_w1[k * 128 + tid], acc);
    sBaseRc[tid] = acc;
  } else if (tid < 192) {
    const int o = tid - 128;
    float acc = an_b1[o];
    for (int k = 0; k < 64; ++k) acc = fmaf(sHi[k], an_w1[k * 64 + o], acc);
    sBaseAn[o] = acc;
  } else {
    const int j = tid - 192;
    const float h0 = b2f(sActH[j * 136 + 0]) + b2f(sActL[j * 136 + 0]);
    const float h1 = b2f(sActH[j * 136 + 1]) + b2f(sActL[j * 136 + 1]);
    const float d0 = sHi[0] - h0, d1 = sHi[1] - h1;
    sDist[j] = d0 * d0 + d1 * d1;
  }
  __syncthreads();

  // ---- rc-L1: acc init = base + dist*w1d, MFMA over h_j (K=64)
  f32x4 accR[2][4];
#pragma unroll
  for (int t = 0; t < 2; ++t)
#pragma unroll
    for (int s = 0; s < 4; ++s) {
      const float dj = sDist[16 * s + l15];
      f32x4 a;
#pragma unroll
      for (int r = 0; r < 4; ++r) {
        const int o = o0 + 16 * t + quad * 4 + r;
        a[r] = sBaseRc[o] + dj * sW1d[o];
      }
      accR[t][s] = a;
    }
  run_layer<2, 2, 136, 1024>(accR, blob + RC1T_OFF, sActH, sActL, sW, tid, o0, quad, l15);

  // ---- an-L1 (same B = h_j)
  f32x4 accN[1][4];
#pragma unroll
  for (int s = 0; s < 4; ++s) {
    const float dj = sDist[16 * s + l15];
    f32x4 a;
#pragma unroll
    for (int r = 0; r < 4; ++r) {
      const int o = o0a + quad * 4 + r;
      a[r] = sBaseAn[o] + dj * sAnd[o];
    }
    accN[0][s] = a;
  }
  run_layer<1, 2, 136, 512>(accN, blob + AN1T_OFF, sActH, sActL, sW, tid, o0a, quad, l15);
  __syncthreads();  // all reads of h done
  store_acts<2, 136>(accR, nullptr, sActH, sActL, o0, quad, l15);  // rc1 acts
  store_acts<1, 72>(accN, nullptr, sAnH, sAnL, o0a, quad, l15);    // an1 acts
  __syncthreads();

  // ---- an-L2 -> att in regs
  f32x4 accT[2][4];
#pragma unroll
  for (int t = 0; t < 2; ++t)
#pragma unroll
    for (int s = 0; s < 4; ++s) accT[t][s] = (f32x4){0.f, 0.f, 0.f, 0.f};
  run_layer<2, 2, 72, 1024>(accT, blob + AN2T_OFF, sAnH, sAnL, sW, tid, o0, quad, l15);
  float att[2][4][4];
#pragma unroll
  for (int t = 0; t < 2; ++t)
#pragma unroll
    for (int s = 0; s < 4; ++s)
#pragma unroll
      for (int r = 0; r < 4; ++r) {
        const float z = accT[t][s][r] + sAb2[o0 + 16 * t + quad * 4 + r];
        att[t][s][r] = 1.0f / (1.0f + __expf(-z));
      }

  // ---- rc-L2 (K=128), write back in place
#pragma unroll
  for (int t = 0; t < 2; ++t)
#pragma unroll
    for (int s = 0; s < 4; ++s) accR[t][s] = (f32x4){0.f, 0.f, 0.f, 0.f};
  run_layer<2, 4, 136, 1024>(accR, blob + RC2T_OFF, sActH, sActL, sW, tid, o0, quad, l15);
  __syncthreads();
  store_acts<2, 136>(accR, sB2, sActH, sActL, o0, quad, l15);
  __syncthreads();

  // ---- rc-L3 + rel*att + reduce over j
#pragma unroll
  for (int t = 0; t < 2; ++t)
#pragma unroll
    for (int s = 0; s < 4; ++s) accR[t][s] = (f32x4){0.f, 0.f, 0.f, 0.f};
  run_layer<2, 4, 136, 1024>(accR, blob + RC3T_OFF, sActH, sActL, sW, tid, o0, quad, l15);
  float ps[2][4] = {{0.f, 0.f, 0.f, 0.f}, {0.f, 0.f, 0.f, 0.f}};
#pragma unroll
  for (int t = 0; t < 2; ++t)
#pragma unroll
    for (int s = 0; s < 4; ++s)
#pragma unroll
      for (int r = 0; r < 4; ++r) {
        const float rel = fmaxf(accR[t][s][r] + sB3[o0 + 16 * t + quad * 4 + r], 0.f);
        ps[t][r] = fmaf(rel, att[t][s][r], ps[t][r]);
      }
#pragma unroll
  for (int t = 0; t < 2; ++t)
#pragma unroll
    for (int r = 0; r < 4; ++r) {
      float v = ps[t][r];
      v += __shfl_xor(v, 1, 64);
      v += __shfl_xor(v, 2, 64);
      v += __shfl_xor(v, 4, 64);
      v += __shfl_xor(v, 8, 64);
      ps[t][r] = v;
    }
  if (l15 == 0) {
#pragma unroll
    for (int t = 0; t < 2; ++t)
#pragma unroll
      for (int r = 0; r < 4; ++r)
        sRed[o0 + 16 * t + quad * 4 + r] = ps[t][r];
  }
  __syncthreads();
  if (tid < 128)
    atomicAdd(&out[b * 128 + tid], sRed[tid] * (1.0f / 4096.0f));
}

// ---------------------------------------------------------------------------
// Fallback pair kernel (R1, VALU): used only if ws_size < WS_NEED.
// Reads h from bf16 hi/lo hws (recombined).
// ---------------------------------------------------------------------------
__global__ __launch_bounds__(TPB, 3) void pair_kernel(
    const u16* __restrict__ hwsH, const u16* __restrict__ hwsL,
    const float* __restrict__ rc_w1, const float* __restrict__ rc_b1,
    const float* __restrict__ rc_w2, const float* __restrict__ rc_b2,
    const float* __restrict__ rc_w3, const float* __restrict__ rc_b3,
    const float* __restrict__ an_w1, const float* __restrict__ an_b1,
    const float* __restrict__ an_w2, const float* __restrict__ an_b2,
    float* __restrict__ out) {
  __shared__ __align__(16) float sHj[2048];
  __shared__ __align__(16) float sA[4096];
  __shared__ __align__(16) float sAn1[2048];
  __shared__ __align__(16) float sW[4096];
  __shared__ __align__(16) float sHi[64];
  __shared__ __align__(16) float sBaseRc[128];
  __shared__ __align__(16) float sBaseAn[64];
  __shared__ float sDist[32];
  __shared__ __align__(16) float sW1d[128], sAn1d[64], sB2[128], sB3[128], sAb2[128];

  const int tid = threadIdx.x;
  const int jg = tid >> 5;
  const int og = tid & 31;
  const int blk = blockIdx.x;
  const int jh = blk & 1;
  const int i = (blk >> 1) & 63;
  const int b = blk >> 7;
  const int j0 = jg * 4;

  for (int idx = tid; idx < 2048; idx += TPB) {
    const int off = (b * 64 + jh * 32) * 64 + idx;
    sHj[idx] = b2f(hwsH[off]) + b2f(hwsL[off]);
  }
  if (tid < 64) sHi[tid] = b2f(hwsH[(b * 64 + i) * 64 + tid]) + b2f(hwsL[(b * 64 + i) * 64 + tid]);
  if (tid < 128) {
    sW1d[tid] = rc_w1[128 * 128 + tid];
    sB2[tid] = rc_b2[tid]; sB3[tid] = rc_b3[tid]; sAb2[tid] = an_b2[tid];
  } else if (tid < 192) {
    sAn1d[tid - 128] = an_w1[128 * 64 + (tid - 128)];
  }
  __syncthreads();
  if (tid < 128) {
    float acc = rc_b1[tid];
    for (int k = 0; k < 64; k++) acc = fmaf(sHi[k], rc_w1[k * 128 + tid], acc);
    sBaseRc[tid] = acc;
  } else if (tid < 192) {
    const int o = tid - 128;
    float acc = an_b1[o];
    for (int k = 0; k < 64; k++) acc = fmaf(sHi[k], an_w1[k * 64 + o], acc);
    sBaseAn[o] = acc;
  } else if (tid < 224) {
    const int j = tid - 192;
    const float d0 = sHi[0] - sHj[j * 64 + 0];
    const float d1 = sHi[1] - sHj[j * 64 + 1];
    sDist[j] = d0 * d0 + d1 * d1;
  }
  __syncthreads();

  float aR[4][4], aA[4][2];
#pragma unroll
  for (int jj = 0; jj < 4; jj++) {
#pragma unroll
    for (int oo = 0; oo < 4; oo++) aR[jj][oo] = 0.f;
    aA[jj][0] = 0.f; aA[jj][1] = 0.f;
  }
  for (int c = 0; c < 4; c++) {
    cp_lds(sW, rc_w1 + (64 + c * 16) * 128, 2048, tid);
    cp_lds(sW + 2048, an_w1 + (64 + c * 16) * 64, 1024, tid);
    __syncthreads();
    for (int kk = 0; kk < 16; kk += 4) {
      float xr[4][4], wr[4][4], wa[4][2];
#pragma unroll
      for (int jj = 0; jj < 4; jj++) ld4(xr[jj], &sHj[(j0 + jj) * 64 + c * 16 + kk]);
#pragma unroll
      for (int t = 0; t < 4; t++) ld4(wr[t], &sW[(kk + t) * 128 + og * 4]);
#pragma unroll
      for (int t = 0; t < 4; t++) ld2(wa[t], &sW[2048 + (kk + t) * 64 + og * 2]);
#pragma unroll
      for (int t = 0; t < 4; t++)
#pragma unroll
        for (int jj = 0; jj < 4; jj++) {
#pragma unroll
          for (int oo = 0; oo < 4; oo++)
            aR[jj][oo] = fmaf(xr[jj][t], wr[t][oo], aR[jj][oo]);
          aA[jj][0] = fmaf(xr[jj][t], wa[t][0], aA[jj][0]);
          aA[jj][1] = fmaf(xr[jj][t], wa[t][1], aA[jj][1]);
        }
    }
    __syncthreads();
  }
#pragma unroll
  for (int jj = 0; jj < 4; jj++) {
    const int j = j0 + jj;
    const float dj = sDist[j];
    float4 v;
    v.x = fmaxf(aR[jj][0] + sBaseRc[og * 4 + 0] + dj * sW1d[og * 4 + 0], 0.f);
    v.y = fmaxf(aR[jj][1] + sBaseRc[og * 4 + 1] + dj * sW1d[og * 4 + 1], 0.f);
    v.z = fmaxf(aR[jj][2] + sBaseRc[og * 4 + 2] + dj * sW1d[og * 4 + 2], 0.f);
    v.w = fmaxf(aR[jj][3] + sBaseRc[og * 4 + 3] + dj * sW1d[og * 4 + 3], 0.f);
    *(float4*)&sA[j * 128 + og * 4] = v;
    float2 u;
    u.x = fmaxf(aA[jj][0] + sBaseAn[og * 2 + 0] + dj * sAn1d[og * 2 + 0], 0.f);
    u.y = fmaxf(aA[jj][1] + sBaseAn[og * 2 + 1] + dj * sAn1d[og * 2 + 1], 0.f);
    *(float2*)&sAn1[j * 64 + og * 2] = u;
  }
  __syncthreads();

  float aT[4][4];
#pragma unroll
  for (int jj = 0; jj < 4; jj++)
#pragma unroll
    for (int oo = 0; oo < 4; oo++) aT[jj][oo] = 0.f;
  for (int c = 0; c < 2; c++) {
    cp_lds(sW, an_w2 + c * 32 * 128, 4096, tid);
    __syncthreads();
    for (int kk = 0; kk < 32; kk += 4) {
      float xr[4][4], wr[4][4];
#pragma unroll
      for (int jj = 0; jj < 4; jj++) ld4(xr[jj], &sAn1[(j0 + jj) * 64 + c * 32 + kk]);
#pragma unroll
      for (int t = 0; t < 4; t++) ld4(wr[t], &sW[(kk + t) * 128 + og * 4]);
#pragma unroll
      for (int t = 0; t < 4; t++)
#pragma unroll
        for (int jj = 0; jj < 4; jj++)
#pragma unroll
          for (int oo = 0; oo < 4; oo++)
            aT[jj][oo] = fmaf(xr[jj][t], wr[t][oo], aT[jj][oo]);
    }
    __syncthreads();
  }
  float att[4][4];
#pragma unroll
  for (int jj = 0; jj < 4; jj++)
#pragma unroll
    for (int oo = 0; oo < 4; oo++) {
      const float z = aT[jj][oo] + sAb2[og * 4 + oo];
      att[jj][oo] = 1.0f / (1.0f + __expf(-z));
    }

#pragma unroll
  for (int jj = 0; jj < 4; jj++)
#pragma unroll
    for (int oo = 0; oo < 4; oo++) aT[jj][oo] = 0.f;
  for (int c = 0; c < 4; c++) {
    cp_lds(sW, rc_w2 + c * 32 * 128, 4096, tid);
    __syncthreads();
    for (int kk = 0; kk < 32; kk += 4) {
      float xr[4][4], wr[4][4];
#pragma unroll
      for (int jj = 0; jj < 4; jj++) ld4(xr[jj], &sA[(j0 + jj) * 128 + c * 32 + kk]);
#pragma unroll
      for (int t = 0; t < 4; t++) ld4(wr[t], &sW[(kk + t) * 128 + og * 4]);
#pragma unroll
      for (int t = 0; t < 4; t++)
#pragma unroll
        for (int jj = 0; jj < 4; jj++)
#pragma unroll
          for (int oo = 0; oo < 4; oo++)
            aT[jj][oo] = fmaf(xr[jj][t], wr[t][oo], aT[jj][oo]);
    }
    __syncthreads();
  }
#pragma unroll
  for (int jj = 0; jj < 4; jj++) {
    float4 v;
    v.x = fmaxf(aT[jj][0] + sB2[og * 4 + 0], 0.f);
    v.y = fmaxf(aT[jj][1] + sB2[og * 4 + 1], 0.f);
    v.z = fmaxf(aT[jj][2] + sB2[og * 4 + 2], 0.f);
    v.w = fmaxf(aT[jj][3] + sB2[og * 4 + 3], 0.f);
    *(float4*)&sA[(j0 + jj) * 128 + og * 4] = v;
  }
  __syncthreads();

#pragma unroll
  for (int jj = 0; jj < 4; jj++)
#pragma unroll
    for (int oo = 0; oo < 4; oo++) aT[jj][oo] = 0.f;
  for (int c = 0; c < 4; c++) {
    cp_lds(sW, rc_w3 + c * 32 * 128, 4096, tid);
    __syncthreads();
    for (int kk = 0; kk < 32; kk += 4) {
      float xr[4][4], wr[4][4];
#pragma unroll
      for (int jj = 0; jj < 4; jj++) ld4(xr[jj], &sA[(j0 + jj) * 128 + c * 32 + kk]);
#pragma unroll
      for (int t = 0; t < 4; t++) ld4(wr[t], &sW[(kk + t) * 128 + og * 4]);
#pragma unroll
      for (int t = 0; t < 4; t++)
#pragma unroll
        for (int jj = 0; jj < 4; jj++)
#pragma unroll
          for (int oo = 0; oo < 4; oo++)
            aT[jj][oo] = fmaf(xr[jj][t], wr[t][oo], aT[jj][oo]);
    }
    __syncthreads();
  }
  float p[4] = {0.f, 0.f, 0.f, 0.f};
#pragma unroll
  for (int jj = 0; jj < 4; jj++)
#pragma unroll
    for (int oo = 0; oo < 4; oo++) {
      const float rel = fmaxf(aT[jj][oo] + sB3[og * 4 + oo], 0.f);
      p[oo] = fmaf(rel, att[jj][oo], p[oo]);
    }
  *(float4*)&sAn1[jg * 128 + og * 4] = make_float4(p[0], p[1], p[2], p[3]);
  __syncthreads();
  if (tid < 128) {
    float ssum = 0.f;
#pragma unroll
    for (int g = 0; g < 8; g++) ssum += sAn1[g * 128 + tid];
    atomicAdd(&out[b * 128 + tid], ssum * (1.0f / 4096.0f));
  }
}

extern "C" void kernel_launch(void* const* d_in, const int* in_sizes, int n_in,
                              void* d_out, int out_size, void* d_ws, size_t ws_size,
                              hipStream_t stream) {
  const float* s     = (const float*)d_in[0];
  const float* se_w1 = (const float*)d_in[1];
  const float* se_b1 = (const float*)d_in[2];
  const float* se_w2 = (const float*)d_in[3];
  const float* se_b2 = (const float*)d_in[4];
  const float* sd_w1 = (const float*)d_in[5];
  const float* sd_b1 = (const float*)d_in[6];
  const float* sd_w2 = (const float*)d_in[7];
  const float* sd_b2 = (const float*)d_in[8];
  const float* rc_w1 = (const float*)d_in[9];
  const float* rc_b1 = (const float*)d_in[10];
  const float* rc_w2 = (const float*)d_in[11];
  const float* rc_b2 = (const float*)d_in[12];
  const float* rc_w3 = (const float*)d_in[13];
  const float* rc_b3 = (const float*)d_in[14];
  const float* an_w1 = (const float*)d_in[15];
  const float* an_b1 = (const float*)d_in[16];
  const float* an_w2 = (const float*)d_in[17];
  const float* an_b2 = (const float*)d_in[18];
  float* out = (float*)d_out;
  u16* hwsH = (u16*)d_ws;
  u16* hwsL = hwsH + HWSL_U16;
  u16* blob = hwsH + BLOB_U16;

  hipMemsetAsync(d_out, 0, (size_t)out_size * sizeof(float), stream);
  enc_self_kernel<<<256, TPB, 0, stream>>>(s, se_w1, se_b1, se_w2, se_b2,
                                           sd_w1, sd_b1, sd_w2, sd_b2, hwsH, hwsL, out);
  if (ws_size >= WS_NEED) {
    prep_weights<<<208, TPB, 0, stream>>>(rc_w1, rc_w2, rc_w3, an_w1, an_w2, blob);
    pair_mfma_kernel<<<8192, TPB, 0, stream>>>(hwsH, hwsL, blob,
                                               rc_w1, rc_b1, rc_b2, rc_b3,
                                               an_w1, an_b1, an_b2, out);
  } else {
    pair_kernel<<<16384, TPB, 0, stream>>>(hwsH, hwsL, rc_w1, rc_b1, rc_w2, rc_b2,
                                           rc_w3, rc_b3, an_w1, an_b1, an_w2, an_b2, out);
  }
}

// Round 3
// 280.776 us; speedup vs baseline: 3.1877x; 1.5714x over previous
//
#include <hip/hip_runtime.h>
#include <math.h>

#define TPB 256

typedef unsigned short u16;
typedef __attribute__((ext_vector_type(8))) short bf16x8;
typedef __attribute__((ext_vector_type(4))) float f32x4;

// ---------------- ws layout (u16 element offsets from d_ws) ----------------
#define HWSL_U16 524288
#define BLOB_U16 1048576
// blob: fragment-linear A images. Per layer: hi[OK] then lo[OK].
// Frag addr (u16): layerOff + ((c*TILES + tg)*64 + lane)*8, lane=(quad*16+l15),
// element (o,k): o = tg*16 + (lane&15), k = c*32 + (lane>>4)*8 + u.
#define RC1F 0        // O=128,K=64  T=8  OK=8192
#define AN1F 16384    // O=64, K=64  T=4  OK=4096
#define AN2F 24576    // O=128,K=64  T=8  OK=8192
#define RC2F 40960    // O=128,K=128 T=8  OK=16384
#define RC3F 73728    // O=128,K=128 T=8  OK=16384
#define BLOB_TOT 106496
#define WS_NEED ((size_t)(BLOB_U16 + BLOB_TOT) * 2)

__device__ __forceinline__ float b2f(u16 h) {
  return __uint_as_float(((unsigned)h) << 16);
}
// truncation split: x ~= hi + lo with |err| ~ 2^-17 |x|
__device__ __forceinline__ void split_bf16(float x, u16& hi, u16& lo) {
  unsigned u = __float_as_uint(x);
  hi = (u16)(u >> 16);
  float hif = __uint_as_float(u & 0xFFFF0000u);
  lo = (u16)(__float_as_uint(x - hif) >> 16);
}

__device__ __forceinline__ void cp_lds(float* dst, const float* src, int nfloats, int tid) {
  const float4* s4 = (const float4*)src;
  float4* d4 = (float4*)dst;
  const int n4 = nfloats >> 2;
  for (int i = tid; i < n4; i += TPB) d4[i] = s4[i];
}
__device__ __forceinline__ void ld4(float r[4], const float* p) {
  float4 v = *(const float4*)p;
  r[0] = v.x; r[1] = v.y; r[2] = v.z; r[3] = v.w;
}
__device__ __forceinline__ void ld2(float r[2], const float* p) {
  float2 v = *(const float2*)p;
  r[0] = v.x; r[1] = v.y;
}

// ---------------------------------------------------------------------------
// Prep: split weights into bf16 hi/lo, FRAGMENT-LINEAR layout (per 16x16x32
// MFMA A-operand): consecutive lanes own consecutive 16B frags.
// ---------------------------------------------------------------------------
__global__ void prep_weights(const float* __restrict__ rc_w1, const float* __restrict__ rc_w2,
                             const float* __restrict__ rc_w3, const float* __restrict__ an_w1,
                             const float* __restrict__ an_w2, u16* __restrict__ blob) {
  int idx = blockIdx.x * TPB + threadIdx.x;
  if (idx >= 53248) return;
  int r, base, OK, T; const float* W; int Wld; int krow0;
  if (idx < 8192)       { r = idx;         base = RC1F; OK = 8192;  T = 8; W = rc_w1; Wld = 128; krow0 = 64; }
  else if (idx < 12288) { r = idx - 8192;  base = AN1F; OK = 4096;  T = 4; W = an_w1; Wld = 64;  krow0 = 64; }
  else if (idx < 20480) { r = idx - 12288; base = AN2F; OK = 8192;  T = 8; W = an_w2; Wld = 128; krow0 = 0;  }
  else if (idx < 36864) { r = idx - 20480; base = RC2F; OK = 16384; T = 8; W = rc_w2; Wld = 128; krow0 = 0;  }
  else                  { r = idx - 36864; base = RC3F; OK = 16384; T = 8; W = rc_w3; Wld = 128; krow0 = 0;  }
  const int u = r & 7;
  const int lane = (r >> 3) & 63;
  const int ct = r >> 9;
  const int c = (T == 8) ? (ct >> 3) : (ct >> 2);
  const int tg = (T == 8) ? (ct & 7) : (ct & 3);
  const int o = tg * 16 + (lane & 15);
  const int k = c * 32 + (lane >> 4) * 8 + u;
  const float x = W[(krow0 + k) * Wld + o];
  u16 hi, lo; split_bf16(x, hi, lo);
  blob[base + r] = hi;
  blob[base + OK + r] = lo;
}

// ---------------------------------------------------------------------------
// Kernel A: state encoder -> hwsH/hwsL (bf16 hi/lo), fused self_dyn -> out.
// ---------------------------------------------------------------------------
__global__ __launch_bounds__(TPB, 3) void enc_self_kernel(
    const float* __restrict__ s_in,
    const float* __restrict__ se_w1, const float* __restrict__ se_b1,
    const float* __restrict__ se_w2, const float* __restrict__ se_b2,
    const float* __restrict__ sd_w1, const float* __restrict__ sd_b1,
    const float* __restrict__ sd_w2, const float* __restrict__ sd_b2,
    u16* __restrict__ hwsH, u16* __restrict__ hwsL, float* __restrict__ out) {
  __shared__ __align__(16) float sX[2048];
  __shared__ __align__(16) float sH1[2048];
  __shared__ __align__(16) float sT[4096];
  __shared__ __align__(16) float sW[4096];
  __shared__ float sb1[64], sb2[64], sdb1[128], sdb2[128];

  const int tid = threadIdx.x;
  const int lg = tid >> 5;
  const int og = tid & 31;
  const int b = blockIdx.x >> 1;
  const int row0 = b * 64 + (blockIdx.x & 1) * 32;
  const int n0 = lg * 4;

  cp_lds(sX, s_in + row0 * 64, 2048, tid);
  cp_lds(sW, se_w1, 4096, tid);
  if (tid < 64) { sb1[tid] = se_b1[tid]; sb2[tid] = se_b2[tid]; }
  else if (tid < 192) { const int o = tid - 64; sdb1[o] = sd_b1[o]; sdb2[o] = sd_b2[o]; }
  __syncthreads();

  float a2[4][2];
#pragma unroll
  for (int nn = 0; nn < 4; nn++) { a2[nn][0] = 0.f; a2[nn][1] = 0.f; }
  for (int kk = 0; kk < 64; kk += 4) {
    float xr[4][4], wr[4][2];
#pragma unroll
    for (int nn = 0; nn < 4; nn++) ld4(xr[nn], &sX[(n0 + nn) * 64 + kk]);
#pragma unroll
    for (int t = 0; t < 4; t++) ld2(wr[t], &sW[(kk + t) * 64 + og * 2]);
#pragma unroll
    for (int t = 0; t < 4; t++)
#pragma unroll
      for (int nn = 0; nn < 4; nn++) {
        a2[nn][0] = fmaf(xr[nn][t], wr[t][0], a2[nn][0]);
        a2[nn][1] = fmaf(xr[nn][t], wr[t][1], a2[nn][1]);
      }
  }
#pragma unroll
  for (int nn = 0; nn < 4; nn++) {
    float2 v;
    v.x = fmaxf(a2[nn][0] + sb1[og * 2 + 0], 0.f);
    v.y = fmaxf(a2[nn][1] + sb1[og * 2 + 1], 0.f);
    *(float2*)&sH1[(n0 + nn) * 64 + og * 2] = v;
  }
  __syncthreads();
  cp_lds(sW, se_w2, 4096, tid);
  __syncthreads();

#pragma unroll
  for (int nn = 0; nn < 4; nn++) { a2[nn][0] = 0.f; a2[nn][1] = 0.f; }
  for (int kk = 0; kk < 64; kk += 4) {
    float xr[4][4], wr[4][2];
#pragma unroll
    for (int nn = 0; nn < 4; nn++) ld4(xr[nn], &sH1[(n0 + nn) * 64 + kk]);
#pragma unroll
    for (int t = 0; t < 4; t++) ld2(wr[t], &sW[(kk + t) * 64 + og * 2]);
#pragma unroll
    for (int t = 0; t < 4; t++)
#pragma unroll
      for (int nn = 0; nn < 4; nn++) {
        a2[nn][0] = fmaf(xr[nn][t], wr[t][0], a2[nn][0]);
        a2[nn][1] = fmaf(xr[nn][t], wr[t][1], a2[nn][1]);
      }
  }
#pragma unroll
  for (int nn = 0; nn < 4; nn++) {
    float2 v;
    v.x = fmaxf(a2[nn][0] + sb2[og * 2 + 0], 0.f);
    v.y = fmaxf(a2[nn][1] + sb2[og * 2 + 1], 0.f);
    *(float2*)&sX[(n0 + nn) * 64 + og * 2] = v;
    u16 h0h, h0l, h1h, h1l;
    split_bf16(v.x, h0h, h0l);
    split_bf16(v.y, h1h, h1l);
    const int off = (row0 + n0 + nn) * 64 + og * 2;
    *(ushort2*)&hwsH[off] = make_ushort2(h0h, h1h);
    *(ushort2*)&hwsL[off] = make_ushort2(h0l, h1l);
  }
  __syncthreads();

  float a4[4][4];
#pragma unroll
  for (int nn = 0; nn < 4; nn++)
#pragma unroll
    for (int oo = 0; oo < 4; oo++) a4[nn][oo] = 0.f;
  for (int c = 0; c < 2; c++) {
    cp_lds(sW, sd_w1 + c * 32 * 128, 4096, tid);
    __syncthreads();
    for (int kk = 0; kk < 32; kk += 4) {
      float xr[4][4], wr[4][4];
#pragma unroll
      for (int nn = 0; nn < 4; nn++) ld4(xr[nn], &sX[(n0 + nn) * 64 + c * 32 + kk]);
#pragma unroll
      for (int t = 0; t < 4; t++) ld4(wr[t], &sW[(kk + t) * 128 + og * 4]);
#pragma unroll
      for (int t = 0; t < 4; t++)
#pragma unroll
        for (int nn = 0; nn < 4; nn++)
#pragma unroll
          for (int oo = 0; oo < 4; oo++)
            a4[nn][oo] = fmaf(xr[nn][t], wr[t][oo], a4[nn][oo]);
    }
    __syncthreads();
  }
#pragma unroll
  for (int nn = 0; nn < 4; nn++) {
    float4 v;
    v.x = fmaxf(a4[nn][0] + sdb1[og * 4 + 0], 0.f);
    v.y = fmaxf(a4[nn][1] + sdb1[og * 4 + 1], 0.f);
    v.z = fmaxf(a4[nn][2] + sdb1[og * 4 + 2], 0.f);
    v.w = fmaxf(a4[nn][3] + sdb1[og * 4 + 3], 0.f);
    *(float4*)&sT[(n0 + nn) * 128 + og * 4] = v;
  }
  __syncthreads();

#pragma unroll
  for (int nn = 0; nn < 4; nn++)
#pragma unroll
    for (int oo = 0; oo < 4; oo++) a4[nn][oo] = 0.f;
  for (int c = 0; c < 4; c++) {
    cp_lds(sW, sd_w2 + c * 32 * 128, 4096, tid);
    __syncthreads();
    for (int kk = 0; kk < 32; kk += 4) {
      float xr[4][4], wr[4][4];
#pragma unroll
      for (int nn = 0; nn < 4; nn++) ld4(xr[nn], &sT[(n0 + nn) * 128 + c * 32 + kk]);
#pragma unroll
      for (int t = 0; t < 4; t++) ld4(wr[t], &sW[(kk + t) * 128 + og * 4]);
#pragma unroll
      for (int t = 0; t < 4; t++)
#pragma unroll
        for (int nn = 0; nn < 4; nn++)
#pragma unroll
          for (int oo = 0; oo < 4; oo++)
            a4[nn][oo] = fmaf(xr[nn][t], wr[t][oo], a4[nn][oo]);
    }
    __syncthreads();
  }
  float p[4];
#pragma unroll
  for (int oo = 0; oo < 4; oo++)
    p[oo] = a4[0][oo] + a4[1][oo] + a4[2][oo] + a4[3][oo] + 4.f * sdb2[og * 4 + oo];
  *(float4*)&sH1[lg * 128 + og * 4] = make_float4(p[0], p[1], p[2], p[3]);
  __syncthreads();
  if (tid < 128) {
    float ssum = 0.f;
#pragma unroll
    for (int g = 0; g < 8; g++) ssum += sH1[g * 128 + tid];
    atomicAdd(&out[b * 128 + tid], ssum * (1.0f / 64.0f));
  }
}

// ---------------------------------------------------------------------------
// MFMA layer: A-frags direct from global (fragment-linear blob, L2-resident),
// B-frags from XOR-swizzled LDS acts. No barriers inside.
// Act LDS layout: row j (stride RSG*8 u16), granule g stored at slot g^(j&7).
// ---------------------------------------------------------------------------
#define MFMA3(Ah, Al, Bh, Bl, a)                                        \
  a = __builtin_amdgcn_mfma_f32_16x16x32_bf16(Ah, Bh, a, 0, 0, 0);      \
  a = __builtin_amdgcn_mfma_f32_16x16x32_bf16(Al, Bh, a, 0, 0, 0);      \
  a = __builtin_amdgcn_mfma_f32_16x16x32_bf16(Ah, Bl, a, 0, 0, 0);

template<int MT, int NCHUNK, int RSG, int TILES>
__device__ __forceinline__ void run_layer_g(f32x4 (&acc)[MT][4],
    const u16* __restrict__ blobL, int OKhalf,
    const u16* __restrict__ sBH, const u16* __restrict__ sBL,
    int tg0, int quad, int l15) {
  const int lane = quad * 16 + l15;
#pragma unroll
  for (int c = 0; c < NCHUNK; ++c) {
    bf16x8 Ah[MT], Al[MT];
#pragma unroll
    for (int t = 0; t < MT; ++t) {
      const u16* p = blobL + ((c * TILES + tg0 + t) * 64 + lane) * 8;
      Ah[t] = *(const bf16x8*)p;
      Al[t] = *(const bf16x8*)(p + OKhalf);
    }
    const int slot = (4 * c + quad) ^ (l15 & 7);
    bf16x8 Bh[4], Bl[4];
#pragma unroll
    for (int s = 0; s < 4; ++s) {
      const int addr = (16 * s + l15) * (RSG * 8) + slot * 8;
      Bh[s] = *(const bf16x8*)&sBH[addr];
      Bl[s] = *(const bf16x8*)&sBL[addr];
    }
#pragma unroll
    for (int t = 0; t < MT; ++t)
#pragma unroll
      for (int s = 0; s < 4; ++s) {
        f32x4 a = acc[t][s];
        MFMA3(Ah[t], Al[t], Bh[s], Bl[s], a);
        acc[t][s] = a;
      }
  }
}

// relu(+bias) -> split -> swizzled LDS act store (ushort4 hi/lo).
template<int MT, int RSG>
__device__ __forceinline__ void store_acts_sw(const f32x4 (&acc)[MT][4], const float* bias,
                                              u16* dH, u16* dL, int o0, int quad, int l15) {
#pragma unroll
  for (int t = 0; t < MT; ++t) {
    const int ob = o0 + 16 * t + quad * 4;
    const int g = ob >> 3, e = ob & 7;
    const int slot = g ^ (l15 & 7);
#pragma unroll
    for (int s = 0; s < 4; ++s) {
      const int j = 16 * s + l15;
      u16 hv[4], lv[4];
#pragma unroll
      for (int r = 0; r < 4; ++r) {
        float x = acc[t][s][r];
        if (bias) x += bias[ob + r];
        x = fmaxf(x, 0.f);
        split_bf16(x, hv[r], lv[r]);
      }
      const int addr = j * (RSG * 8) + slot * 8 + e;
      *(ushort4*)&dH[addr] = make_ushort4(hv[0], hv[1], hv[2], hv[3]);
      *(ushort4*)&dL[addr] = make_ushort4(lv[0], lv[1], lv[2], lv[3]);
    }
  }
}

// ---------------------------------------------------------------------------
// Kernel B (MFMA): one block per (b,i). 52 KB LDS -> 3 blocks/CU. A-frags from
// global (L2), acts XOR-swizzled in LDS, 6 barriers total.
// ---------------------------------------------------------------------------
__global__ __launch_bounds__(TPB, 3) void pair_mfma_kernel(
    const u16* __restrict__ hwsH, const u16* __restrict__ hwsL,
    const u16* __restrict__ blob,
    const float* __restrict__ rc_w1, const float* __restrict__ rc_b1,
    const float* __restrict__ rc_b2, const float* __restrict__ rc_b3,
    const float* __restrict__ an_w1, const float* __restrict__ an_b1,
    const float* __restrict__ an_b2,
    float* __restrict__ out) {
  __shared__ __align__(16) u16 sActH[64 * 128];  // swizzled, RSG=16
  __shared__ __align__(16) u16 sActL[64 * 128];
  __shared__ __align__(16) u16 sAnH[64 * 64];    // swizzled, RSG=8
  __shared__ __align__(16) u16 sAnL[64 * 64];
  __shared__ float sHi[64], sDist[64];
  __shared__ float sBaseRc[128], sBaseAn[64], sW1d[128], sAnd[64];
  __shared__ float sB2[128], sB3[128], sAb2[128], sRed[128];

  const int tid = threadIdx.x;
  const int w = tid >> 6, lane = tid & 63;
  const int quad = lane >> 4, l15 = lane & 15;
  const int b = blockIdx.x >> 6, i = blockIdx.x & 63;
  const int o0 = w * 32;    // rc/an2 layers (O=128): tiles 2w, 2w+1
  const int o0a = w * 16;   // an1 (O=64): tile w

  // ---- init: stage h_j swizzled into sAct granules 0..7; constants
  {
    const float4* srcH = (const float4*)(hwsH + b * 4096);
    const float4* srcL = (const float4*)(hwsL + b * 4096);
    for (int idx = tid; idx < 512; idx += TPB) {
      const int row = idx >> 3, g = idx & 7;
      const int addr = row * 128 + (g ^ (row & 7)) * 8;
      *(float4*)&sActH[addr] = srcH[idx];
      *(float4*)&sActL[addr] = srcL[idx];
    }
  }
  if (tid < 64)
    sHi[tid] = b2f(hwsH[(b * 64 + i) * 64 + tid]) + b2f(hwsL[(b * 64 + i) * 64 + tid]);
  if (tid < 128) {
    sB2[tid] = rc_b2[tid]; sB3[tid] = rc_b3[tid]; sAb2[tid] = an_b2[tid];
    sW1d[tid] = rc_w1[128 * 128 + tid];
  } else if (tid < 192) {
    sAnd[tid - 128] = an_w1[128 * 64 + (tid - 128)];
  }
  __syncthreads();
  if (tid < 128) {
    float acc = rc_b1[tid];
    for (int k = 0; k < 64; ++k) acc = fmaf(sHi[k], rc_w1[k * 128 + tid], acc);
    sBaseRc[tid] = acc;
  } else if (tid < 192) {
    const int o = tid - 128;
    float acc = an_b1[o];
    for (int k = 0; k < 64; ++k) acc = fmaf(sHi[k], an_w1[k * 64 + o], acc);
    sBaseAn[o] = acc;
  } else {
    const int j = tid - 192;
    const int base = j * 128 + (j & 7) * 8;  // granule 0 slot
    const float h0 = b2f(sActH[base + 0]) + b2f(sActL[base + 0]);
    const float h1 = b2f(sActH[base + 1]) + b2f(sActL[base + 1]);
    const float d0 = sHi[0] - h0, d1 = sHi[1] - h1;
    sDist[j] = d0 * d0 + d1 * d1;
  }
  __syncthreads();

  // ---- rc-L1 + an-L1 fused (shared B = h_j), K=64, no inner barriers
  f32x4 accR[2][4];
  f32x4 accN[1][4];
#pragma unroll
  for (int t = 0; t < 2; ++t)
#pragma unroll
    for (int s = 0; s < 4; ++s) {
      const float dj = sDist[16 * s + l15];
      f32x4 a;
#pragma unroll
      for (int r = 0; r < 4; ++r) {
        const int o = o0 + 16 * t + quad * 4 + r;
        a[r] = sBaseRc[o] + dj * sW1d[o];
      }
      accR[t][s] = a;
    }
#pragma unroll
  for (int s = 0; s < 4; ++s) {
    const float dj = sDist[16 * s + l15];
    f32x4 a;
#pragma unroll
    for (int r = 0; r < 4; ++r) {
      const int o = o0a + quad * 4 + r;
      a[r] = sBaseAn[o] + dj * sAnd[o];
    }
    accN[0][s] = a;
  }
  {
    const int lane64 = quad * 16 + l15;
#pragma unroll
    for (int c = 0; c < 2; ++c) {
      bf16x8 Ah[2], Al[2], AhN, AlN;
#pragma unroll
      for (int t = 0; t < 2; ++t) {
        const u16* p = blob + RC1F + ((c * 8 + 2 * w + t) * 64 + lane64) * 8;
        Ah[t] = *(const bf16x8*)p;
        Al[t] = *(const bf16x8*)(p + 8192);
      }
      {
        const u16* p = blob + AN1F + ((c * 4 + w) * 64 + lane64) * 8;
        AhN = *(const bf16x8*)p;
        AlN = *(const bf16x8*)(p + 4096);
      }
      const int slot = (4 * c + quad) ^ (l15 & 7);
      bf16x8 Bh[4], Bl[4];
#pragma unroll
      for (int s = 0; s < 4; ++s) {
        const int addr = (16 * s + l15) * 128 + slot * 8;
        Bh[s] = *(const bf16x8*)&sActH[addr];
        Bl[s] = *(const bf16x8*)&sActL[addr];
      }
#pragma unroll
      for (int s = 0; s < 4; ++s) {
#pragma unroll
        for (int t = 0; t < 2; ++t) {
          f32x4 a = accR[t][s];
          MFMA3(Ah[t], Al[t], Bh[s], Bl[s], a);
          accR[t][s] = a;
        }
        f32x4 a = accN[0][s];
        MFMA3(AhN, AlN, Bh[s], Bl[s], a);
        accN[0][s] = a;
      }
    }
  }
  __syncthreads();  // h fully consumed
  store_acts_sw<2, 16>(accR, nullptr, sActH, sActL, o0, quad, l15);  // rc1 acts
  store_acts_sw<1, 8>(accN, nullptr, sAnH, sAnL, o0a, quad, l15);    // an1 acts
  __syncthreads();

  // ---- an-L2 -> att in regs (reads sAn), then rc-L2 (reads sAct): no barrier between
  f32x4 accT[2][4];
#pragma unroll
  for (int t = 0; t < 2; ++t)
#pragma unroll
    for (int s = 0; s < 4; ++s) accT[t][s] = (f32x4){0.f, 0.f, 0.f, 0.f};
  run_layer_g<2, 2, 8, 8>(accT, blob + AN2F, 8192, sAnH, sAnL, 2 * w, quad, l15);
  float att[2][4][4];
#pragma unroll
  for (int t = 0; t < 2; ++t)
#pragma unroll
    for (int s = 0; s < 4; ++s)
#pragma unroll
      for (int r = 0; r < 4; ++r) {
        const float z = accT[t][s][r] + sAb2[o0 + 16 * t + quad * 4 + r];
        att[t][s][r] = 1.0f / (1.0f + __expf(-z));
      }

#pragma unroll
  for (int t = 0; t < 2; ++t)
#pragma unroll
    for (int s = 0; s < 4; ++s) accR[t][s] = (f32x4){0.f, 0.f, 0.f, 0.f};
  run_layer_g<2, 4, 16, 8>(accR, blob + RC2F, 16384, sActH, sActL, 2 * w, quad, l15);
  __syncthreads();  // sAct reads done
  store_acts_sw<2, 16>(accR, sB2, sActH, sActL, o0, quad, l15);
  __syncthreads();

  // ---- rc-L3 + rel*att + reduce over j
#pragma unroll
  for (int t = 0; t < 2; ++t)
#pragma unroll
    for (int s = 0; s < 4; ++s) accR[t][s] = (f32x4){0.f, 0.f, 0.f, 0.f};
  run_layer_g<2, 4, 16, 8>(accR, blob + RC3F, 16384, sActH, sActL, 2 * w, quad, l15);
  float ps[2][4] = {{0.f, 0.f, 0.f, 0.f}, {0.f, 0.f, 0.f, 0.f}};
#pragma unroll
  for (int t = 0; t < 2; ++t)
#pragma unroll
    for (int s = 0; s < 4; ++s)
#pragma unroll
      for (int r = 0; r < 4; ++r) {
        const float rel = fmaxf(accR[t][s][r] + sB3[o0 + 16 * t + quad * 4 + r], 0.f);
        ps[t][r] = fmaf(rel, att[t][s][r], ps[t][r]);
      }
#pragma unroll
  for (int t = 0; t < 2; ++t)
#pragma unroll
    for (int r = 0; r < 4; ++r) {
      float v = ps[t][r];
      v += __shfl_xor(v, 1, 64);
      v += __shfl_xor(v, 2, 64);
      v += __shfl_xor(v, 4, 64);
      v += __shfl_xor(v, 8, 64);
      ps[t][r] = v;
    }
  if (l15 == 0) {
#pragma unroll
    for (int t = 0; t < 2; ++t)
#pragma unroll
      for (int r = 0; r < 4; ++r)
        sRed[o0 + 16 * t + quad * 4 + r] = ps[t][r];
  }
  __syncthreads();
  if (tid < 128)
    atomicAdd(&out[b * 128 + tid], sRed[tid] * (1.0f / 4096.0f));
}

// ---------------------------------------------------------------------------
// Fallback pair kernel (R1, VALU): used only if ws_size < WS_NEED.
// ---------------------------------------------------------------------------
__global__ __launch_bounds__(TPB, 3) void pair_kernel(
    const u16* __restrict__ hwsH, const u16* __restrict__ hwsL,
    const float* __restrict__ rc_w1, const float* __restrict__ rc_b1,
    const float* __restrict__ rc_w2, const float* __restrict__ rc_b2,
    const float* __restrict__ rc_w3, const float* __restrict__ rc_b3,
    const float* __restrict__ an_w1, const float* __restrict__ an_b1,
    const float* __restrict__ an_w2, const float* __restrict__ an_b2,
    float* __restrict__ out) {
  __shared__ __align__(16) float sHj[2048];
  __shared__ __align__(16) float sA[4096];
  __shared__ __align__(16) float sAn1[2048];
  __shared__ __align__(16) float sW[4096];
  __shared__ __align__(16) float sHi[64];
  __shared__ __align__(16) float sBaseRc[128];
  __shared__ __align__(16) float sBaseAn[64];
  __shared__ float sDist[32];
  __shared__ __align__(16) float sW1d[128], sAn1d[64], sB2[128], sB3[128], sAb2[128];

  const int tid = threadIdx.x;
  const int jg = tid >> 5;
  const int og = tid & 31;
  const int blk = blockIdx.x;
  const int jh = blk & 1;
  const int i = (blk >> 1) & 63;
  const int b = blk >> 7;
  const int j0 = jg * 4;

  for (int idx = tid; idx < 2048; idx += TPB) {
    const int off = (b * 64 + jh * 32) * 64 + idx;
    sHj[idx] = b2f(hwsH[off]) + b2f(hwsL[off]);
  }
  if (tid < 64) sHi[tid] = b2f(hwsH[(b * 64 + i) * 64 + tid]) + b2f(hwsL[(b * 64 + i) * 64 + tid]);
  if (tid < 128) {
    sW1d[tid] = rc_w1[128 * 128 + tid];
    sB2[tid] = rc_b2[tid]; sB3[tid] = rc_b3[tid]; sAb2[tid] = an_b2[tid];
  } else if (tid < 192) {
    sAn1d[tid - 128] = an_w1[128 * 64 + (tid - 128)];
  }
  __syncthreads();
  if (tid < 128) {
    float acc = rc_b1[tid];
    for (int k = 0; k < 64; k++) acc = fmaf(sHi[k], rc_w1[k * 128 + tid], acc);
    sBaseRc[tid] = acc;
  } else if (tid < 192) {
    const int o = tid - 128;
    float acc = an_b1[o];
    for (int k = 0; k < 64; k++) acc = fmaf(sHi[k], an_w1[k * 64 + o], acc);
    sBaseAn[o] = acc;
  } else if (tid < 224) {
    const int j = tid - 192;
    const float d0 = sHi[0] - sHj[j * 64 + 0];
    const float d1 = sHi[1] - sHj[j * 64 + 1];
    sDist[j] = d0 * d0 + d1 * d1;
  }
  __syncthreads();

  float aR[4][4], aA[4][2];
#pragma unroll
  for (int jj = 0; jj < 4; jj++) {
#pragma unroll
    for (int oo = 0; oo < 4; oo++) aR[jj][oo] = 0.f;
    aA[jj][0] = 0.f; aA[jj][1] = 0.f;
  }
  for (int c = 0; c < 4; c++) {
    cp_lds(sW, rc_w1 + (64 + c * 16) * 128, 2048, tid);
    cp_lds(sW + 2048, an_w1 + (64 + c * 16) * 64, 1024, tid);
    __syncthreads();
    for (int kk = 0; kk < 16; kk += 4) {
      float xr[4][4], wr[4][4], wa[4][2];
#pragma unroll
      for (int jj = 0; jj < 4; jj++) ld4(xr[jj], &sHj[(j0 + jj) * 64 + c * 16 + kk]);
#pragma unroll
      for (int t = 0; t < 4; t++) ld4(wr[t], &sW[(kk + t) * 128 + og * 4]);
#pragma unroll
      for (int t = 0; t < 4; t++) ld2(wa[t], &sW[2048 + (kk + t) * 64 + og * 2]);
#pragma unroll
      for (int t = 0; t < 4; t++)
#pragma unroll
        for (int jj = 0; jj < 4; jj++) {
#pragma unroll
          for (int oo = 0; oo < 4; oo++)
            aR[jj][oo] = fmaf(xr[jj][t], wr[t][oo], aR[jj][oo]);
          aA[jj][0] = fmaf(xr[jj][t], wa[t][0], aA[jj][0]);
          aA[jj][1] = fmaf(xr[jj][t], wa[t][1], aA[jj][1]);
        }
    }
    __syncthreads();
  }
#pragma unroll
  for (int jj = 0; jj < 4; jj++) {
    const int j = j0 + jj;
    const float dj = sDist[j];
    float4 v;
    v.x = fmaxf(aR[jj][0] + sBaseRc[og * 4 + 0] + dj * sW1d[og * 4 + 0], 0.f);
    v.y = fmaxf(aR[jj][1] + sBaseRc[og * 4 + 1] + dj * sW1d[og * 4 + 1], 0.f);
    v.z = fmaxf(aR[jj][2] + sBaseRc[og * 4 + 2] + dj * sW1d[og * 4 + 2], 0.f);
    v.w = fmaxf(aR[jj][3] + sBaseRc[og * 4 + 3] + dj * sW1d[og * 4 + 3], 0.f);
    *(float4*)&sA[j * 128 + og * 4] = v;
    float2 u;
    u.x = fmaxf(aA[jj][0] + sBaseAn[og * 2 + 0] + dj * sAn1d[og * 2 + 0], 0.f);
    u.y = fmaxf(aA[jj][1] + sBaseAn[og * 2 + 1] + dj * sAn1d[og * 2 + 1], 0.f);
    *(float2*)&sAn1[j * 64 + og * 2] = u;
  }
  __syncthreads();

  float aT[4][4];
#pragma unroll
  for (int jj = 0; jj < 4; jj++)
#pragma unroll
    for (int oo = 0; oo < 4; oo++) aT[jj][oo] = 0.f;
  for (int c = 0; c < 2; c++) {
    cp_lds(sW, an_w2 + c * 32 * 128, 4096, tid);
    __syncthreads();
    for (int kk = 0; kk < 32; kk += 4) {
      float xr[4][4], wr[4][4];
#pragma unroll
      for (int jj = 0; jj < 4; jj++) ld4(xr[jj], &sAn1[(j0 + jj) * 64 + c * 32 + kk]);
#pragma unroll
      for (int t = 0; t < 4; t++) ld4(wr[t], &sW[(kk + t) * 128 + og * 4]);
#pragma unroll
      for (int t = 0; t < 4; t++)
#pragma unroll
        for (int jj = 0; jj < 4; jj++)
#pragma unroll
          for (int oo = 0; oo < 4; oo++)
            aT[jj][oo] = fmaf(xr[jj][t], wr[t][oo], aT[jj][oo]);
    }
    __syncthreads();
  }
  float att[4][4];
#pragma unroll
  for (int jj = 0; jj < 4; jj++)
#pragma unroll
    for (int oo = 0; oo < 4; oo++) {
      const float z = aT[jj][oo] + sAb2[og * 4 + oo];
      att[jj][oo] = 1.0f / (1.0f + __expf(-z));
    }

#pragma unroll
  for (int jj = 0; jj < 4; jj++)
#pragma unroll
    for (int oo = 0; oo < 4; oo++) aT[jj][oo] = 0.f;
  for (int c = 0; c < 4; c++) {
    cp_lds(sW, rc_w2 + c * 32 * 128, 4096, tid);
    __syncthreads();
    for (int kk = 0; kk < 32; kk += 4) {
      float xr[4][4], wr[4][4];
#pragma unroll
      for (int jj = 0; jj < 4; jj++) ld4(xr[jj], &sA[(j0 + jj) * 128 + c * 32 + kk]);
#pragma unroll
      for (int t = 0; t < 4; t++) ld4(wr[t], &sW[(kk + t) * 128 + og * 4]);
#pragma unroll
      for (int t = 0; t < 4; t++)
#pragma unroll
        for (int jj = 0; jj < 4; jj++)
#pragma unroll
          for (int oo = 0; oo < 4; oo++)
            aT[jj][oo] = fmaf(xr[jj][t], wr[t][oo], aT[jj][oo]);
    }
    __syncthreads();
  }
#pragma unroll
  for (int jj = 0; jj < 4; jj++) {
    float4 v;
    v.x = fmaxf(aT[jj][0] + sB2[og * 4 + 0], 0.f);
    v.y = fmaxf(aT[jj][1] + sB2[og * 4 + 1], 0.f);
    v.z = fmaxf(aT[jj][2] + sB2[og * 4 + 2], 0.f);
    v.w = fmaxf(aT[jj][3] + sB2[og * 4 + 3], 0.f);
    *(float4*)&sA[(j0 + jj) * 128 + og * 4] = v;
  }
  __syncthreads();

#pragma unroll
  for (int jj = 0; jj < 4; jj++)
#pragma unroll
    for (int oo = 0; oo < 4; oo++) aT[jj][oo] = 0.f;
  for (int c = 0; c < 4; c++) {
    cp_lds(sW, rc_w3 + c * 32 * 128, 4096, tid);
    __syncthreads();
    for (int kk = 0; kk < 32; kk += 4) {
      float xr[4][4], wr[4][4];
#pragma unroll
      for (int jj = 0; jj < 4; jj++) ld4(xr[jj], &sA[(j0 + jj) * 128 + c * 32 + kk]);
#pragma unroll
      for (int t = 0; t < 4; t++) ld4(wr[t], &sW[(kk + t) * 128 + og * 4]);
#pragma unroll
      for (int t = 0; t < 4; t++)
#pragma unroll
        for (int jj = 0; jj < 4; jj++)
#pragma unroll
          for (int oo = 0; oo < 4; oo++)
            aT[jj][oo] = fmaf(xr[jj][t], wr[t][oo], aT[jj][oo]);
    }
    __syncthreads();
  }
  float p[4] = {0.f, 0.f, 0.f, 0.f};
#pragma unroll
  for (int jj = 0; jj < 4; jj++)
#pragma unroll
    for (int oo = 0; oo < 4; oo++) {
      const float rel = fmaxf(aT[jj][oo] + sB3[og * 4 + oo], 0.f);
      p[oo] = fmaf(rel, att[jj][oo], p[oo]);
    }
  *(float4*)&sAn1[jg * 128 + og * 4] = make_float4(p[0], p[1], p[2], p[3]);
  __syncthreads();
  if (tid < 128) {
    float ssum = 0.f;
#pragma unroll
    for (int g = 0; g < 8; g++) ssum += sAn1[g * 128 + tid];
    atomicAdd(&out[b * 128 + tid], ssum * (1.0f / 4096.0f));
  }
}

extern "C" void kernel_launch(void* const* d_in, const int* in_sizes, int n_in,
                              void* d_out, int out_size, void* d_ws, size_t ws_size,
                              hipStream_t stream) {
  const float* s     = (const float*)d_in[0];
  const float* se_w1 = (const float*)d_in[1];
  const float* se_b1 = (const float*)d_in[2];
  const float* se_w2 = (const float*)d_in[3];
  const float* se_b2 = (const float*)d_in[4];
  const float* sd_w1 = (const float*)d_in[5];
  const float* sd_b1 = (const float*)d_in[6];
  const float* sd_w2 = (const float*)d_in[7];
  const float* sd_b2 = (const float*)d_in[8];
  const float* rc_w1 = (const float*)d_in[9];
  const float* rc_b1 = (const float*)d_in[10];
  const float* rc_w2 = (const float*)d_in[11];
  const float* rc_b2 = (const float*)d_in[12];
  const float* rc_w3 = (const float*)d_in[13];
  const float* rc_b3 = (const float*)d_in[14];
  const float* an_w1 = (const float*)d_in[15];
  const float* an_b1 = (const float*)d_in[16];
  const float* an_w2 = (const float*)d_in[17];
  const float* an_b2 = (const float*)d_in[18];
  float* out = (float*)d_out;
  u16* hwsH = (u16*)d_ws;
  u16* hwsL = hwsH + HWSL_U16;
  u16* blob = hwsH + BLOB_U16;

  hipMemsetAsync(d_out, 0, (size_t)out_size * sizeof(float), stream);
  enc_self_kernel<<<256, TPB, 0, stream>>>(s, se_w1, se_b1, se_w2, se_b2,
                                           sd_w1, sd_b1, sd_w2, sd_b2, hwsH, hwsL, out);
  if (ws_size >= WS_NEED) {
    prep_weights<<<208, TPB, 0, stream>>>(rc_w1, rc_w2, rc_w3, an_w1, an_w2, blob);
    pair_mfma_kernel<<<8192, TPB, 0, stream>>>(hwsH, hwsL, blob,
                                               rc_w1, rc_b1, rc_b2, rc_b3,
                                               an_w1, an_b1, an_b2, out);
  } else {
    pair_kernel<<<16384, TPB, 0, stream>>>(hwsH, hwsL, rc_w1, rc_b1, rc_w2, rc_b2,
                                           rc_w3, rc_b3, an_w1, an_b1, an_w2, an_b2, out);
  }
}

// Round 4
// 263.096 us; speedup vs baseline: 3.4019x; 1.0672x over previous
//
#include <hip/hip_runtime.h>
#include <math.h>

#define TPB 256

typedef unsigned short u16;
typedef __attribute__((ext_vector_type(8))) short bf16x8;
typedef __attribute__((ext_vector_type(4))) float f32x4;

// ---------------- ws layout (u16 element offsets from d_ws) ----------------
#define HWSL_U16 524288
#define BLOB_U16 1048576
// blob: fragment-linear A images. Per layer: hi[OK] then lo[OK].
#define RC1F 0        // O=128,K=64  T=8  OK=8192
#define AN1F 16384    // O=64, K=64  T=4  OK=4096
#define AN2F 24576    // O=128,K=64  T=8  OK=8192
#define RC2F 40960    // O=128,K=128 T=8  OK=16384
#define RC3F 73728    // O=128,K=128 T=8  OK=16384
#define BLOB_TOT 106496
#define WS_NEED ((size_t)(BLOB_U16 + BLOB_TOT) * 2)

__device__ __forceinline__ float b2f(u16 h) {
  return __uint_as_float(((unsigned)h) << 16);
}
// truncation split: x ~= hi + lo with |err| ~ 2^-17 |x|
__device__ __forceinline__ void split_bf16(float x, u16& hi, u16& lo) {
  unsigned u = __float_as_uint(x);
  hi = (u16)(u >> 16);
  float hif = __uint_as_float(u & 0xFFFF0000u);
  lo = (u16)(__float_as_uint(x - hif) >> 16);
}
// round-to-nearest-even f32 -> bf16
__device__ __forceinline__ u16 f2bf_rne(float x) {
  unsigned u = __float_as_uint(x);
  return (u16)((u + 0x7FFFu + ((u >> 16) & 1u)) >> 16);
}

__device__ __forceinline__ void cp_lds(float* dst, const float* src, int nfloats, int tid) {
  const float4* s4 = (const float4*)src;
  float4* d4 = (float4*)dst;
  const int n4 = nfloats >> 2;
  for (int i = tid; i < n4; i += TPB) d4[i] = s4[i];
}
__device__ __forceinline__ void ld4(float r[4], const float* p) {
  float4 v = *(const float4*)p;
  r[0] = v.x; r[1] = v.y; r[2] = v.z; r[3] = v.w;
}
__device__ __forceinline__ void ld2(float r[2], const float* p) {
  float2 v = *(const float2*)p;
  r[0] = v.x; r[1] = v.y;
}

// ---------------------------------------------------------------------------
// Kernel A: fused encoder (blocks 0..127, one per b, all weights LDS-resident,
// writes self_dyn mean DIRECTLY to out — no memset/atomics needed) + weight
// prep role (blocks 128..335: split+transpose pair weights into blob).
// ---------------------------------------------------------------------------
__global__ __launch_bounds__(TPB, 1) void enc_prep_kernel(
    const float* __restrict__ s_in,
    const float* __restrict__ se_w1, const float* __restrict__ se_b1,
    const float* __restrict__ se_w2, const float* __restrict__ se_b2,
    const float* __restrict__ sd_w1, const float* __restrict__ sd_b1,
    const float* __restrict__ sd_w2, const float* __restrict__ sd_b2,
    const float* __restrict__ rc_w1, const float* __restrict__ rc_w2,
    const float* __restrict__ rc_w3, const float* __restrict__ an_w1,
    const float* __restrict__ an_w2,
    u16* __restrict__ hwsH, u16* __restrict__ hwsL, u16* __restrict__ blob,
    float* __restrict__ out) {
  if (blockIdx.x >= 128) {
    // ---- prep role: fragment-linear bf16 hi/lo weight images
    int idx = (int)(blockIdx.x - 128) * TPB + threadIdx.x;
    if (idx >= 53248) return;
    int r, base, OK, T; const float* W; int Wld; int krow0;
    if (idx < 8192)       { r = idx;         base = RC1F; OK = 8192;  T = 8; W = rc_w1; Wld = 128; krow0 = 64; }
    else if (idx < 12288) { r = idx - 8192;  base = AN1F; OK = 4096;  T = 4; W = an_w1; Wld = 64;  krow0 = 64; }
    else if (idx < 20480) { r = idx - 12288; base = AN2F; OK = 8192;  T = 8; W = an_w2; Wld = 128; krow0 = 0;  }
    else if (idx < 36864) { r = idx - 20480; base = RC2F; OK = 16384; T = 8; W = rc_w2; Wld = 128; krow0 = 0;  }
    else                  { r = idx - 36864; base = RC3F; OK = 16384; T = 8; W = rc_w3; Wld = 128; krow0 = 0;  }
    const int u = r & 7;
    const int lane = (r >> 3) & 63;
    const int ct = r >> 9;
    const int c = (T == 8) ? (ct >> 3) : (ct >> 2);
    const int tg = (T == 8) ? (ct & 7) : (ct & 3);
    const int o = tg * 16 + (lane & 15);
    const int k = c * 32 + (lane >> 4) * 8 + u;
    const float x = W[(krow0 + k) * Wld + o];
    u16 hi, lo; split_bf16(x, hi, lo);
    blob[base + r] = hi;
    blob[base + OK + r] = lo;
    return;
  }

  // ---- encoder role: one block per b, 64 rows in two 32-row halves.
  __shared__ __align__(16) float sWsd1[8192];   // sd_w1 (32 KB)
  __shared__ __align__(16) float sWsd2[16384];  // sd_w2 (64 KB)
  __shared__ __align__(16) float sWse[8192];    // se_w1 @0, se_w2 @4096; later sT alias
  __shared__ __align__(16) float sX[4096];      // 64 x 64: s rows -> h rows
  __shared__ __align__(16) float sH1[2048];     // 32 x 64 scratch
  __shared__ float sb1[64], sb2[64], sdb1[128], sdb2[128];

  const int tid = threadIdx.x;
  const int lg = tid >> 5;   // 0..7 row group
  const int og = tid & 31;
  const int b = blockIdx.x;

  cp_lds(sWse, se_w1, 4096, tid);
  cp_lds(sWse + 4096, se_w2, 4096, tid);
  cp_lds(sWsd1, sd_w1, 8192, tid);
  cp_lds(sWsd2, sd_w2, 16384, tid);
  cp_lds(sX, s_in + b * 4096, 4096, tid);
  if (tid < 64) { sb1[tid] = se_b1[tid]; sb2[tid] = se_b2[tid]; }
  else if (tid < 192) { const int o = tid - 64; sdb1[o] = sd_b1[o]; sdb2[o] = sd_b2[o]; }
  __syncthreads();

  // ---- state encoder, two 32-row halves
  for (int p = 0; p < 2; ++p) {
    const int r0 = p * 32 + lg * 4;   // global row in sX
    const int h0 = lg * 4;            // row in sH1
    // L1
    float a2[4][2];
#pragma unroll
    for (int nn = 0; nn < 4; nn++) { a2[nn][0] = 0.f; a2[nn][1] = 0.f; }
    for (int kk = 0; kk < 64; kk += 4) {
      float xr[4][4], wr[4][2];
#pragma unroll
      for (int nn = 0; nn < 4; nn++) ld4(xr[nn], &sX[(r0 + nn) * 64 + kk]);
#pragma unroll
      for (int t = 0; t < 4; t++) ld2(wr[t], &sWse[(kk + t) * 64 + og * 2]);
#pragma unroll
      for (int t = 0; t < 4; t++)
#pragma unroll
        for (int nn = 0; nn < 4; nn++) {
          a2[nn][0] = fmaf(xr[nn][t], wr[t][0], a2[nn][0]);
          a2[nn][1] = fmaf(xr[nn][t], wr[t][1], a2[nn][1]);
        }
    }
#pragma unroll
    for (int nn = 0; nn < 4; nn++) {
      float2 v;
      v.x = fmaxf(a2[nn][0] + sb1[og * 2 + 0], 0.f);
      v.y = fmaxf(a2[nn][1] + sb1[og * 2 + 1], 0.f);
      *(float2*)&sH1[(h0 + nn) * 64 + og * 2] = v;
    }
    __syncthreads();
    // L2 -> h (overwrite sX rows) + hws hi/lo
#pragma unroll
    for (int nn = 0; nn < 4; nn++) { a2[nn][0] = 0.f; a2[nn][1] = 0.f; }
    for (int kk = 0; kk < 64; kk += 4) {
      float xr[4][4], wr[4][2];
#pragma unroll
      for (int nn = 0; nn < 4; nn++) ld4(xr[nn], &sH1[(h0 + nn) * 64 + kk]);
#pragma unroll
      for (int t = 0; t < 4; t++) ld2(wr[t], &sWse[4096 + (kk + t) * 64 + og * 2]);
#pragma unroll
      for (int t = 0; t < 4; t++)
#pragma unroll
        for (int nn = 0; nn < 4; nn++) {
          a2[nn][0] = fmaf(xr[nn][t], wr[t][0], a2[nn][0]);
          a2[nn][1] = fmaf(xr[nn][t], wr[t][1], a2[nn][1]);
        }
    }
#pragma unroll
    for (int nn = 0; nn < 4; nn++) {
      float2 v;
      v.x = fmaxf(a2[nn][0] + sb2[og * 2 + 0], 0.f);
      v.y = fmaxf(a2[nn][1] + sb2[og * 2 + 1], 0.f);
      *(float2*)&sX[(r0 + nn) * 64 + og * 2] = v;
      u16 h0h, h0l, h1h, h1l;
      split_bf16(v.x, h0h, h0l);
      split_bf16(v.y, h1h, h1l);
      const int off = (b * 64 + r0 + nn) * 64 + og * 2;
      *(ushort2*)&hwsH[off] = make_ushort2(h0h, h1h);
      *(ushort2*)&hwsL[off] = make_ushort2(h0l, h1l);
    }
    __syncthreads();
  }

  // ---- self_dyn, two 32-row halves; sT aliases sWse (se weights consumed)
  float* sT = sWse;  // 32 x 128
  float osum = 0.f;
  for (int p = 0; p < 2; ++p) {
    const int r0 = p * 32 + lg * 4;
    float a4[4][4];
#pragma unroll
    for (int nn = 0; nn < 4; nn++)
#pragma unroll
      for (int oo = 0; oo < 4; oo++) a4[nn][oo] = 0.f;
    for (int kk = 0; kk < 64; kk += 4) {
      float xr[4][4], wr[4][4];
#pragma unroll
      for (int nn = 0; nn < 4; nn++) ld4(xr[nn], &sX[(r0 + nn) * 64 + kk]);
#pragma unroll
      for (int t = 0; t < 4; t++) ld4(wr[t], &sWsd1[(kk + t) * 128 + og * 4]);
#pragma unroll
      for (int t = 0; t < 4; t++)
#pragma unroll
        for (int nn = 0; nn < 4; nn++)
#pragma unroll
          for (int oo = 0; oo < 4; oo++)
            a4[nn][oo] = fmaf(xr[nn][t], wr[t][oo], a4[nn][oo]);
    }
#pragma unroll
    for (int nn = 0; nn < 4; nn++) {
      float4 v;
      v.x = fmaxf(a4[nn][0] + sdb1[og * 4 + 0], 0.f);
      v.y = fmaxf(a4[nn][1] + sdb1[og * 4 + 1], 0.f);
      v.z = fmaxf(a4[nn][2] + sdb1[og * 4 + 2], 0.f);
      v.w = fmaxf(a4[nn][3] + sdb1[og * 4 + 3], 0.f);
      *(float4*)&sT[(lg * 4 + nn) * 128 + og * 4] = v;
    }
    __syncthreads();
#pragma unroll
    for (int nn = 0; nn < 4; nn++)
#pragma unroll
      for (int oo = 0; oo < 4; oo++) a4[nn][oo] = 0.f;
    for (int kk = 0; kk < 128; kk += 4) {
      float xr[4][4], wr[4][4];
#pragma unroll
      for (int nn = 0; nn < 4; nn++) ld4(xr[nn], &sT[(lg * 4 + nn) * 128 + kk]);
#pragma unroll
      for (int t = 0; t < 4; t++) ld4(wr[t], &sWsd2[(kk + t) * 128 + og * 4]);
#pragma unroll
      for (int t = 0; t < 4; t++)
#pragma unroll
        for (int nn = 0; nn < 4; nn++)
#pragma unroll
          for (int oo = 0; oo < 4; oo++)
            a4[nn][oo] = fmaf(xr[nn][t], wr[t][oo], a4[nn][oo]);
    }
    float pr[4];
#pragma unroll
    for (int oo = 0; oo < 4; oo++)
      pr[oo] = a4[0][oo] + a4[1][oo] + a4[2][oo] + a4[3][oo] + 4.f * sdb2[og * 4 + oo];
    *(float4*)&sH1[lg * 128 + og * 4] = make_float4(pr[0], pr[1], pr[2], pr[3]);
    __syncthreads();
    if (tid < 128) {
      float ss = 0.f;
#pragma unroll
      for (int g = 0; g < 8; g++) ss += sH1[g * 128 + tid];
      osum += ss;
    }
    __syncthreads();  // before sT/sH1 reuse
  }
  if (tid < 128) out[b * 128 + tid] = osum * (1.0f / 64.0f);
}

// ---------------------------------------------------------------------------
// MFMA layer (2-term: weights split hi/lo, B single bf16). A-frags direct from
// global blob; B from XOR-swizzled LDS. No barriers inside.
// ---------------------------------------------------------------------------
template<int MT, int NCHUNK, int RSG, int TILES>
__device__ __forceinline__ void run_layer2(f32x4 (&acc)[MT][4],
    const u16* __restrict__ blobL, int OK,
    const u16* __restrict__ sB, int tg0, int quad, int l15) {
  const int lane = quad * 16 + l15;
#pragma unroll
  for (int c = 0; c < NCHUNK; ++c) {
    bf16x8 Ah[MT], Al[MT];
#pragma unroll
    for (int t = 0; t < MT; ++t) {
      const u16* p = blobL + ((c * TILES + tg0 + t) * 64 + lane) * 8;
      Ah[t] = *(const bf16x8*)p;
      Al[t] = *(const bf16x8*)(p + OK);
    }
    const int slot = (4 * c + quad) ^ (l15 & 7);
    bf16x8 Bh[4];
#pragma unroll
    for (int s = 0; s < 4; ++s)
      Bh[s] = *(const bf16x8*)&sB[(16 * s + l15) * (RSG * 8) + slot * 8];
#pragma unroll
    for (int t = 0; t < MT; ++t)
#pragma unroll
      for (int s = 0; s < 4; ++s) {
        f32x4 a = acc[t][s];
        a = __builtin_amdgcn_mfma_f32_16x16x32_bf16(Ah[t], Bh[s], a, 0, 0, 0);
        a = __builtin_amdgcn_mfma_f32_16x16x32_bf16(Al[t], Bh[s], a, 0, 0, 0);
        acc[t][s] = a;
      }
  }
}

// relu(+bias) -> RNE bf16 -> swizzled LDS store (ushort4).
template<int MT, int RSG>
__device__ __forceinline__ void store_acts_rne(const f32x4 (&acc)[MT][4], const float* bias,
                                               u16* dst, int o0, int quad, int l15) {
#pragma unroll
  for (int t = 0; t < MT; ++t) {
    const int ob = o0 + 16 * t + quad * 4;
    const int slot = (ob >> 3) ^ (l15 & 7);
    const int e = ob & 7;
#pragma unroll
    for (int s = 0; s < 4; ++s) {
      const int j = 16 * s + l15;
      u16 v[4];
#pragma unroll
      for (int r = 0; r < 4; ++r) {
        float x = acc[t][s][r];
        if (bias) x += bias[ob + r];
        v[r] = f2bf_rne(fmaxf(x, 0.f));
      }
      *(ushort4*)&dst[j * (RSG * 8) + slot * 8 + e] = make_ushort4(v[0], v[1], v[2], v[3]);
    }
  }
}

// ---------------------------------------------------------------------------
// Kernel B (MFMA): one block per (b,i). ~28 KB LDS -> 4 blocks/CU.
// Layer-1 B (=h) kept split hi/lo (3-term) packed in sActH slots 0..7 / 8..15;
// all later layers use RNE-bf16 acts (2-term).
// ---------------------------------------------------------------------------
__global__ __launch_bounds__(TPB, 4) void pair_mfma_kernel(
    const u16* __restrict__ hwsH, const u16* __restrict__ hwsL,
    const u16* __restrict__ blob,
    const float* __restrict__ rc_w1, const float* __restrict__ rc_b1,
    const float* __restrict__ rc_b2, const float* __restrict__ rc_b3,
    const float* __restrict__ an_w1, const float* __restrict__ an_b1,
    const float* __restrict__ an_b2,
    float* __restrict__ out) {
  __shared__ __align__(16) u16 sActH[64 * 128];  // 16 KB: h hi|lo, then rc acts
  __shared__ __align__(16) u16 sAnH[64 * 64];    // 8 KB: an1 acts
  __shared__ float sHi[64], sDist[64];
  __shared__ float sBaseRc[128], sBaseAn[64], sW1d[128], sAnd[64];
  __shared__ float sB2[128], sB3[128], sAb2[128], sRed[128];

  const int tid = threadIdx.x;
  const int w = tid >> 6, lane = tid & 63;
  const int quad = lane >> 4, l15 = lane & 15;
  const int b = blockIdx.x >> 6, i = blockIdx.x & 63;
  const int o0 = w * 32;
  const int o0a = w * 16;

  // ---- stage h_j: hi at slot g^(j&7), lo at +8 slots; constants
  {
    const float4* srcH = (const float4*)(hwsH + b * 4096);
    const float4* srcL = (const float4*)(hwsL + b * 4096);
    for (int idx = tid; idx < 512; idx += TPB) {
      const int row = idx >> 3, g = idx & 7;
      const int addr = row * 128 + (g ^ (row & 7)) * 8;
      *(float4*)&sActH[addr] = srcH[idx];
      *(float4*)&sActH[addr + 64] = srcL[idx];
    }
  }
  if (tid < 64)
    sHi[tid] = b2f(hwsH[(b * 64 + i) * 64 + tid]) + b2f(hwsL[(b * 64 + i) * 64 + tid]);
  if (tid < 128) {
    sB2[tid] = rc_b2[tid]; sB3[tid] = rc_b3[tid]; sAb2[tid] = an_b2[tid];
    sW1d[tid] = rc_w1[128 * 128 + tid];
  } else if (tid < 192) {
    sAnd[tid - 128] = an_w1[128 * 64 + (tid - 128)];
  }
  __syncthreads();
  if (tid < 128) {
    float acc = rc_b1[tid];
    for (int k = 0; k < 64; ++k) acc = fmaf(sHi[k], rc_w1[k * 128 + tid], acc);
    sBaseRc[tid] = acc;
  } else if (tid < 192) {
    const int o = tid - 128;
    float acc = an_b1[o];
    for (int k = 0; k < 64; ++k) acc = fmaf(sHi[k], an_w1[k * 64 + o], acc);
    sBaseAn[o] = acc;
  } else {
    const int j = tid - 192;
    const int base = j * 128 + (j & 7) * 8;  // granule 0 (hi); lo at +64
    const float h0 = b2f(sActH[base + 0]) + b2f(sActH[base + 64 + 0]);
    const float h1 = b2f(sActH[base + 1]) + b2f(sActH[base + 64 + 1]);
    const float d0 = sHi[0] - h0, d1 = sHi[1] - h1;
    sDist[j] = d0 * d0 + d1 * d1;
  }
  __syncthreads();

  // ---- rc-L1 + an-L1 fused (B = h hi/lo, 3-term), acc init = base + dist*w1d
  f32x4 accR[2][4];
  f32x4 accN[1][4];
  {
    float bbR[2][4], wwR[2][4], bbN[4], wwN[4];
#pragma unroll
    for (int t = 0; t < 2; ++t) {
      ld4(bbR[t], &sBaseRc[o0 + 16 * t + quad * 4]);
      ld4(wwR[t], &sW1d[o0 + 16 * t + quad * 4]);
    }
    ld4(bbN, &sBaseAn[o0a + quad * 4]);
    ld4(wwN, &sAnd[o0a + quad * 4]);
#pragma unroll
    for (int s = 0; s < 4; ++s) {
      const float dj = sDist[16 * s + l15];
#pragma unroll
      for (int t = 0; t < 2; ++t) {
        f32x4 a;
#pragma unroll
        for (int r = 0; r < 4; ++r) a[r] = fmaf(dj, wwR[t][r], bbR[t][r]);
        accR[t][s] = a;
      }
      f32x4 a;
#pragma unroll
      for (int r = 0; r < 4; ++r) a[r] = fmaf(dj, wwN[r], bbN[r]);
      accN[0][s] = a;
    }
  }
  {
    const int lane64 = quad * 16 + l15;
#pragma unroll
    for (int c = 0; c < 2; ++c) {
      bf16x8 Ah[2], Al[2], AhN, AlN;
#pragma unroll
      for (int t = 0; t < 2; ++t) {
        const u16* p = blob + RC1F + ((c * 8 + 2 * w + t) * 64 + lane64) * 8;
        Ah[t] = *(const bf16x8*)p;
        Al[t] = *(const bf16x8*)(p + 8192);
      }
      {
        const u16* p = blob + AN1F + ((c * 4 + w) * 64 + lane64) * 8;
        AhN = *(const bf16x8*)p;
        AlN = *(const bf16x8*)(p + 4096);
      }
      const int slot = (4 * c + quad) ^ (l15 & 7);
      bf16x8 Bh[4], Bl[4];
#pragma unroll
      for (int s = 0; s < 4; ++s) {
        const int addr = (16 * s + l15) * 128 + slot * 8;
        Bh[s] = *(const bf16x8*)&sActH[addr];
        Bl[s] = *(const bf16x8*)&sActH[addr + 64];
      }
#pragma unroll
      for (int s = 0; s < 4; ++s) {
#pragma unroll
        for (int t = 0; t < 2; ++t) {
          f32x4 a = accR[t][s];
          a = __builtin_amdgcn_mfma_f32_16x16x32_bf16(Ah[t], Bh[s], a, 0, 0, 0);
          a = __builtin_amdgcn_mfma_f32_16x16x32_bf16(Al[t], Bh[s], a, 0, 0, 0);
          a = __builtin_amdgcn_mfma_f32_16x16x32_bf16(Ah[t], Bl[s], a, 0, 0, 0);
          accR[t][s] = a;
        }
        f32x4 a = accN[0][s];
        a = __builtin_amdgcn_mfma_f32_16x16x32_bf16(AhN, Bh[s], a, 0, 0, 0);
        a = __builtin_amdgcn_mfma_f32_16x16x32_bf16(AlN, Bh[s], a, 0, 0, 0);
        a = __builtin_amdgcn_mfma_f32_16x16x32_bf16(AhN, Bl[s], a, 0, 0, 0);
        accN[0][s] = a;
      }
    }
  }
  __syncthreads();  // h fully consumed
  store_acts_rne<2, 16>(accR, nullptr, sActH, o0, quad, l15);  // rc1 acts (16 granules)
  store_acts_rne<1, 8>(accN, nullptr, sAnH, o0a, quad, l15);   // an1 acts
  __syncthreads();

  // ---- an-L2 -> att in regs, then rc-L2 (different buffers, no barrier between)
  f32x4 accT[2][4];
#pragma unroll
  for (int t = 0; t < 2; ++t)
#pragma unroll
    for (int s = 0; s < 4; ++s) accT[t][s] = (f32x4){0.f, 0.f, 0.f, 0.f};
  run_layer2<2, 2, 8, 8>(accT, blob + AN2F, 8192, sAnH, 2 * w, quad, l15);
  float att[2][4][4];
#pragma unroll
  for (int t = 0; t < 2; ++t)
#pragma unroll
    for (int s = 0; s < 4; ++s)
#pragma unroll
      for (int r = 0; r < 4; ++r) {
        const float z = accT[t][s][r] + sAb2[o0 + 16 * t + quad * 4 + r];
        att[t][s][r] = 1.0f / (1.0f + __expf(-z));
      }

#pragma unroll
  for (int t = 0; t < 2; ++t)
#pragma unroll
    for (int s = 0; s < 4; ++s) accR[t][s] = (f32x4){0.f, 0.f, 0.f, 0.f};
  run_layer2<2, 4, 16, 8>(accR, blob + RC2F, 16384, sActH, 2 * w, quad, l15);
  __syncthreads();  // sActH reads done
  store_acts_rne<2, 16>(accR, sB2, sActH, o0, quad, l15);
  __syncthreads();

  // ---- rc-L3 + rel*att + reduce over j
#pragma unroll
  for (int t = 0; t < 2; ++t)
#pragma unroll
    for (int s = 0; s < 4; ++s) accR[t][s] = (f32x4){0.f, 0.f, 0.f, 0.f};
  run_layer2<2, 4, 16, 8>(accR, blob + RC3F, 16384, sActH, 2 * w, quad, l15);
  float ps[2][4] = {{0.f, 0.f, 0.f, 0.f}, {0.f, 0.f, 0.f, 0.f}};
#pragma unroll
  for (int t = 0; t < 2; ++t)
#pragma unroll
    for (int s = 0; s < 4; ++s)
#pragma unroll
      for (int r = 0; r < 4; ++r) {
        const float rel = fmaxf(accR[t][s][r] + sB3[o0 + 16 * t + quad * 4 + r], 0.f);
        ps[t][r] = fmaf(rel, att[t][s][r], ps[t][r]);
      }
#pragma unroll
  for (int t = 0; t < 2; ++t)
#pragma unroll
    for (int r = 0; r < 4; ++r) {
      float v = ps[t][r];
      v += __shfl_xor(v, 1, 64);
      v += __shfl_xor(v, 2, 64);
      v += __shfl_xor(v, 4, 64);
      v += __shfl_xor(v, 8, 64);
      ps[t][r] = v;
    }
  if (l15 == 0) {
#pragma unroll
    for (int t = 0; t < 2; ++t)
#pragma unroll
      for (int r = 0; r < 4; ++r)
        sRed[o0 + 16 * t + quad * 4 + r] = ps[t][r];
  }
  __syncthreads();
  if (tid < 128)
    atomicAdd(&out[b * 128 + tid], sRed[tid] * (1.0f / 4096.0f));
}

// ---------------------------------------------------------------------------
// Fallback pair kernel (VALU): used only if ws_size < WS_NEED.
// ---------------------------------------------------------------------------
__global__ __launch_bounds__(TPB, 3) void pair_kernel(
    const u16* __restrict__ hwsH, const u16* __restrict__ hwsL,
    const float* __restrict__ rc_w1, const float* __restrict__ rc_b1,
    const float* __restrict__ rc_w2, const float* __restrict__ rc_b2,
    const float* __restrict__ rc_w3, const float* __restrict__ rc_b3,
    const float* __restrict__ an_w1, const float* __restrict__ an_b1,
    const float* __restrict__ an_w2, const float* __restrict__ an_b2,
    float* __restrict__ out) {
  __shared__ __align__(16) float sHj[2048];
  __shared__ __align__(16) float sA[4096];
  __shared__ __align__(16) float sAn1[2048];
  __shared__ __align__(16) float sW[4096];
  __shared__ __align__(16) float sHi[64];
  __shared__ __align__(16) float sBaseRc[128];
  __shared__ __align__(16) float sBaseAn[64];
  __shared__ float sDist[32];
  __shared__ __align__(16) float sW1d[128], sAn1d[64], sB2[128], sB3[128], sAb2[128];

  const int tid = threadIdx.x;
  const int jg = tid >> 5;
  const int og = tid & 31;
  const int blk = blockIdx.x;
  const int jh = blk & 1;
  const int i = (blk >> 1) & 63;
  const int b = blk >> 7;
  const int j0 = jg * 4;

  for (int idx = tid; idx < 2048; idx += TPB) {
    const int off = (b * 64 + jh * 32) * 64 + idx;
    sHj[idx] = b2f(hwsH[off]) + b2f(hwsL[off]);
  }
  if (tid < 64) sHi[tid] = b2f(hwsH[(b * 64 + i) * 64 + tid]) + b2f(hwsL[(b * 64 + i) * 64 + tid]);
  if (tid < 128) {
    sW1d[tid] = rc_w1[128 * 128 + tid];
    sB2[tid] = rc_b2[tid]; sB3[tid] = rc_b3[tid]; sAb2[tid] = an_b2[tid];
  } else if (tid < 192) {
    sAn1d[tid - 128] = an_w1[128 * 64 + (tid - 128)];
  }
  __syncthreads();
  if (tid < 128) {
    float acc = rc_b1[tid];
    for (int k = 0; k < 64; k++) acc = fmaf(sHi[k], rc_w1[k * 128 + tid], acc);
    sBaseRc[tid] = acc;
  } else if (tid < 192) {
    const int o = tid - 128;
    float acc = an_b1[o];
    for (int k = 0; k < 64; k++) acc = fmaf(sHi[k], an_w1[k * 64 + o], acc);
    sBaseAn[o] = acc;
  } else if (tid < 224) {
    const int j = tid - 192;
    const float d0 = sHi[0] - sHj[j * 64 + 0];
    const float d1 = sHi[1] - sHj[j * 64 + 1];
    sDist[j] = d0 * d0 + d1 * d1;
  }
  __syncthreads();

  float aR[4][4], aA[4][2];
#pragma unroll
  for (int jj = 0; jj < 4; jj++) {
#pragma unroll
    for (int oo = 0; oo < 4; oo++) aR[jj][oo] = 0.f;
    aA[jj][0] = 0.f; aA[jj][1] = 0.f;
  }
  for (int c = 0; c < 4; c++) {
    cp_lds(sW, rc_w1 + (64 + c * 16) * 128, 2048, tid);
    cp_lds(sW + 2048, an_w1 + (64 + c * 16) * 64, 1024, tid);
    __syncthreads();
    for (int kk = 0; kk < 16; kk += 4) {
      float xr[4][4], wr[4][4], wa[4][2];
#pragma unroll
      for (int jj = 0; jj < 4; jj++) ld4(xr[jj], &sHj[(j0 + jj) * 64 + c * 16 + kk]);
#pragma unroll
      for (int t = 0; t < 4; t++) ld4(wr[t], &sW[(kk + t) * 128 + og * 4]);
#pragma unroll
      for (int t = 0; t < 4; t++) ld2(wa[t], &sW[2048 + (kk + t) * 64 + og * 2]);
#pragma unroll
      for (int t = 0; t < 4; t++)
#pragma unroll
        for (int jj = 0; jj < 4; jj++) {
#pragma unroll
          for (int oo = 0; oo < 4; oo++)
            aR[jj][oo] = fmaf(xr[jj][t], wr[t][oo], aR[jj][oo]);
          aA[jj][0] = fmaf(xr[jj][t], wa[t][0], aA[jj][0]);
          aA[jj][1] = fmaf(xr[jj][t], wa[t][1], aA[jj][1]);
        }
    }
    __syncthreads();
  }
#pragma unroll
  for (int jj = 0; jj < 4; jj++) {
    const int j = j0 + jj;
    const float dj = sDist[j];
    float4 v;
    v.x = fmaxf(aR[jj][0] + sBaseRc[og * 4 + 0] + dj * sW1d[og * 4 + 0], 0.f);
    v.y = fmaxf(aR[jj][1] + sBaseRc[og * 4 + 1] + dj * sW1d[og * 4 + 1], 0.f);
    v.z = fmaxf(aR[jj][2] + sBaseRc[og * 4 + 2] + dj * sW1d[og * 4 + 2], 0.f);
    v.w = fmaxf(aR[jj][3] + sBaseRc[og * 4 + 3] + dj * sW1d[og * 4 + 3], 0.f);
    *(float4*)&sA[j * 128 + og * 4] = v;
    float2 u;
    u.x = fmaxf(aA[jj][0] + sBaseAn[og * 2 + 0] + dj * sAn1d[og * 2 + 0], 0.f);
    u.y = fmaxf(aA[jj][1] + sBaseAn[og * 2 + 1] + dj * sAn1d[og * 2 + 1], 0.f);
    *(float2*)&sAn1[j * 64 + og * 2] = u;
  }
  __syncthreads();

  float aT[4][4];
#pragma unroll
  for (int jj = 0; jj < 4; jj++)
#pragma unroll
    for (int oo = 0; oo < 4; oo++) aT[jj][oo] = 0.f;
  for (int c = 0; c < 2; c++) {
    cp_lds(sW, an_w2 + c * 32 * 128, 4096, tid);
    __syncthreads();
    for (int kk = 0; kk < 32; kk += 4) {
      float xr[4][4], wr[4][4];
#pragma unroll
      for (int jj = 0; jj < 4; jj++) ld4(xr[jj], &sAn1[(j0 + jj) * 64 + c * 32 + kk]);
#pragma unroll
      for (int t = 0; t < 4; t++) ld4(wr[t], &sW[(kk + t) * 128 + og * 4]);
#pragma unroll
      for (int t = 0; t < 4; t++)
#pragma unroll
        for (int jj = 0; jj < 4; jj++)
#pragma unroll
          for (int oo = 0; oo < 4; oo++)
            aT[jj][oo] = fmaf(xr[jj][t], wr[t][oo], aT[jj][oo]);
    }
    __syncthreads();
  }
  float att[4][4];
#pragma unroll
  for (int jj = 0; jj < 4; jj++)
#pragma unroll
    for (int oo = 0; oo < 4; oo++) {
      const float z = aT[jj][oo] + sAb2[og * 4 + oo];
      att[jj][oo] = 1.0f / (1.0f + __expf(-z));
    }

#pragma unroll
  for (int jj = 0; jj < 4; jj++)
#pragma unroll
    for (int oo = 0; oo < 4; oo++) aT[jj][oo] = 0.f;
  for (int c = 0; c < 4; c++) {
    cp_lds(sW, rc_w2 + c * 32 * 128, 4096, tid);
    __syncthreads();
    for (int kk = 0; kk < 32; kk += 4) {
      float xr[4][4], wr[4][4];
#pragma unroll
      for (int jj = 0; jj < 4; jj++) ld4(xr[jj], &sA[(j0 + jj) * 128 + c * 32 + kk]);
#pragma unroll
      for (int t = 0; t < 4; t++) ld4(wr[t], &sW[(kk + t) * 128 + og * 4]);
#pragma unroll
      for (int t = 0; t < 4; t++)
#pragma unroll
        for (int jj = 0; jj < 4; jj++)
#pragma unroll
          for (int oo = 0; oo < 4; oo++)
            aT[jj][oo] = fmaf(xr[jj][t], wr[t][oo], aT[jj][oo]);
    }
    __syncthreads();
  }
#pragma unroll
  for (int jj = 0; jj < 4; jj++) {
    float4 v;
    v.x = fmaxf(aT[jj][0] + sB2[og * 4 + 0], 0.f);
    v.y = fmaxf(aT[jj][1] + sB2[og * 4 + 1], 0.f);
    v.z = fmaxf(aT[jj][2] + sB2[og * 4 + 2], 0.f);
    v.w = fmaxf(aT[jj][3] + sB2[og * 4 + 3], 0.f);
    *(float4*)&sA[(j0 + jj) * 128 + og * 4] = v;
  }
  __syncthreads();

#pragma unroll
  for (int jj = 0; jj < 4; jj++)
#pragma unroll
    for (int oo = 0; oo < 4; oo++) aT[jj][oo] = 0.f;
  for (int c = 0; c < 4; c++) {
    cp_lds(sW, rc_w3 + c * 32 * 128, 4096, tid);
    __syncthreads();
    for (int kk = 0; kk < 32; kk += 4) {
      float xr[4][4], wr[4][4];
#pragma unroll
      for (int jj = 0; jj < 4; jj++) ld4(xr[jj], &sA[(j0 + jj) * 128 + c * 32 + kk]);
#pragma unroll
      for (int t = 0; t < 4; t++) ld4(wr[t], &sW[(kk + t) * 128 + og * 4]);
#pragma unroll
      for (int t = 0; t < 4; t++)
#pragma unroll
        for (int jj = 0; jj < 4; jj++)
#pragma unroll
          for (int oo = 0; oo < 4; oo++)
            aT[jj][oo] = fmaf(xr[jj][t], wr[t][oo], aT[jj][oo]);
    }
    __syncthreads();
  }
  float p[4] = {0.f, 0.f, 0.f, 0.f};
#pragma unroll
  for (int jj = 0; jj < 4; jj++)
#pragma unroll
    for (int oo = 0; oo < 4; oo++) {
      const float rel = fmaxf(aT[jj][oo] + sB3[og * 4 + oo], 0.f);
      p[oo] = fmaf(rel, att[jj][oo], p[oo]);
    }
  *(float4*)&sAn1[jg * 128 + og * 4] = make_float4(p[0], p[1], p[2], p[3]);
  __syncthreads();
  if (tid < 128) {
    float ssum = 0.f;
#pragma unroll
    for (int g = 0; g < 8; g++) ssum += sAn1[g * 128 + tid];
    atomicAdd(&out[b * 128 + tid], ssum * (1.0f / 4096.0f));
  }
}

extern "C" void kernel_launch(void* const* d_in, const int* in_sizes, int n_in,
                              void* d_out, int out_size, void* d_ws, size_t ws_size,
                              hipStream_t stream) {
  const float* s     = (const float*)d_in[0];
  const float* se_w1 = (const float*)d_in[1];
  const float* se_b1 = (const float*)d_in[2];
  const float* se_w2 = (const float*)d_in[3];
  const float* se_b2 = (const float*)d_in[4];
  const float* sd_w1 = (const float*)d_in[5];
  const float* sd_b1 = (const float*)d_in[6];
  const float* sd_w2 = (const float*)d_in[7];
  const float* sd_b2 = (const float*)d_in[8];
  const float* rc_w1 = (const float*)d_in[9];
  const float* rc_b1 = (const float*)d_in[10];
  const float* rc_w2 = (const float*)d_in[11];
  const float* rc_b2 = (const float*)d_in[12];
  const float* rc_w3 = (const float*)d_in[13];
  const float* rc_b3 = (const float*)d_in[14];
  const float* an_w1 = (const float*)d_in[15];
  const float* an_b1 = (const float*)d_in[16];
  const float* an_w2 = (const float*)d_in[17];
  const float* an_b2 = (const float*)d_in[18];
  float* out = (float*)d_out;
  u16* hwsH = (u16*)d_ws;
  u16* hwsL = hwsH + HWSL_U16;
  u16* blob = hwsH + BLOB_U16;

  // enc (blocks 0..127, writes out directly) + weight prep (blocks 128..335)
  enc_prep_kernel<<<336, TPB, 0, stream>>>(s, se_w1, se_b1, se_w2, se_b2,
                                           sd_w1, sd_b1, sd_w2, sd_b2,
                                           rc_w1, rc_w2, rc_w3, an_w1, an_w2,
                                           hwsH, hwsL, blob, out);
  if (ws_size >= WS_NEED) {
    pair_mfma_kernel<<<8192, TPB, 0, stream>>>(hwsH, hwsL, blob,
                                               rc_w1, rc_b1, rc_b2, rc_b3,
                                               an_w1, an_b1, an_b2, out);
  } else {
    pair_kernel<<<16384, TPB, 0, stream>>>(hwsH, hwsL, rc_w1, rc_b1, rc_w2, rc_b2,
                                           rc_w3, rc_b3, an_w1, an_b1, an_w2, an_b2, out);
  }
}

// Round 5
// 259.993 us; speedup vs baseline: 3.4425x; 1.0119x over previous
//
#include <hip/hip_runtime.h>
#include <math.h>

#define TPB 256

typedef unsigned short u16;
typedef __attribute__((ext_vector_type(8))) short bf16x8;
typedef __attribute__((ext_vector_type(4))) float f32x4;

// ---------------- ws layout (u16 element offsets from d_ws) ----------------
// hB: u16[524288] @ 0 — h as single RNE bf16, row-major [b][n][64]
// blob: u16[131072] @ 524288 — fragment-linear A images (hi[OK] then lo[OK])
#define HB_U16   0
#define BLOB_U16 524288
// blob-internal offsets (u16):
#define RC1F 0       // O=128, K=128 (k0..63 = W1[64..127] h_j-half, k64..127 = W1[0..63] h_i-half)
#define AN1F 32768   // O=64,  K=128 (same row mapping from an_w1)
#define AN2F 49152   // O=128, K=64
#define RC2F 65536   // O=128, K=128
#define RC3F 98304   // O=128, K=128
#define BLOB_TOT 131072
#define WS_NEED ((size_t)(BLOB_U16 + BLOB_TOT) * 2)   // 1.31 MB (< proven ws_size)

__device__ __forceinline__ float b2f(u16 h) {
  return __uint_as_float(((unsigned)h) << 16);
}
// truncation split: x ~= hi + lo with |err| ~ 2^-17 |x|
__device__ __forceinline__ void split_bf16(float x, u16& hi, u16& lo) {
  unsigned u = __float_as_uint(x);
  hi = (u16)(u >> 16);
  float hif = __uint_as_float(u & 0xFFFF0000u);
  lo = (u16)(__float_as_uint(x - hif) >> 16);
}
// round-to-nearest-even f32 -> bf16
__device__ __forceinline__ u16 f2bf_rne(float x) {
  unsigned u = __float_as_uint(x);
  return (u16)((u + 0x7FFFu + ((u >> 16) & 1u)) >> 16);
}

__device__ __forceinline__ void cp_lds(float* dst, const float* src, int nfloats, int tid) {
  const float4* s4 = (const float4*)src;
  float4* d4 = (float4*)dst;
  const int n4 = nfloats >> 2;
  for (int i = tid; i < n4; i += TPB) d4[i] = s4[i];
}
__device__ __forceinline__ void ld4(float r[4], const float* p) {
  float4 v = *(const float4*)p;
  r[0] = v.x; r[1] = v.y; r[2] = v.z; r[3] = v.w;
}
__device__ __forceinline__ void ld2(float r[2], const float* p) {
  float2 v = *(const float2*)p;
  r[0] = v.x; r[1] = v.y;
}

// ---------------------------------------------------------------------------
// Prep: split weights into bf16 hi/lo, fragment-linear A layout.
// 65536 elements total -> 256 blocks. No LDS.
// Frag addr: ((c*T + tg)*64 + lane)*8 + u; o = tg*16+(lane&15), k = c*32+(lane>>4)*8+u.
// ---------------------------------------------------------------------------
__global__ void prep_weights(const float* __restrict__ rc_w1, const float* __restrict__ rc_w2,
                             const float* __restrict__ rc_w3, const float* __restrict__ an_w1,
                             const float* __restrict__ an_w2, u16* __restrict__ blob) {
  int idx = blockIdx.x * TPB + threadIdx.x;
  if (idx >= 65536) return;
  int r, base, OK, T; const float* W; int Wld; int mode;  // mode 1 = L1 row remap
  if (idx < 16384)      { r = idx;         base = RC1F; OK = 16384; T = 8; W = rc_w1; Wld = 128; mode = 1; }
  else if (idx < 24576) { r = idx - 16384; base = AN1F; OK = 8192;  T = 4; W = an_w1; Wld = 64;  mode = 1; }
  else if (idx < 32768) { r = idx - 24576; base = AN2F; OK = 8192;  T = 8; W = an_w2; Wld = 128; mode = 0; }
  else if (idx < 49152) { r = idx - 32768; base = RC2F; OK = 16384; T = 8; W = rc_w2; Wld = 128; mode = 0; }
  else                  { r = idx - 49152; base = RC3F; OK = 16384; T = 8; W = rc_w3; Wld = 128; mode = 0; }
  const int u = r & 7;
  const int lane = (r >> 3) & 63;
  const int ct = r >> 9;
  const int c = (T == 8) ? (ct >> 3) : (ct >> 2);
  const int tg = (T == 8) ? (ct & 7) : (ct & 3);
  const int o = tg * 16 + (lane & 15);
  const int k = c * 32 + (lane >> 4) * 8 + u;
  const int krow = mode ? ((k < 64) ? 64 + k : k - 64) : k;
  const float x = W[krow * Wld + o];
  u16 hi, lo; split_bf16(x, hi, lo);
  blob[base + r] = hi;
  blob[base + OK + r] = lo;
}

// ---------------------------------------------------------------------------
// Kernel A: state encoder -> hB (RNE bf16), fused self_dyn -> out (atomic).
// One block = 32 rows (half of one b). 256 blocks, 52 KB LDS (proven ~8 µs shape).
// ---------------------------------------------------------------------------
__global__ __launch_bounds__(TPB, 3) void enc_self_kernel(
    const float* __restrict__ s_in,
    const float* __restrict__ se_w1, const float* __restrict__ se_b1,
    const float* __restrict__ se_w2, const float* __restrict__ se_b2,
    const float* __restrict__ sd_w1, const float* __restrict__ sd_b1,
    const float* __restrict__ sd_w2, const float* __restrict__ sd_b2,
    u16* __restrict__ hB, float* __restrict__ out) {
  __shared__ __align__(16) float sX[2048];
  __shared__ __align__(16) float sH1[2048];
  __shared__ __align__(16) float sT[4096];
  __shared__ __align__(16) float sW[4096];
  __shared__ float sb1[64], sb2[64], sdb1[128], sdb2[128];

  const int tid = threadIdx.x;
  const int lg = tid >> 5;
  const int og = tid & 31;
  const int b = blockIdx.x >> 1;
  const int row0 = b * 64 + (blockIdx.x & 1) * 32;
  const int n0 = lg * 4;

  cp_lds(sX, s_in + row0 * 64, 2048, tid);
  cp_lds(sW, se_w1, 4096, tid);
  if (tid < 64) { sb1[tid] = se_b1[tid]; sb2[tid] = se_b2[tid]; }
  else if (tid < 192) { const int o = tid - 64; sdb1[o] = sd_b1[o]; sdb2[o] = sd_b2[o]; }
  __syncthreads();

  float a2[4][2];
#pragma unroll
  for (int nn = 0; nn < 4; nn++) { a2[nn][0] = 0.f; a2[nn][1] = 0.f; }
  for (int kk = 0; kk < 64; kk += 4) {
    float xr[4][4], wr[4][2];
#pragma unroll
    for (int nn = 0; nn < 4; nn++) ld4(xr[nn], &sX[(n0 + nn) * 64 + kk]);
#pragma unroll
    for (int t = 0; t < 4; t++) ld2(wr[t], &sW[(kk + t) * 64 + og * 2]);
#pragma unroll
    for (int t = 0; t < 4; t++)
#pragma unroll
      for (int nn = 0; nn < 4; nn++) {
        a2[nn][0] = fmaf(xr[nn][t], wr[t][0], a2[nn][0]);
        a2[nn][1] = fmaf(xr[nn][t], wr[t][1], a2[nn][1]);
      }
  }
#pragma unroll
  for (int nn = 0; nn < 4; nn++) {
    float2 v;
    v.x = fmaxf(a2[nn][0] + sb1[og * 2 + 0], 0.f);
    v.y = fmaxf(a2[nn][1] + sb1[og * 2 + 1], 0.f);
    *(float2*)&sH1[(n0 + nn) * 64 + og * 2] = v;
  }
  __syncthreads();
  cp_lds(sW, se_w2, 4096, tid);
  __syncthreads();

#pragma unroll
  for (int nn = 0; nn < 4; nn++) { a2[nn][0] = 0.f; a2[nn][1] = 0.f; }
  for (int kk = 0; kk < 64; kk += 4) {
    float xr[4][4], wr[4][2];
#pragma unroll
    for (int nn = 0; nn < 4; nn++) ld4(xr[nn], &sH1[(n0 + nn) * 64 + kk]);
#pragma unroll
    for (int t = 0; t < 4; t++) ld2(wr[t], &sW[4096 - 4096 + (kk + t) * 64 + og * 2]);
#pragma unroll
    for (int t = 0; t < 4; t++)
#pragma unroll
      for (int nn = 0; nn < 4; nn++) {
        a2[nn][0] = fmaf(xr[nn][t], wr[t][0], a2[nn][0]);
        a2[nn][1] = fmaf(xr[nn][t], wr[t][1], a2[nn][1]);
      }
  }
#pragma unroll
  for (int nn = 0; nn < 4; nn++) {
    float2 v;
    v.x = fmaxf(a2[nn][0] + sb2[og * 2 + 0], 0.f);
    v.y = fmaxf(a2[nn][1] + sb2[og * 2 + 1], 0.f);
    *(float2*)&sX[(n0 + nn) * 64 + og * 2] = v;
    const int off = (row0 + n0 + nn) * 64 + og * 2;
    *(ushort2*)&hB[off] = make_ushort2(f2bf_rne(v.x), f2bf_rne(v.y));
  }
  __syncthreads();

  float a4[4][4];
#pragma unroll
  for (int nn = 0; nn < 4; nn++)
#pragma unroll
    for (int oo = 0; oo < 4; oo++) a4[nn][oo] = 0.f;
  for (int c = 0; c < 2; c++) {
    cp_lds(sW, sd_w1 + c * 32 * 128, 4096, tid);
    __syncthreads();
    for (int kk = 0; kk < 32; kk += 4) {
      float xr[4][4], wr[4][4];
#pragma unroll
      for (int nn = 0; nn < 4; nn++) ld4(xr[nn], &sX[(n0 + nn) * 64 + c * 32 + kk]);
#pragma unroll
      for (int t = 0; t < 4; t++) ld4(wr[t], &sW[(kk + t) * 128 + og * 4]);
#pragma unroll
      for (int t = 0; t < 4; t++)
#pragma unroll
        for (int nn = 0; nn < 4; nn++)
#pragma unroll
          for (int oo = 0; oo < 4; oo++)
            a4[nn][oo] = fmaf(xr[nn][t], wr[t][oo], a4[nn][oo]);
    }
    __syncthreads();
  }
#pragma unroll
  for (int nn = 0; nn < 4; nn++) {
    float4 v;
    v.x = fmaxf(a4[nn][0] + sdb1[og * 4 + 0], 0.f);
    v.y = fmaxf(a4[nn][1] + sdb1[og * 4 + 1], 0.f);
    v.z = fmaxf(a4[nn][2] + sdb1[og * 4 + 2], 0.f);
    v.w = fmaxf(a4[nn][3] + sdb1[og * 4 + 3], 0.f);
    *(float4*)&sT[(n0 + nn) * 128 + og * 4] = v;
  }
  __syncthreads();

#pragma unroll
  for (int nn = 0; nn < 4; nn++)
#pragma unroll
    for (int oo = 0; oo < 4; oo++) a4[nn][oo] = 0.f;
  for (int c = 0; c < 4; c++) {
    cp_lds(sW, sd_w2 + c * 32 * 128, 4096, tid);
    __syncthreads();
    for (int kk = 0; kk < 32; kk += 4) {
      float xr[4][4], wr[4][4];
#pragma unroll
      for (int nn = 0; nn < 4; nn++) ld4(xr[nn], &sT[(n0 + nn) * 128 + c * 32 + kk]);
#pragma unroll
      for (int t = 0; t < 4; t++) ld4(wr[t], &sW[(kk + t) * 128 + og * 4]);
#pragma unroll
      for (int t = 0; t < 4; t++)
#pragma unroll
        for (int nn = 0; nn < 4; nn++)
#pragma unroll
          for (int oo = 0; oo < 4; oo++)
            a4[nn][oo] = fmaf(xr[nn][t], wr[t][oo], a4[nn][oo]);
    }
    __syncthreads();
  }
  float p[4];
#pragma unroll
  for (int oo = 0; oo < 4; oo++)
    p[oo] = a4[0][oo] + a4[1][oo] + a4[2][oo] + a4[3][oo] + 4.f * sdb2[og * 4 + oo];
  *(float4*)&sH1[lg * 128 + og * 4] = make_float4(p[0], p[1], p[2], p[3]);
  __syncthreads();
  if (tid < 128) {
    float ssum = 0.f;
#pragma unroll
    for (int g = 0; g < 8; g++) ssum += sH1[g * 128 + tid];
    atomicAdd(&out[b * 128 + tid], ssum * (1.0f / 64.0f));
  }
}

// ---------------------------------------------------------------------------
// MFMA layer (2-term: weights hi/lo, B single bf16). A-frags from global blob
// (L2-resident); B from XOR-swizzled LDS. No barriers inside.
// ---------------------------------------------------------------------------
template<int MT, int NCHUNK, int RSG, int TILES>
__device__ __forceinline__ void run_layer2(f32x4 (&acc)[MT][4],
    const u16* __restrict__ blobL, int OK,
    const u16* __restrict__ sB, int tg0, int quad, int l15) {
  const int lane = quad * 16 + l15;
#pragma unroll
  for (int c = 0; c < NCHUNK; ++c) {
    bf16x8 Ah[MT], Al[MT];
#pragma unroll
    for (int t = 0; t < MT; ++t) {
      const u16* p = blobL + ((c * TILES + tg0 + t) * 64 + lane) * 8;
      Ah[t] = *(const bf16x8*)p;
      Al[t] = *(const bf16x8*)(p + OK);
    }
    const int slot = (4 * c + quad) ^ (l15 & 7);
    bf16x8 Bh[4];
#pragma unroll
    for (int s = 0; s < 4; ++s)
      Bh[s] = *(const bf16x8*)&sB[(16 * s + l15) * (RSG * 8) + slot * 8];
#pragma unroll
    for (int t = 0; t < MT; ++t)
#pragma unroll
      for (int s = 0; s < 4; ++s) {
        f32x4 a = acc[t][s];
        a = __builtin_amdgcn_mfma_f32_16x16x32_bf16(Ah[t], Bh[s], a, 0, 0, 0);
        a = __builtin_amdgcn_mfma_f32_16x16x32_bf16(Al[t], Bh[s], a, 0, 0, 0);
        acc[t][s] = a;
      }
  }
}

// relu(+bias) -> RNE bf16 -> swizzled LDS store (ushort4).
template<int MT, int RSG>
__device__ __forceinline__ void store_acts_rne(const f32x4 (&acc)[MT][4], const float* bias,
                                               u16* dst, int o0, int quad, int l15) {
#pragma unroll
  for (int t = 0; t < MT; ++t) {
    const int ob = o0 + 16 * t + quad * 4;
    const int slot = (ob >> 3) ^ (l15 & 7);
    const int e = ob & 7;
#pragma unroll
    for (int s = 0; s < 4; ++s) {
      const int j = 16 * s + l15;
      u16 v[4];
#pragma unroll
      for (int r = 0; r < 4; ++r) {
        float x = acc[t][s][r];
        if (bias) x += bias[ob + r];
        v[r] = f2bf_rne(fmaxf(x, 0.f));
      }
      *(ushort4*)&dst[j * (RSG * 8) + slot * 8 + e] = make_ushort4(v[0], v[1], v[2], v[3]);
    }
  }
}

// ---------------------------------------------------------------------------
// Kernel B (MFMA): one block per (b,i). ~28 KB LDS -> 4 blocks/CU.
// L1 is a plain K=128 GEMM: B rows = [h_j(64) | h_i(64) broadcast]; dist+bias
// live in the accumulator init. No per-block base-vector loops at all.
// ---------------------------------------------------------------------------
__global__ __launch_bounds__(TPB, 4) void pair_mfma_kernel(
    const u16* __restrict__ hB, const u16* __restrict__ blob,
    const float* __restrict__ rc_w1, const float* __restrict__ rc_b1,
    const float* __restrict__ rc_b2, const float* __restrict__ rc_b3,
    const float* __restrict__ an_w1, const float* __restrict__ an_b1,
    const float* __restrict__ an_b2,
    float* __restrict__ out) {
  __shared__ __align__(16) u16 sActH[64 * 128];  // 16 KB: [h_j|h_i] then rc acts (16 granules)
  __shared__ __align__(16) u16 sAnH[64 * 64];    // 8 KB: an1 acts (8 granules)
  __shared__ float sDist[64];
  __shared__ float sB1[128], sW1d[128], sAb1[64], sAnd[64];
  __shared__ float sB2[128], sB3[128], sAb2[128], sRed[128];

  const int tid = threadIdx.x;
  const int w = tid >> 6, lane = tid & 63;
  const int quad = lane >> 4, l15 = lane & 15;
  const int b = blockIdx.x >> 6, i = blockIdx.x & 63;
  const int o0 = w * 32;    // O=128 layers: tiles 2w, 2w+1
  const int o0a = w * 16;   // an1 (O=64): tile w

  // ---- stage B for L1: granules 0..7 = h_j rows, 8..15 = h_i (broadcast)
  {
    const float4* srcJ = (const float4*)(hB + b * 4096);
    const float4* srcI = (const float4*)(hB + b * 4096 + i * 64);
    for (int idx = tid; idx < 1024; idx += TPB) {
      const int half = idx >> 9;
      const int id = idx & 511;
      const int row = id >> 3, g = id & 7;
      const float4 v = half ? srcI[g] : srcJ[id];
      const int gl = half ? (8 + g) : g;
      *(float4*)&sActH[row * 128 + (gl ^ (row & 7)) * 8] = v;
    }
  }
  if (tid < 128) {
    sB1[tid] = rc_b1[tid]; sW1d[tid] = rc_w1[128 * 128 + tid];
    sB2[tid] = rc_b2[tid]; sB3[tid] = rc_b3[tid]; sAb2[tid] = an_b2[tid];
  } else if (tid < 192) {
    sAnd[tid - 128] = an_w1[128 * 64 + (tid - 128)];
    sAb1[tid - 128] = an_b1[tid - 128];
  }
  __syncthreads();
  if (tid < 64) {
    const int j = tid;
    const int b0 = j * 128 + ((0 ^ (j & 7)) * 8);   // granule 0 (h_j k=0,1)
    const int b8 = j * 128 + ((8 ^ (j & 7)) * 8);   // granule 8 (h_i k=0,1)
    const float d0 = b2f(sActH[b8 + 0]) - b2f(sActH[b0 + 0]);
    const float d1 = b2f(sActH[b8 + 1]) - b2f(sActH[b0 + 1]);
    sDist[j] = d0 * d0 + d1 * d1;
  }
  __syncthreads();

  // ---- an-L1 first (retire accN early), then rc-L1; init = bias + dist*w_dist
  f32x4 accN[1][4];
  {
    float bb[4], ww[4];
    ld4(bb, &sAb1[o0a + quad * 4]);
    ld4(ww, &sAnd[o0a + quad * 4]);
#pragma unroll
    for (int s = 0; s < 4; ++s) {
      const float dj = sDist[16 * s + l15];
      f32x4 a;
#pragma unroll
      for (int r = 0; r < 4; ++r) a[r] = fmaf(dj, ww[r], bb[r]);
      accN[0][s] = a;
    }
  }
  run_layer2<1, 4, 16, 4>(accN, blob + AN1F, 8192, sActH, w, quad, l15);
  store_acts_rne<1, 8>(accN, nullptr, sAnH, o0a, quad, l15);  // sAnH disjoint from sActH

  f32x4 accR[2][4];
  {
    float bb[2][4], ww[2][4];
#pragma unroll
    for (int t = 0; t < 2; ++t) {
      ld4(bb[t], &sB1[o0 + 16 * t + quad * 4]);
      ld4(ww[t], &sW1d[o0 + 16 * t + quad * 4]);
    }
#pragma unroll
    for (int s = 0; s < 4; ++s) {
      const float dj = sDist[16 * s + l15];
#pragma unroll
      for (int t = 0; t < 2; ++t) {
        f32x4 a;
#pragma unroll
        for (int r = 0; r < 4; ++r) a[r] = fmaf(dj, ww[t][r], bb[t][r]);
        accR[t][s] = a;
      }
    }
  }
  run_layer2<2, 4, 16, 8>(accR, blob + RC1F, 16384, sActH, 2 * w, quad, l15);
  __syncthreads();  // all reads of [h_j|h_i] done
  store_acts_rne<2, 16>(accR, nullptr, sActH, o0, quad, l15);  // rc1 acts
  __syncthreads();

  // ---- an-L2 -> att in regs (reads sAnH)
  f32x4 accT[2][4];
#pragma unroll
  for (int t = 0; t < 2; ++t)
#pragma unroll
    for (int s = 0; s < 4; ++s) accT[t][s] = (f32x4){0.f, 0.f, 0.f, 0.f};
  run_layer2<2, 2, 8, 8>(accT, blob + AN2F, 8192, sAnH, 2 * w, quad, l15);
  float att[2][4][4];
#pragma unroll
  for (int t = 0; t < 2; ++t)
#pragma unroll
    for (int s = 0; s < 4; ++s)
#pragma unroll
      for (int r = 0; r < 4; ++r) {
        const float z = accT[t][s][r] + sAb2[o0 + 16 * t + quad * 4 + r];
        att[t][s][r] = 1.0f / (1.0f + __expf(-z));
      }

  // ---- rc-L2 (reads sActH), write back in place
#pragma unroll
  for (int t = 0; t < 2; ++t)
#pragma unroll
    for (int s = 0; s < 4; ++s) accR[t][s] = (f32x4){0.f, 0.f, 0.f, 0.f};
  run_layer2<2, 4, 16, 8>(accR, blob + RC2F, 16384, sActH, 2 * w, quad, l15);
  __syncthreads();
  store_acts_rne<2, 16>(accR, sB2, sActH, o0, quad, l15);
  __syncthreads();

  // ---- rc-L3 + rel*att + reduce over j
#pragma unroll
  for (int t = 0; t < 2; ++t)
#pragma unroll
    for (int s = 0; s < 4; ++s) accR[t][s] = (f32x4){0.f, 0.f, 0.f, 0.f};
  run_layer2<2, 4, 16, 8>(accR, blob + RC3F, 16384, sActH, 2 * w, quad, l15);
  float ps[2][4] = {{0.f, 0.f, 0.f, 0.f}, {0.f, 0.f, 0.f, 0.f}};
#pragma unroll
  for (int t = 0; t < 2; ++t)
#pragma unroll
    for (int s = 0; s < 4; ++s)
#pragma unroll
      for (int r = 0; r < 4; ++r) {
        const float rel = fmaxf(accR[t][s][r] + sB3[o0 + 16 * t + quad * 4 + r], 0.f);
        ps[t][r] = fmaf(rel, att[t][s][r], ps[t][r]);
      }
#pragma unroll
  for (int t = 0; t < 2; ++t)
#pragma unroll
    for (int r = 0; r < 4; ++r) {
      float v = ps[t][r];
      v += __shfl_xor(v, 1, 64);
      v += __shfl_xor(v, 2, 64);
      v += __shfl_xor(v, 4, 64);
      v += __shfl_xor(v, 8, 64);
      ps[t][r] = v;
    }
  if (l15 == 0) {
#pragma unroll
    for (int t = 0; t < 2; ++t)
#pragma unroll
      for (int r = 0; r < 4; ++r)
        sRed[o0 + 16 * t + quad * 4 + r] = ps[t][r];
  }
  __syncthreads();
  if (tid < 128)
    atomicAdd(&out[b * 128 + tid], sRed[tid] * (1.0f / 4096.0f));
}

extern "C" void kernel_launch(void* const* d_in, const int* in_sizes, int n_in,
                              void* d_out, int out_size, void* d_ws, size_t ws_size,
                              hipStream_t stream) {
  const float* s     = (const float*)d_in[0];
  const float* se_w1 = (const float*)d_in[1];
  const float* se_b1 = (const float*)d_in[2];
  const float* se_w2 = (const float*)d_in[3];
  const float* se_b2 = (const float*)d_in[4];
  const float* sd_w1 = (const float*)d_in[5];
  const float* sd_b1 = (const float*)d_in[6];
  const float* sd_w2 = (const float*)d_in[7];
  const float* sd_b2 = (const float*)d_in[8];
  const float* rc_w1 = (const float*)d_in[9];
  const float* rc_b1 = (const float*)d_in[10];
  const float* rc_w2 = (const float*)d_in[11];
  const float* rc_b2 = (const float*)d_in[12];
  const float* rc_w3 = (const float*)d_in[13];
  const float* rc_b3 = (const float*)d_in[14];
  const float* an_w1 = (const float*)d_in[15];
  const float* an_b1 = (const float*)d_in[16];
  const float* an_w2 = (const float*)d_in[17];
  const float* an_b2 = (const float*)d_in[18];
  float* out = (float*)d_out;
  u16* hB   = (u16*)d_ws;
  u16* blob = hB + BLOB_U16;
  (void)ws_size; (void)n_in; (void)in_sizes;  // WS_NEED 1.31 MB < proven ws_size

  hipMemsetAsync(d_out, 0, (size_t)out_size * sizeof(float), stream);
  prep_weights<<<256, TPB, 0, stream>>>(rc_w1, rc_w2, rc_w3, an_w1, an_w2, blob);
  enc_self_kernel<<<256, TPB, 0, stream>>>(s, se_w1, se_b1, se_w2, se_b2,
                                           sd_w1, sd_b1, sd_w2, sd_b2, hB, out);
  pair_mfma_kernel<<<8192, TPB, 0, stream>>>(hB, blob,
                                             rc_w1, rc_b1, rc_b2, rc_b3,
                                             an_w1, an_b1, an_b2, out);
}

// Round 6
// 239.271 us; speedup vs baseline: 3.7407x; 1.0866x over previous
//
#include <hip/hip_runtime.h>
#include <math.h>

#define TPB 256

typedef unsigned short u16;
typedef __attribute__((ext_vector_type(8))) short bf16x8;
typedef __attribute__((ext_vector_type(4))) float f32x4;

// ---------------- ws layout (u16 element offsets from d_ws) ----------------
// hB: u16[524288] @ 0 — h as single RNE bf16, row-major [b][n][64]
// blob @ 524288 — fragment-linear A images, per layer hi[OK] then lo[OK]
#define BLOB_U16 524288
#define RC1F 0       // O=128, K=64  (rc_w1 rows 64..127) T=8 OK=8192
#define AN1F 16384   // O=64,  K=64  (an_w1 rows 64..127) T=4 OK=4096
#define AN2F 24576   // O=128, K=64  T=8 OK=8192
#define RC2F 40960   // O=128, K=128 T=8 OK=16384
#define RC3F 73728   // O=128, K=128 T=8 OK=16384
#define BLOB_TOT 106496

__device__ __forceinline__ float b2f(u16 h) {
  return __uint_as_float(((unsigned)h) << 16);
}
// truncation split (for weights): x ~= hi + lo, |err| ~ 2^-17 |x|
__device__ __forceinline__ void split_bf16(float x, u16& hi, u16& lo) {
  unsigned u = __float_as_uint(x);
  hi = (u16)(u >> 16);
  float hif = __uint_as_float(u & 0xFFFF0000u);
  lo = (u16)(__float_as_uint(x - hif) >> 16);
}
// round-to-nearest-even f32 -> bf16 (used in enc only)
__device__ __forceinline__ u16 f2bf_rne(float x) {
  unsigned u = __float_as_uint(x);
  return (u16)((u + 0x7FFFu + ((u >> 16) & 1u)) >> 16);
}
// fast pack: two f32 -> bf16x2 via round-half-up + byte-perm (2 add + 1 perm)
__device__ __forceinline__ unsigned pack_bf16_hu(float v0, float v1) {
  unsigned a = __float_as_uint(v0) + 0x8000u;
  unsigned b = __float_as_uint(v1) + 0x8000u;
  return __builtin_amdgcn_perm(b, a, 0x07060302u);  // D = [hi16(a) | hi16(b)<<16]
}

__device__ __forceinline__ void cp_lds(float* dst, const float* src, int nfloats, int tid) {
  const float4* s4 = (const float4*)src;
  float4* d4 = (float4*)dst;
  const int n4 = nfloats >> 2;
  for (int i = tid; i < n4; i += TPB) d4[i] = s4[i];
}
__device__ __forceinline__ void ld4(float r[4], const float* p) {
  float4 v = *(const float4*)p;
  r[0] = v.x; r[1] = v.y; r[2] = v.z; r[3] = v.w;
}
__device__ __forceinline__ void ld2(float r[2], const float* p) {
  float2 v = *(const float2*)p;
  r[0] = v.x; r[1] = v.y;
}

// ---------------------------------------------------------------------------
// Kernel A (fused): blocks 0..255 = encoder (R1-proven 32-row shape, emits hB
// RNE bf16 + self_dyn atomicAdd); blocks 256..463 = weight prep into blob.
// ---------------------------------------------------------------------------
__global__ __launch_bounds__(TPB, 3) void enc_prep_kernel(
    const float* __restrict__ s_in,
    const float* __restrict__ se_w1, const float* __restrict__ se_b1,
    const float* __restrict__ se_w2, const float* __restrict__ se_b2,
    const float* __restrict__ sd_w1, const float* __restrict__ sd_b1,
    const float* __restrict__ sd_w2, const float* __restrict__ sd_b2,
    const float* __restrict__ rc_w1, const float* __restrict__ rc_w2,
    const float* __restrict__ rc_w3, const float* __restrict__ an_w1,
    const float* __restrict__ an_w2,
    u16* __restrict__ hB, u16* __restrict__ blob, float* __restrict__ out) {
  if (blockIdx.x >= 256) {
    // ---- prep role: split weights to bf16 hi/lo, fragment-linear A layout
    int idx = (int)(blockIdx.x - 256) * TPB + threadIdx.x;
    if (idx >= 53248) return;
    int r, base, OK, T; const float* W; int Wld, krow0;
    if (idx < 8192)       { r = idx;         base = RC1F; OK = 8192;  T = 8; W = rc_w1; Wld = 128; krow0 = 64; }
    else if (idx < 12288) { r = idx - 8192;  base = AN1F; OK = 4096;  T = 4; W = an_w1; Wld = 64;  krow0 = 64; }
    else if (idx < 20480) { r = idx - 12288; base = AN2F; OK = 8192;  T = 8; W = an_w2; Wld = 128; krow0 = 0;  }
    else if (idx < 36864) { r = idx - 20480; base = RC2F; OK = 16384; T = 8; W = rc_w2; Wld = 128; krow0 = 0;  }
    else                  { r = idx - 36864; base = RC3F; OK = 16384; T = 8; W = rc_w3; Wld = 128; krow0 = 0;  }
    const int u = r & 7;
    const int lane = (r >> 3) & 63;
    const int ct = r >> 9;
    const int c = (T == 8) ? (ct >> 3) : (ct >> 2);
    const int tg = (T == 8) ? (ct & 7) : (ct & 3);
    const int o = tg * 16 + (lane & 15);
    const int k = c * 32 + (lane >> 4) * 8 + u;
    const float x = W[(krow0 + k) * Wld + o];
    u16 hi, lo; split_bf16(x, hi, lo);
    blob[base + r] = hi;
    blob[base + OK + r] = lo;
    return;
  }

  // ---- encoder role
  __shared__ __align__(16) float sX[2048];
  __shared__ __align__(16) float sH1[2048];
  __shared__ __align__(16) float sT[4096];
  __shared__ __align__(16) float sW[4096];
  __shared__ float sb1[64], sb2[64], sdb1[128], sdb2[128];

  const int tid = threadIdx.x;
  const int lg = tid >> 5;
  const int og = tid & 31;
  const int b = blockIdx.x >> 1;
  const int row0 = b * 64 + (blockIdx.x & 1) * 32;
  const int n0 = lg * 4;

  cp_lds(sX, s_in + row0 * 64, 2048, tid);
  cp_lds(sW, se_w1, 4096, tid);
  if (tid < 64) { sb1[tid] = se_b1[tid]; sb2[tid] = se_b2[tid]; }
  else if (tid < 192) { const int o = tid - 64; sdb1[o] = sd_b1[o]; sdb2[o] = sd_b2[o]; }
  __syncthreads();

  float a2[4][2];
#pragma unroll
  for (int nn = 0; nn < 4; nn++) { a2[nn][0] = 0.f; a2[nn][1] = 0.f; }
  for (int kk = 0; kk < 64; kk += 4) {
    float xr[4][4], wr[4][2];
#pragma unroll
    for (int nn = 0; nn < 4; nn++) ld4(xr[nn], &sX[(n0 + nn) * 64 + kk]);
#pragma unroll
    for (int t = 0; t < 4; t++) ld2(wr[t], &sW[(kk + t) * 64 + og * 2]);
#pragma unroll
    for (int t = 0; t < 4; t++)
#pragma unroll
      for (int nn = 0; nn < 4; nn++) {
        a2[nn][0] = fmaf(xr[nn][t], wr[t][0], a2[nn][0]);
        a2[nn][1] = fmaf(xr[nn][t], wr[t][1], a2[nn][1]);
      }
  }
#pragma unroll
  for (int nn = 0; nn < 4; nn++) {
    float2 v;
    v.x = fmaxf(a2[nn][0] + sb1[og * 2 + 0], 0.f);
    v.y = fmaxf(a2[nn][1] + sb1[og * 2 + 1], 0.f);
    *(float2*)&sH1[(n0 + nn) * 64 + og * 2] = v;
  }
  __syncthreads();
  cp_lds(sW, se_w2, 4096, tid);
  __syncthreads();

#pragma unroll
  for (int nn = 0; nn < 4; nn++) { a2[nn][0] = 0.f; a2[nn][1] = 0.f; }
  for (int kk = 0; kk < 64; kk += 4) {
    float xr[4][4], wr[4][2];
#pragma unroll
    for (int nn = 0; nn < 4; nn++) ld4(xr[nn], &sH1[(n0 + nn) * 64 + kk]);
#pragma unroll
    for (int t = 0; t < 4; t++) ld2(wr[t], &sW[(kk + t) * 64 + og * 2]);
#pragma unroll
    for (int t = 0; t < 4; t++)
#pragma unroll
      for (int nn = 0; nn < 4; nn++) {
        a2[nn][0] = fmaf(xr[nn][t], wr[t][0], a2[nn][0]);
        a2[nn][1] = fmaf(xr[nn][t], wr[t][1], a2[nn][1]);
      }
  }
#pragma unroll
  for (int nn = 0; nn < 4; nn++) {
    float2 v;
    v.x = fmaxf(a2[nn][0] + sb2[og * 2 + 0], 0.f);
    v.y = fmaxf(a2[nn][1] + sb2[og * 2 + 1], 0.f);
    *(float2*)&sX[(n0 + nn) * 64 + og * 2] = v;
    const int off = (row0 + n0 + nn) * 64 + og * 2;
    *(ushort2*)&hB[off] = make_ushort2(f2bf_rne(v.x), f2bf_rne(v.y));
  }
  __syncthreads();

  float a4[4][4];
#pragma unroll
  for (int nn = 0; nn < 4; nn++)
#pragma unroll
    for (int oo = 0; oo < 4; oo++) a4[nn][oo] = 0.f;
  for (int c = 0; c < 2; c++) {
    cp_lds(sW, sd_w1 + c * 32 * 128, 4096, tid);
    __syncthreads();
    for (int kk = 0; kk < 32; kk += 4) {
      float xr[4][4], wr[4][4];
#pragma unroll
      for (int nn = 0; nn < 4; nn++) ld4(xr[nn], &sX[(n0 + nn) * 64 + c * 32 + kk]);
#pragma unroll
      for (int t = 0; t < 4; t++) ld4(wr[t], &sW[(kk + t) * 128 + og * 4]);
#pragma unroll
      for (int t = 0; t < 4; t++)
#pragma unroll
        for (int nn = 0; nn < 4; nn++)
#pragma unroll
          for (int oo = 0; oo < 4; oo++)
            a4[nn][oo] = fmaf(xr[nn][t], wr[t][oo], a4[nn][oo]);
    }
    __syncthreads();
  }
#pragma unroll
  for (int nn = 0; nn < 4; nn++) {
    float4 v;
    v.x = fmaxf(a4[nn][0] + sdb1[og * 4 + 0], 0.f);
    v.y = fmaxf(a4[nn][1] + sdb1[og * 4 + 1], 0.f);
    v.z = fmaxf(a4[nn][2] + sdb1[og * 4 + 2], 0.f);
    v.w = fmaxf(a4[nn][3] + sdb1[og * 4 + 3], 0.f);
    *(float4*)&sT[(n0 + nn) * 128 + og * 4] = v;
  }
  __syncthreads();

#pragma unroll
  for (int nn = 0; nn < 4; nn++)
#pragma unroll
    for (int oo = 0; oo < 4; oo++) a4[nn][oo] = 0.f;
  for (int c = 0; c < 4; c++) {
    cp_lds(sW, sd_w2 + c * 32 * 128, 4096, tid);
    __syncthreads();
    for (int kk = 0; kk < 32; kk += 4) {
      float xr[4][4], wr[4][4];
#pragma unroll
      for (int nn = 0; nn < 4; nn++) ld4(xr[nn], &sT[(n0 + nn) * 128 + c * 32 + kk]);
#pragma unroll
      for (int t = 0; t < 4; t++) ld4(wr[t], &sW[(kk + t) * 128 + og * 4]);
#pragma unroll
      for (int t = 0; t < 4; t++)
#pragma unroll
        for (int nn = 0; nn < 4; nn++)
#pragma unroll
          for (int oo = 0; oo < 4; oo++)
            a4[nn][oo] = fmaf(xr[nn][t], wr[t][oo], a4[nn][oo]);
    }
    __syncthreads();
  }
  float p[4];
#pragma unroll
  for (int oo = 0; oo < 4; oo++)
    p[oo] = a4[0][oo] + a4[1][oo] + a4[2][oo] + a4[3][oo] + 4.f * sdb2[og * 4 + oo];
  *(float4*)&sH1[lg * 128 + og * 4] = make_float4(p[0], p[1], p[2], p[3]);
  __syncthreads();
  if (tid < 128) {
    float ssum = 0.f;
#pragma unroll
    for (int g = 0; g < 8; g++) ssum += sH1[g * 128 + tid];
    atomicAdd(&out[b * 128 + tid], ssum * (1.0f / 64.0f));
  }
}

// ---------------------------------------------------------------------------
// MFMA layer (2-term). A-frags from global blob (L2); B from XOR-swizzled LDS.
// acc comes pre-initialized with bias (or base+dist). No barriers inside.
// ---------------------------------------------------------------------------
template<int MT, int NCHUNK, int RSG, int TILES>
__device__ __forceinline__ void run_layer2(f32x4 (&acc)[MT][4],
    const u16* __restrict__ blobL, int OK,
    const u16* __restrict__ sB, int tg0, int quad, int l15) {
  const int lane = quad * 16 + l15;
#pragma unroll
  for (int c = 0; c < NCHUNK; ++c) {
    bf16x8 Ah[MT], Al[MT];
#pragma unroll
    for (int t = 0; t < MT; ++t) {
      const u16* p = blobL + ((c * TILES + tg0 + t) * 64 + lane) * 8;
      Ah[t] = *(const bf16x8*)p;
      Al[t] = *(const bf16x8*)(p + OK);
    }
    const int slot = (4 * c + quad) ^ (l15 & 7);
    bf16x8 Bh[4];
#pragma unroll
    for (int s = 0; s < 4; ++s)
      Bh[s] = *(const bf16x8*)&sB[(16 * s + l15) * (RSG * 8) + slot * 8];
#pragma unroll
    for (int t = 0; t < MT; ++t)
#pragma unroll
      for (int s = 0; s < 4; ++s) {
        f32x4 a = acc[t][s];
        a = __builtin_amdgcn_mfma_f32_16x16x32_bf16(Ah[t], Bh[s], a, 0, 0, 0);
        a = __builtin_amdgcn_mfma_f32_16x16x32_bf16(Al[t], Bh[s], a, 0, 0, 0);
        acc[t][s] = a;
      }
  }
}

// relu -> half-up bf16 pack (perm) -> swizzled LDS store. Bias already in acc.
template<int MT, int RSG>
__device__ __forceinline__ void store_acts_pk(const f32x4 (&acc)[MT][4],
                                              u16* dst, int o0, int quad, int l15) {
#pragma unroll
  for (int t = 0; t < MT; ++t) {
    const int ob = o0 + 16 * t + quad * 4;
    const int slot = (ob >> 3) ^ (l15 & 7);
    const int e = ob & 7;
#pragma unroll
    for (int s = 0; s < 4; ++s) {
      const int j = 16 * s + l15;
      uint2 pk;
      pk.x = pack_bf16_hu(fmaxf(acc[t][s][0], 0.f), fmaxf(acc[t][s][1], 0.f));
      pk.y = pack_bf16_hu(fmaxf(acc[t][s][2], 0.f), fmaxf(acc[t][s][3], 0.f));
      *(uint2*)&dst[j * (RSG * 8) + slot * 8 + e] = pk;
    }
  }
}

// ---------------------------------------------------------------------------
// Kernel B (MFMA): one block per (b,i). 28 KB LDS -> 4 blocks/CU.
// L1 = K=64 over h_j only; h_i via f32 base vectors (prologue); bias folded
// into every acc init; 208 MFMA/wave (pipe floor ~54 us).
// ---------------------------------------------------------------------------
__global__ __launch_bounds__(TPB, 4) void pair_mfma_kernel(
    const u16* __restrict__ hB, const u16* __restrict__ blob,
    const float* __restrict__ rc_w1, const float* __restrict__ rc_b1,
    const float* __restrict__ rc_b2, const float* __restrict__ rc_b3,
    const float* __restrict__ an_w1, const float* __restrict__ an_b1,
    const float* __restrict__ an_b2,
    float* __restrict__ out) {
  __shared__ __align__(16) u16 sAct[64 * 128];  // 16 KB: h_j (g0..7) then rc acts (g0..15)
  __shared__ __align__(16) u16 sAn[64 * 64];    // 8 KB: an1 acts
  __shared__ float sHi[64], sDist[64];
  __shared__ float sBaseRc[128], sBaseAn[64], sW1d[128], sAnd[64];
  __shared__ float sB2[128], sB3[128], sAb2[128], sRed[128];

  const int tid = threadIdx.x;
  const int w = tid >> 6, lane = tid & 63;
  const int quad = lane >> 4, l15 = lane & 15;
  const int b = blockIdx.x >> 6, i = blockIdx.x & 63;
  const int o0 = w * 32;    // O=128 layers: tiles 2w, 2w+1
  const int o0a = w * 16;   // an1 (O=64): tile w

  // ---- stage h_j (single bf16) into granules 0..7, swizzled; constants
  {
    const float4* srcJ = (const float4*)(hB + b * 4096);
    for (int idx = tid; idx < 512; idx += TPB) {
      const int row = idx >> 3, g = idx & 7;
      *(float4*)&sAct[row * 128 + ((g ^ (row & 7)) * 8)] = srcJ[idx];
    }
  }
  if (tid < 64) sHi[tid] = b2f(hB[(b * 64 + i) * 64 + tid]);
  if (tid < 128) {
    sW1d[tid] = rc_w1[128 * 128 + tid];
    sB2[tid] = rc_b2[tid]; sB3[tid] = rc_b3[tid]; sAb2[tid] = an_b2[tid];
  } else if (tid < 192) {
    sAnd[tid - 128] = an_w1[128 * 64 + (tid - 128)];
  }
  __syncthreads();
  // ---- base vectors (h_i half of L1, f32) + dist
  if (tid < 128) {
    float acc = rc_b1[tid];
    for (int k = 0; k < 64; ++k) acc = fmaf(sHi[k], rc_w1[k * 128 + tid], acc);
    sBaseRc[tid] = acc;
  } else if (tid < 192) {
    const int o = tid - 128;
    float acc = an_b1[o];
    for (int k = 0; k < 64; ++k) acc = fmaf(sHi[k], an_w1[k * 64 + o], acc);
    sBaseAn[o] = acc;
  } else {
    const int j = tid - 192;
    const int base = j * 128 + ((0 ^ (j & 7)) * 8);  // granule 0: h_j k=0,1
    const float d0 = sHi[0] - b2f(sAct[base + 0]);
    const float d1 = sHi[1] - b2f(sAct[base + 1]);
    sDist[j] = d0 * d0 + d1 * d1;
  }
  __syncthreads();

  // ---- rc-L1 + an-L1 fused (shared B = h_j, K=64, 2-term)
  f32x4 accR[2][4];
  f32x4 accN[1][4];
  {
    float bbR[2][4], wwR[2][4], bbN[4], wwN[4];
#pragma unroll
    for (int t = 0; t < 2; ++t) {
      ld4(bbR[t], &sBaseRc[o0 + 16 * t + quad * 4]);
      ld4(wwR[t], &sW1d[o0 + 16 * t + quad * 4]);
    }
    ld4(bbN, &sBaseAn[o0a + quad * 4]);
    ld4(wwN, &sAnd[o0a + quad * 4]);
#pragma unroll
    for (int s = 0; s < 4; ++s) {
      const float dj = sDist[16 * s + l15];
#pragma unroll
      for (int t = 0; t < 2; ++t) {
        f32x4 a;
#pragma unroll
        for (int r = 0; r < 4; ++r) a[r] = fmaf(dj, wwR[t][r], bbR[t][r]);
        accR[t][s] = a;
      }
      f32x4 a;
#pragma unroll
      for (int r = 0; r < 4; ++r) a[r] = fmaf(dj, wwN[r], bbN[r]);
      accN[0][s] = a;
    }
  }
  {
    const int lane64 = quad * 16 + l15;
#pragma unroll
    for (int c = 0; c < 2; ++c) {
      bf16x8 Ah[2], Al[2], AhN, AlN;
#pragma unroll
      for (int t = 0; t < 2; ++t) {
        const u16* p = blob + RC1F + ((c * 8 + 2 * w + t) * 64 + lane64) * 8;
        Ah[t] = *(const bf16x8*)p;
        Al[t] = *(const bf16x8*)(p + 8192);
      }
      {
        const u16* p = blob + AN1F + ((c * 4 + w) * 64 + lane64) * 8;
        AhN = *(const bf16x8*)p;
        AlN = *(const bf16x8*)(p + 4096);
      }
      const int slot = (4 * c + quad) ^ (l15 & 7);
      bf16x8 Bh[4];
#pragma unroll
      for (int s = 0; s < 4; ++s)
        Bh[s] = *(const bf16x8*)&sAct[(16 * s + l15) * 128 + slot * 8];
#pragma unroll
      for (int s = 0; s < 4; ++s) {
#pragma unroll
        for (int t = 0; t < 2; ++t) {
          f32x4 a = accR[t][s];
          a = __builtin_amdgcn_mfma_f32_16x16x32_bf16(Ah[t], Bh[s], a, 0, 0, 0);
          a = __builtin_amdgcn_mfma_f32_16x16x32_bf16(Al[t], Bh[s], a, 0, 0, 0);
          accR[t][s] = a;
        }
        f32x4 a = accN[0][s];
        a = __builtin_amdgcn_mfma_f32_16x16x32_bf16(AhN, Bh[s], a, 0, 0, 0);
        a = __builtin_amdgcn_mfma_f32_16x16x32_bf16(AlN, Bh[s], a, 0, 0, 0);
        accN[0][s] = a;
      }
    }
  }
  store_acts_pk<1, 8>(accN, sAn, o0a, quad, l15);  // sAn untouched until an2
  __syncthreads();  // h_j fully consumed
  store_acts_pk<2, 16>(accR, sAct, o0, quad, l15); // rc1 acts (granules 0..15)
  __syncthreads();

  // ---- an-L2 -> att in regs (init = an_b2)
  f32x4 accT[2][4];
  {
    float bb[2][4];
#pragma unroll
    for (int t = 0; t < 2; ++t) ld4(bb[t], &sAb2[o0 + 16 * t + quad * 4]);
#pragma unroll
    for (int t = 0; t < 2; ++t)
#pragma unroll
      for (int s = 0; s < 4; ++s) {
        f32x4 a;
#pragma unroll
        for (int r = 0; r < 4; ++r) a[r] = bb[t][r];
        accT[t][s] = a;
      }
  }
  run_layer2<2, 2, 8, 8>(accT, blob + AN2F, 8192, sAn, 2 * w, quad, l15);
  float att[2][4][4];
#pragma unroll
  for (int t = 0; t < 2; ++t)
#pragma unroll
    for (int s = 0; s < 4; ++s)
#pragma unroll
      for (int r = 0; r < 4; ++r)
        att[t][s][r] = 1.0f / (1.0f + __expf(-accT[t][s][r]));

  // ---- rc-L2 (init = rc_b2), write back in place
  {
    float bb[2][4];
#pragma unroll
    for (int t = 0; t < 2; ++t) ld4(bb[t], &sB2[o0 + 16 * t + quad * 4]);
#pragma unroll
    for (int t = 0; t < 2; ++t)
#pragma unroll
      for (int s = 0; s < 4; ++s) {
        f32x4 a;
#pragma unroll
        for (int r = 0; r < 4; ++r) a[r] = bb[t][r];
        accR[t][s] = a;
      }
  }
  run_layer2<2, 4, 16, 8>(accR, blob + RC2F, 16384, sAct, 2 * w, quad, l15);
  __syncthreads();
  store_acts_pk<2, 16>(accR, sAct, o0, quad, l15);
  __syncthreads();

  // ---- rc-L3 (init = rc_b3) + rel*att + reduce over j
  {
    float bb[2][4];
#pragma unroll
    for (int t = 0; t < 2; ++t) ld4(bb[t], &sB3[o0 + 16 * t + quad * 4]);
#pragma unroll
    for (int t = 0; t < 2; ++t)
#pragma unroll
      for (int s = 0; s < 4; ++s) {
        f32x4 a;
#pragma unroll
        for (int r = 0; r < 4; ++r) a[r] = bb[t][r];
        accR[t][s] = a;
      }
  }
  run_layer2<2, 4, 16, 8>(accR, blob + RC3F, 16384, sAct, 2 * w, quad, l15);
  float ps[2][4] = {{0.f, 0.f, 0.f, 0.f}, {0.f, 0.f, 0.f, 0.f}};
#pragma unroll
  for (int t = 0; t < 2; ++t)
#pragma unroll
    for (int s = 0; s < 4; ++s)
#pragma unroll
      for (int r = 0; r < 4; ++r) {
        const float rel = fmaxf(accR[t][s][r], 0.f);
        ps[t][r] = fmaf(rel, att[t][s][r], ps[t][r]);
      }
#pragma unroll
  for (int t = 0; t < 2; ++t)
#pragma unroll
    for (int r = 0; r < 4; ++r) {
      float v = ps[t][r];
      v += __shfl_xor(v, 1, 64);
      v += __shfl_xor(v, 2, 64);
      v += __shfl_xor(v, 4, 64);
      v += __shfl_xor(v, 8, 64);
      ps[t][r] = v;
    }
  if (l15 == 0) {
#pragma unroll
    for (int t = 0; t < 2; ++t)
#pragma unroll
      for (int r = 0; r < 4; ++r)
        sRed[o0 + 16 * t + quad * 4 + r] = ps[t][r];
  }
  __syncthreads();
  if (tid < 128)
    atomicAdd(&out[b * 128 + tid], sRed[tid] * (1.0f / 4096.0f));
}

extern "C" void kernel_launch(void* const* d_in, const int* in_sizes, int n_in,
                              void* d_out, int out_size, void* d_ws, size_t ws_size,
                              hipStream_t stream) {
  const float* s     = (const float*)d_in[0];
  const float* se_w1 = (const float*)d_in[1];
  const float* se_b1 = (const float*)d_in[2];
  const float* se_w2 = (const float*)d_in[3];
  const float* se_b2 = (const float*)d_in[4];
  const float* sd_w1 = (const float*)d_in[5];
  const float* sd_b1 = (const float*)d_in[6];
  const float* sd_w2 = (const float*)d_in[7];
  const float* sd_b2 = (const float*)d_in[8];
  const float* rc_w1 = (const float*)d_in[9];
  const float* rc_b1 = (const float*)d_in[10];
  const float* rc_w2 = (const float*)d_in[11];
  const float* rc_b2 = (const float*)d_in[12];
  const float* rc_w3 = (const float*)d_in[13];
  const float* rc_b3 = (const float*)d_in[14];
  const float* an_w1 = (const float*)d_in[15];
  const float* an_b1 = (const float*)d_in[16];
  const float* an_w2 = (const float*)d_in[17];
  const float* an_b2 = (const float*)d_in[18];
  float* out = (float*)d_out;
  u16* hB   = (u16*)d_ws;
  u16* blob = hB + BLOB_U16;
  (void)ws_size; (void)n_in; (void)in_sizes;  // needs 1.26 MB < proven ws sizes

  hipMemsetAsync(d_out, 0, (size_t)out_size * sizeof(float), stream);
  enc_prep_kernel<<<464, TPB, 0, stream>>>(s, se_w1, se_b1, se_w2, se_b2,
                                           sd_w1, sd_b1, sd_w2, sd_b2,
                                           rc_w1, rc_w2, rc_w3, an_w1, an_w2,
                                           hB, blob, out);
  pair_mfma_kernel<<<8192, TPB, 0, stream>>>(hB, blob,
                                             rc_w1, rc_b1, rc_b2, rc_b3,
                                             an_w1, an_b1, an_b2, out);
}

// Round 7
// 212.961 us; speedup vs baseline: 4.2028x; 1.1235x over previous
//
#include <hip/hip_runtime.h>
#include <math.h>

#define TPB 256

typedef unsigned short u16;
typedef __attribute__((ext_vector_type(8))) short bf16x8;
typedef __attribute__((ext_vector_type(4))) float f32x4;

// ---------------- ws layout ----------------
// hB  : u16[524288]  @ u16 off 0        (1 MB)  h as RNE bf16 [b][n][64]
// blob: u16[106496]  @ u16 off 524288   (208 KB) fragment-linear A images
// baseRc: f32[8192*128] @ f32 off 327680 (4 MB)
// baseAn: f32[8192*64]  @ f32 off 1376256 (2 MB)
#define BLOB_U16 524288
#define BASE_RC_F32 327680
#define BASE_AN_F32 1376256
#define WS_NEED_BASES ((size_t)(1376256 + 524288) * 4)  // ~7.6 MB
// blob-internal u16 offsets (hi[OK] then lo[OK]; lo unused for hi-only layers)
#define RC1F 0       // O=128, K=64  (rc_w1 rows 64..127) T=8 OK=8192  [2-term]
#define AN1F 16384   // O=64,  K=64  (an_w1 rows 64..127) T=4 OK=4096  [2-term]
#define AN2F 24576   // O=128, K=64  T=8 OK=8192  [hi-only RNE]
#define RC2F 40960   // O=128, K=128 T=8 OK=16384 [hi-only RNE]
#define RC3F 73728   // O=128, K=128 T=8 OK=16384 [hi-only RNE]

__device__ __forceinline__ float b2f(u16 h) {
  return __uint_as_float(((unsigned)h) << 16);
}
__device__ __forceinline__ void split_bf16(float x, u16& hi, u16& lo) {
  unsigned u = __float_as_uint(x);
  hi = (u16)(u >> 16);
  float hif = __uint_as_float(u & 0xFFFF0000u);
  lo = (u16)(__float_as_uint(x - hif) >> 16);
}
__device__ __forceinline__ u16 f2bf_rne(float x) {
  unsigned u = __float_as_uint(x);
  return (u16)((u + 0x7FFFu + ((u >> 16) & 1u)) >> 16);
}
// fast pack: two f32 -> bf16x2 via round-half-up + byte-perm
__device__ __forceinline__ unsigned pack_bf16_hu(float v0, float v1) {
  unsigned a = __float_as_uint(v0) + 0x8000u;
  unsigned b = __float_as_uint(v1) + 0x8000u;
  return __builtin_amdgcn_perm(b, a, 0x07060302u);
}

__device__ __forceinline__ void cp_lds(float* dst, const float* src, int nfloats, int tid) {
  const float4* s4 = (const float4*)src;
  float4* d4 = (float4*)dst;
  const int n4 = nfloats >> 2;
  for (int i = tid; i < n4; i += TPB) d4[i] = s4[i];
}
__device__ __forceinline__ void ld4(float r[4], const float* p) {
  float4 v = *(const float4*)p;
  r[0] = v.x; r[1] = v.y; r[2] = v.z; r[3] = v.w;
}
__device__ __forceinline__ void ld2(float r[2], const float* p) {
  float2 v = *(const float2*)p;
  r[0] = v.x; r[1] = v.y;
}

// ---------------------------------------------------------------------------
// Kernel A (fused): blocks 0..255 = encoder (32 rows each): h -> hB, self_dyn
// -> out (atomic), and (do_bases) baseRc/baseAn from f32 h. Blocks 256..463 =
// weight prep into blob.
// ---------------------------------------------------------------------------
__global__ __launch_bounds__(TPB, 3) void enc_prep_kernel(
    const float* __restrict__ s_in,
    const float* __restrict__ se_w1, const float* __restrict__ se_b1,
    const float* __restrict__ se_w2, const float* __restrict__ se_b2,
    const float* __restrict__ sd_w1, const float* __restrict__ sd_b1,
    const float* __restrict__ sd_w2, const float* __restrict__ sd_b2,
    const float* __restrict__ rc_w1, const float* __restrict__ rc_b1,
    const float* __restrict__ rc_w2, const float* __restrict__ rc_w3,
    const float* __restrict__ an_w1, const float* __restrict__ an_b1,
    const float* __restrict__ an_w2,
    u16* __restrict__ hB, u16* __restrict__ blob,
    float* __restrict__ baseRcG, float* __restrict__ baseAnG, int do_bases,
    float* __restrict__ out) {
  if (blockIdx.x >= 256) {
    // ---- prep role
    int idx = (int)(blockIdx.x - 256) * TPB + threadIdx.x;
    if (idx >= 53248) return;
    int r, base, OK, T; const float* W; int Wld, krow0, twoTerm;
    if (idx < 8192)       { r = idx;         base = RC1F; OK = 8192;  T = 8; W = rc_w1; Wld = 128; krow0 = 64; twoTerm = 1; }
    else if (idx < 12288) { r = idx - 8192;  base = AN1F; OK = 4096;  T = 4; W = an_w1; Wld = 64;  krow0 = 64; twoTerm = 1; }
    else if (idx < 20480) { r = idx - 12288; base = AN2F; OK = 8192;  T = 8; W = an_w2; Wld = 128; krow0 = 0;  twoTerm = 0; }
    else if (idx < 36864) { r = idx - 20480; base = RC2F; OK = 16384; T = 8; W = rc_w2; Wld = 128; krow0 = 0;  twoTerm = 0; }
    else                  { r = idx - 36864; base = RC3F; OK = 16384; T = 8; W = rc_w3; Wld = 128; krow0 = 0;  twoTerm = 0; }
    const int u = r & 7;
    const int lane = (r >> 3) & 63;
    const int ct = r >> 9;
    const int c = (T == 8) ? (ct >> 3) : (ct >> 2);
    const int tg = (T == 8) ? (ct & 7) : (ct & 3);
    const int o = tg * 16 + (lane & 15);
    const int k = c * 32 + (lane >> 4) * 8 + u;
    const float x = W[(krow0 + k) * Wld + o];
    if (twoTerm) {
      u16 hi, lo; split_bf16(x, hi, lo);
      blob[base + r] = hi;
      blob[base + OK + r] = lo;
    } else {
      blob[base + r] = f2bf_rne(x);
    }
    return;
  }

  // ---- encoder role
  __shared__ __align__(16) float sX[2048];
  __shared__ __align__(16) float sH1[2048];
  __shared__ __align__(16) float sT[4096];
  __shared__ __align__(16) float sW[4096];
  __shared__ float sb1[64], sb2[64], sdb1[128], sdb2[128], srb1[128], sab1[64];

  const int tid = threadIdx.x;
  const int lg = tid >> 5;
  const int og = tid & 31;
  const int b = blockIdx.x >> 1;
  const int row0 = b * 64 + (blockIdx.x & 1) * 32;
  const int n0 = lg * 4;

  cp_lds(sX, s_in + row0 * 64, 2048, tid);
  cp_lds(sW, se_w1, 4096, tid);
  if (tid < 64) { sb1[tid] = se_b1[tid]; sb2[tid] = se_b2[tid]; }
  else if (tid < 192) { const int o = tid - 64; sdb1[o] = sd_b1[o]; sdb2[o] = sd_b2[o]; }
  if (tid < 128) srb1[tid] = rc_b1[tid];
  else if (tid < 192) sab1[tid - 128] = an_b1[tid - 128];
  __syncthreads();

  float a2[4][2];
#pragma unroll
  for (int nn = 0; nn < 4; nn++) { a2[nn][0] = 0.f; a2[nn][1] = 0.f; }
  for (int kk = 0; kk < 64; kk += 4) {
    float xr[4][4], wr[4][2];
#pragma unroll
    for (int nn = 0; nn < 4; nn++) ld4(xr[nn], &sX[(n0 + nn) * 64 + kk]);
#pragma unroll
    for (int t = 0; t < 4; t++) ld2(wr[t], &sW[(kk + t) * 64 + og * 2]);
#pragma unroll
    for (int t = 0; t < 4; t++)
#pragma unroll
      for (int nn = 0; nn < 4; nn++) {
        a2[nn][0] = fmaf(xr[nn][t], wr[t][0], a2[nn][0]);
        a2[nn][1] = fmaf(xr[nn][t], wr[t][1], a2[nn][1]);
      }
  }
#pragma unroll
  for (int nn = 0; nn < 4; nn++) {
    float2 v;
    v.x = fmaxf(a2[nn][0] + sb1[og * 2 + 0], 0.f);
    v.y = fmaxf(a2[nn][1] + sb1[og * 2 + 1], 0.f);
    *(float2*)&sH1[(n0 + nn) * 64 + og * 2] = v;
  }
  __syncthreads();
  cp_lds(sW, se_w2, 4096, tid);
  __syncthreads();

#pragma unroll
  for (int nn = 0; nn < 4; nn++) { a2[nn][0] = 0.f; a2[nn][1] = 0.f; }
  for (int kk = 0; kk < 64; kk += 4) {
    float xr[4][4], wr[4][2];
#pragma unroll
    for (int nn = 0; nn < 4; nn++) ld4(xr[nn], &sH1[(n0 + nn) * 64 + kk]);
#pragma unroll
    for (int t = 0; t < 4; t++) ld2(wr[t], &sW[(kk + t) * 64 + og * 2]);
#pragma unroll
    for (int t = 0; t < 4; t++)
#pragma unroll
      for (int nn = 0; nn < 4; nn++) {
        a2[nn][0] = fmaf(xr[nn][t], wr[t][0], a2[nn][0]);
        a2[nn][1] = fmaf(xr[nn][t], wr[t][1], a2[nn][1]);
      }
  }
#pragma unroll
  for (int nn = 0; nn < 4; nn++) {
    float2 v;
    v.x = fmaxf(a2[nn][0] + sb2[og * 2 + 0], 0.f);
    v.y = fmaxf(a2[nn][1] + sb2[og * 2 + 1], 0.f);
    *(float2*)&sX[(n0 + nn) * 64 + og * 2] = v;
    const int off = (row0 + n0 + nn) * 64 + og * 2;
    *(ushort2*)&hB[off] = make_ushort2(f2bf_rne(v.x), f2bf_rne(v.y));
  }
  __syncthreads();

  float a4[4][4];
#pragma unroll
  for (int nn = 0; nn < 4; nn++)
#pragma unroll
    for (int oo = 0; oo < 4; oo++) a4[nn][oo] = 0.f;
  for (int c = 0; c < 2; c++) {
    cp_lds(sW, sd_w1 + c * 32 * 128, 4096, tid);
    __syncthreads();
    for (int kk = 0; kk < 32; kk += 4) {
      float xr[4][4], wr[4][4];
#pragma unroll
      for (int nn = 0; nn < 4; nn++) ld4(xr[nn], &sX[(n0 + nn) * 64 + c * 32 + kk]);
#pragma unroll
      for (int t = 0; t < 4; t++) ld4(wr[t], &sW[(kk + t) * 128 + og * 4]);
#pragma unroll
      for (int t = 0; t < 4; t++)
#pragma unroll
        for (int nn = 0; nn < 4; nn++)
#pragma unroll
          for (int oo = 0; oo < 4; oo++)
            a4[nn][oo] = fmaf(xr[nn][t], wr[t][oo], a4[nn][oo]);
    }
    __syncthreads();
  }
#pragma unroll
  for (int nn = 0; nn < 4; nn++) {
    float4 v;
    v.x = fmaxf(a4[nn][0] + sdb1[og * 4 + 0], 0.f);
    v.y = fmaxf(a4[nn][1] + sdb1[og * 4 + 1], 0.f);
    v.z = fmaxf(a4[nn][2] + sdb1[og * 4 + 2], 0.f);
    v.w = fmaxf(a4[nn][3] + sdb1[og * 4 + 3], 0.f);
    *(float4*)&sT[(n0 + nn) * 128 + og * 4] = v;
  }
  __syncthreads();

#pragma unroll
  for (int nn = 0; nn < 4; nn++)
#pragma unroll
    for (int oo = 0; oo < 4; oo++) a4[nn][oo] = 0.f;
  for (int c = 0; c < 4; c++) {
    cp_lds(sW, sd_w2 + c * 32 * 128, 4096, tid);
    __syncthreads();
    for (int kk = 0; kk < 32; kk += 4) {
      float xr[4][4], wr[4][4];
#pragma unroll
      for (int nn = 0; nn < 4; nn++) ld4(xr[nn], &sT[(n0 + nn) * 128 + c * 32 + kk]);
#pragma unroll
      for (int t = 0; t < 4; t++) ld4(wr[t], &sW[(kk + t) * 128 + og * 4]);
#pragma unroll
      for (int t = 0; t < 4; t++)
#pragma unroll
        for (int nn = 0; nn < 4; nn++)
#pragma unroll
          for (int oo = 0; oo < 4; oo++)
            a4[nn][oo] = fmaf(xr[nn][t], wr[t][oo], a4[nn][oo]);
    }
    __syncthreads();
  }
  float p[4];
#pragma unroll
  for (int oo = 0; oo < 4; oo++)
    p[oo] = a4[0][oo] + a4[1][oo] + a4[2][oo] + a4[3][oo] + 4.f * sdb2[og * 4 + oo];
  *(float4*)&sH1[lg * 128 + og * 4] = make_float4(p[0], p[1], p[2], p[3]);
  __syncthreads();
  if (tid < 128) {
    float ssum = 0.f;
#pragma unroll
    for (int g = 0; g < 8; g++) ssum += sH1[g * 128 + tid];
    atomicAdd(&out[b * 128 + tid], ssum * (1.0f / 64.0f));
  }

  // ---- base vectors from f32 h (sX): baseRc = rc_b1 + h @ rc_w1[0:64],
  //      baseAn = an_b1 + h @ an_w1[0:64]
  if (do_bases) {
#pragma unroll
    for (int nn = 0; nn < 4; nn++)
#pragma unroll
      for (int oo = 0; oo < 4; oo++) a4[nn][oo] = 0.f;
    for (int c = 0; c < 2; c++) {
      __syncthreads();
      cp_lds(sW, rc_w1 + c * 32 * 128, 4096, tid);
      __syncthreads();
      for (int kk = 0; kk < 32; kk += 4) {
        float xr[4][4], wr[4][4];
#pragma unroll
        for (int nn = 0; nn < 4; nn++) ld4(xr[nn], &sX[(n0 + nn) * 64 + c * 32 + kk]);
#pragma unroll
        for (int t = 0; t < 4; t++) ld4(wr[t], &sW[(kk + t) * 128 + og * 4]);
#pragma unroll
        for (int t = 0; t < 4; t++)
#pragma unroll
          for (int nn = 0; nn < 4; nn++)
#pragma unroll
            for (int oo = 0; oo < 4; oo++)
              a4[nn][oo] = fmaf(xr[nn][t], wr[t][oo], a4[nn][oo]);
      }
    }
#pragma unroll
    for (int nn = 0; nn < 4; nn++) {
      float4 v;
      v.x = a4[nn][0] + srb1[og * 4 + 0];
      v.y = a4[nn][1] + srb1[og * 4 + 1];
      v.z = a4[nn][2] + srb1[og * 4 + 2];
      v.w = a4[nn][3] + srb1[og * 4 + 3];
      *(float4*)&baseRcG[(size_t)(row0 + n0 + nn) * 128 + og * 4] = v;
    }
    __syncthreads();
    cp_lds(sW, an_w1, 4096, tid);  // rows 0..63 x 64
    __syncthreads();
#pragma unroll
    for (int nn = 0; nn < 4; nn++) { a2[nn][0] = 0.f; a2[nn][1] = 0.f; }
    for (int kk = 0; kk < 64; kk += 4) {
      float xr[4][4], wr[4][2];
#pragma unroll
      for (int nn = 0; nn < 4; nn++) ld4(xr[nn], &sX[(n0 + nn) * 64 + kk]);
#pragma unroll
      for (int t = 0; t < 4; t++) ld2(wr[t], &sW[(kk + t) * 64 + og * 2]);
#pragma unroll
      for (int t = 0; t < 4; t++)
#pragma unroll
        for (int nn = 0; nn < 4; nn++) {
          a2[nn][0] = fmaf(xr[nn][t], wr[t][0], a2[nn][0]);
          a2[nn][1] = fmaf(xr[nn][t], wr[t][1], a2[nn][1]);
        }
    }
#pragma unroll
    for (int nn = 0; nn < 4; nn++) {
      float2 v;
      v.x = a2[nn][0] + sab1[og * 2 + 0];
      v.y = a2[nn][1] + sab1[og * 2 + 1];
      *(float2*)&baseAnG[(size_t)(row0 + n0 + nn) * 64 + og * 2] = v;
    }
  }
}

// ---------------------------------------------------------------------------
// MFMA layers. A-frags from global blob (L2); B from XOR-swizzled LDS.
// run_layer2 = weights split hi/lo (2 MFMA per frag); run_layer1 = hi-only.
// ---------------------------------------------------------------------------
template<int MT, int NCHUNK, int RSG, int TILES>
__device__ __forceinline__ void run_layer2(f32x4 (&acc)[MT][4],
    const u16* __restrict__ blobL, int OK,
    const u16* __restrict__ sB, int tg0, int quad, int l15) {
  const int lane = quad * 16 + l15;
#pragma unroll
  for (int c = 0; c < NCHUNK; ++c) {
    bf16x8 Ah[MT], Al[MT];
#pragma unroll
    for (int t = 0; t < MT; ++t) {
      const u16* p = blobL + ((c * TILES + tg0 + t) * 64 + lane) * 8;
      Ah[t] = *(const bf16x8*)p;
      Al[t] = *(const bf16x8*)(p + OK);
    }
    const int slot = (4 * c + quad) ^ (l15 & 7);
    bf16x8 Bh[4];
#pragma unroll
    for (int s = 0; s < 4; ++s)
      Bh[s] = *(const bf16x8*)&sB[(16 * s + l15) * (RSG * 8) + slot * 8];
#pragma unroll
    for (int t = 0; t < MT; ++t)
#pragma unroll
      for (int s = 0; s < 4; ++s) {
        f32x4 a = acc[t][s];
        a = __builtin_amdgcn_mfma_f32_16x16x32_bf16(Ah[t], Bh[s], a, 0, 0, 0);
        a = __builtin_amdgcn_mfma_f32_16x16x32_bf16(Al[t], Bh[s], a, 0, 0, 0);
        acc[t][s] = a;
      }
  }
}

template<int MT, int NCHUNK, int RSG, int TILES>
__device__ __forceinline__ void run_layer1(f32x4 (&acc)[MT][4],
    const u16* __restrict__ blobL,
    const u16* __restrict__ sB, int tg0, int quad, int l15) {
  const int lane = quad * 16 + l15;
#pragma unroll
  for (int c = 0; c < NCHUNK; ++c) {
    bf16x8 Ah[MT];
#pragma unroll
    for (int t = 0; t < MT; ++t)
      Ah[t] = *(const bf16x8*)(blobL + ((c * TILES + tg0 + t) * 64 + lane) * 8);
    const int slot = (4 * c + quad) ^ (l15 & 7);
    bf16x8 Bh[4];
#pragma unroll
    for (int s = 0; s < 4; ++s)
      Bh[s] = *(const bf16x8*)&sB[(16 * s + l15) * (RSG * 8) + slot * 8];
#pragma unroll
    for (int t = 0; t < MT; ++t)
#pragma unroll
      for (int s = 0; s < 4; ++s)
        acc[t][s] = __builtin_amdgcn_mfma_f32_16x16x32_bf16(Ah[t], Bh[s], acc[t][s], 0, 0, 0);
  }
}

// relu -> half-up bf16 pack -> swizzled LDS store. Bias already in acc.
template<int MT, int RSG>
__device__ __forceinline__ void store_acts_pk(const f32x4 (&acc)[MT][4],
                                              u16* dst, int o0, int quad, int l15) {
#pragma unroll
  for (int t = 0; t < MT; ++t) {
    const int ob = o0 + 16 * t + quad * 4;
    const int slot = (ob >> 3) ^ (l15 & 7);
    const int e = ob & 7;
#pragma unroll
    for (int s = 0; s < 4; ++s) {
      const int j = 16 * s + l15;
      uint2 pk;
      pk.x = pack_bf16_hu(fmaxf(acc[t][s][0], 0.f), fmaxf(acc[t][s][1], 0.f));
      pk.y = pack_bf16_hu(fmaxf(acc[t][s][2], 0.f), fmaxf(acc[t][s][3], 0.f));
      *(uint2*)&dst[j * (RSG * 8) + slot * 8 + e] = pk;
    }
  }
}

// ---------------------------------------------------------------------------
// Kernel B (MFMA): one block per (b,i). 28 KB LDS -> 4 blocks/CU. 128 MFMA/wave.
// Bases precomputed (has_bases) -> prologue is pure coalesced loads.
// ---------------------------------------------------------------------------
__global__ __launch_bounds__(TPB, 4) void pair_mfma_kernel(
    const u16* __restrict__ hB, const u16* __restrict__ blob,
    const float* __restrict__ baseRcG, const float* __restrict__ baseAnG,
    int has_bases,
    const float* __restrict__ rc_w1, const float* __restrict__ rc_b1,
    const float* __restrict__ rc_b2, const float* __restrict__ rc_b3,
    const float* __restrict__ an_w1, const float* __restrict__ an_b1,
    const float* __restrict__ an_b2,
    float* __restrict__ out) {
  __shared__ __align__(16) u16 sAct[64 * 128];  // 16 KB: h_j (g0..7) then rc acts
  __shared__ __align__(16) u16 sAn[64 * 64];    // 8 KB: an1 acts
  __shared__ float sHi[64], sDist[64];
  __shared__ float sBaseRc[128], sBaseAn[64], sW1d[128], sAnd[64];
  __shared__ float sB2[128], sB3[128], sAb2[128], sRed[128];

  const int tid = threadIdx.x;
  const int w = tid >> 6, lane = tid & 63;
  const int quad = lane >> 4, l15 = lane & 15;
  const int b = blockIdx.x >> 6, i = blockIdx.x & 63;
  const int o0 = w * 32;
  const int o0a = w * 16;

  // ---- stage h_j swizzled; bases; constants
  {
    const float4* srcJ = (const float4*)(hB + b * 4096);
    for (int idx = tid; idx < 512; idx += TPB) {
      const int row = idx >> 3, g = idx & 7;
      *(float4*)&sAct[row * 128 + ((g ^ (row & 7)) * 8)] = srcJ[idx];
    }
  }
  if (has_bases) {
    const float4* bR = (const float4*)(baseRcG + (size_t)(b * 64 + i) * 128);
    const float4* bA = (const float4*)(baseAnG + (size_t)(b * 64 + i) * 64);
    if (tid < 32) ((float4*)sBaseRc)[tid] = bR[tid];
    else if (tid < 48) ((float4*)sBaseAn)[tid - 32] = bA[tid - 32];
  }
  if (tid < 64) sHi[tid] = b2f(hB[(b * 64 + i) * 64 + tid]);
  if (tid < 128) {
    sW1d[tid] = rc_w1[128 * 128 + tid];
    sB2[tid] = rc_b2[tid]; sB3[tid] = rc_b3[tid]; sAb2[tid] = an_b2[tid];
  } else if (tid < 192) {
    sAnd[tid - 128] = an_w1[128 * 64 + (tid - 128)];
  }
  __syncthreads();
  if (!has_bases) {
    if (tid < 128) {
      float acc = rc_b1[tid];
      for (int k = 0; k < 64; ++k) acc = fmaf(sHi[k], rc_w1[k * 128 + tid], acc);
      sBaseRc[tid] = acc;
    } else if (tid < 192) {
      const int o = tid - 128;
      float acc = an_b1[o];
      for (int k = 0; k < 64; ++k) acc = fmaf(sHi[k], an_w1[k * 64 + o], acc);
      sBaseAn[o] = acc;
    }
  }
  if (tid >= 192) {
    const int j = tid - 192;
    const int base = j * 128 + ((0 ^ (j & 7)) * 8);  // granule 0: h_j k=0,1
    const float d0 = sHi[0] - b2f(sAct[base + 0]);
    const float d1 = sHi[1] - b2f(sAct[base + 1]);
    sDist[j] = d0 * d0 + d1 * d1;
  }
  __syncthreads();

  // ---- rc-L1 + an-L1 fused (shared B = h_j, K=64, 2-term weights)
  f32x4 accR[2][4];
  f32x4 accN[1][4];
  {
    float bbR[2][4], wwR[2][4], bbN[4], wwN[4];
#pragma unroll
    for (int t = 0; t < 2; ++t) {
      ld4(bbR[t], &sBaseRc[o0 + 16 * t + quad * 4]);
      ld4(wwR[t], &sW1d[o0 + 16 * t + quad * 4]);
    }
    ld4(bbN, &sBaseAn[o0a + quad * 4]);
    ld4(wwN, &sAnd[o0a + quad * 4]);
#pragma unroll
    for (int s = 0; s < 4; ++s) {
      const float dj = sDist[16 * s + l15];
#pragma unroll
      for (int t = 0; t < 2; ++t) {
        f32x4 a;
#pragma unroll
        for (int r = 0; r < 4; ++r) a[r] = fmaf(dj, wwR[t][r], bbR[t][r]);
        accR[t][s] = a;
      }
      f32x4 a;
#pragma unroll
      for (int r = 0; r < 4; ++r) a[r] = fmaf(dj, wwN[r], bbN[r]);
      accN[0][s] = a;
    }
  }
  {
    const int lane64 = quad * 16 + l15;
#pragma unroll
    for (int c = 0; c < 2; ++c) {
      bf16x8 Ah[2], Al[2], AhN, AlN;
#pragma unroll
      for (int t = 0; t < 2; ++t) {
        const u16* p = blob + RC1F + ((c * 8 + 2 * w + t) * 64 + lane64) * 8;
        Ah[t] = *(const bf16x8*)p;
        Al[t] = *(const bf16x8*)(p + 8192);
      }
      {
        const u16* p = blob + AN1F + ((c * 4 + w) * 64 + lane64) * 8;
        AhN = *(const bf16x8*)p;
        AlN = *(const bf16x8*)(p + 4096);
      }
      const int slot = (4 * c + quad) ^ (l15 & 7);
      bf16x8 Bh[4];
#pragma unroll
      for (int s = 0; s < 4; ++s)
        Bh[s] = *(const bf16x8*)&sAct[(16 * s + l15) * 128 + slot * 8];
#pragma unroll
      for (int s = 0; s < 4; ++s) {
#pragma unroll
        for (int t = 0; t < 2; ++t) {
          f32x4 a = accR[t][s];
          a = __builtin_amdgcn_mfma_f32_16x16x32_bf16(Ah[t], Bh[s], a, 0, 0, 0);
          a = __builtin_amdgcn_mfma_f32_16x16x32_bf16(Al[t], Bh[s], a, 0, 0, 0);
          accR[t][s] = a;
        }
        f32x4 a = accN[0][s];
        a = __builtin_amdgcn_mfma_f32_16x16x32_bf16(AhN, Bh[s], a, 0, 0, 0);
        a = __builtin_amdgcn_mfma_f32_16x16x32_bf16(AlN, Bh[s], a, 0, 0, 0);
        accN[0][s] = a;
      }
    }
  }
  store_acts_pk<1, 8>(accN, sAn, o0a, quad, l15);  // sAn untouched until an2
  __syncthreads();  // h_j fully consumed
  store_acts_pk<2, 16>(accR, sAct, o0, quad, l15); // rc1 acts
  __syncthreads();

  // ---- an-L2 -> att in regs (init = an_b2), hi-only weights
  f32x4 accT[2][4];
  {
    float bb[2][4];
#pragma unroll
    for (int t = 0; t < 2; ++t) ld4(bb[t], &sAb2[o0 + 16 * t + quad * 4]);
#pragma unroll
    for (int t = 0; t < 2; ++t)
#pragma unroll
      for (int s = 0; s < 4; ++s) {
        f32x4 a;
#pragma unroll
        for (int r = 0; r < 4; ++r) a[r] = bb[t][r];
        accT[t][s] = a;
      }
  }
  run_layer1<2, 2, 8, 8>(accT, blob + AN2F, sAn, 2 * w, quad, l15);
  float att[2][4][4];
#pragma unroll
  for (int t = 0; t < 2; ++t)
#pragma unroll
    for (int s = 0; s < 4; ++s)
#pragma unroll
      for (int r = 0; r < 4; ++r)
        att[t][s][r] = 1.0f / (1.0f + __expf(-accT[t][s][r]));

  // ---- rc-L2 (init = rc_b2), hi-only, write back in place
  {
    float bb[2][4];
#pragma unroll
    for (int t = 0; t < 2; ++t) ld4(bb[t], &sB2[o0 + 16 * t + quad * 4]);
#pragma unroll
    for (int t = 0; t < 2; ++t)
#pragma unroll
      for (int s = 0; s < 4; ++s) {
        f32x4 a;
#pragma unroll
        for (int r = 0; r < 4; ++r) a[r] = bb[t][r];
        accR[t][s] = a;
      }
  }
  run_layer1<2, 4, 16, 8>(accR, blob + RC2F, sAct, 2 * w, quad, l15);
  __syncthreads();
  store_acts_pk<2, 16>(accR, sAct, o0, quad, l15);
  __syncthreads();

  // ---- rc-L3 (init = rc_b3), hi-only + rel*att + reduce over j
  {
    float bb[2][4];
#pragma unroll
    for (int t = 0; t < 2; ++t) ld4(bb[t], &sB3[o0 + 16 * t + quad * 4]);
#pragma unroll
    for (int t = 0; t < 2; ++t)
#pragma unroll
      for (int s = 0; s < 4; ++s) {
        f32x4 a;
#pragma unroll
        for (int r = 0; r < 4; ++r) a[r] = bb[t][r];
        accR[t][s] = a;
      }
  }
  run_layer1<2, 4, 16, 8>(accR, blob + RC3F, sAct, 2 * w, quad, l15);
  float ps[2][4] = {{0.f, 0.f, 0.f, 0.f}, {0.f, 0.f, 0.f, 0.f}};
#pragma unroll
  for (int t = 0; t < 2; ++t)
#pragma unroll
    for (int s = 0; s < 4; ++s)
#pragma unroll
      for (int r = 0; r < 4; ++r) {
        const float rel = fmaxf(accR[t][s][r], 0.f);
        ps[t][r] = fmaf(rel, att[t][s][r], ps[t][r]);
      }
#pragma unroll
  for (int t = 0; t < 2; ++t)
#pragma unroll
    for (int r = 0; r < 4; ++r) {
      float v = ps[t][r];
      v += __shfl_xor(v, 1, 64);
      v += __shfl_xor(v, 2, 64);
      v += __shfl_xor(v, 4, 64);
      v += __shfl_xor(v, 8, 64);
      ps[t][r] = v;
    }
  if (l15 == 0) {
#pragma unroll
    for (int t = 0; t < 2; ++t)
#pragma unroll
      for (int r = 0; r < 4; ++r)
        sRed[o0 + 16 * t + quad * 4 + r] = ps[t][r];
  }
  __syncthreads();
  if (tid < 128)
    atomicAdd(&out[b * 128 + tid], sRed[tid] * (1.0f / 4096.0f));
}

extern "C" void kernel_launch(void* const* d_in, const int* in_sizes, int n_in,
                              void* d_out, int out_size, void* d_ws, size_t ws_size,
                              hipStream_t stream) {
  const float* s     = (const float*)d_in[0];
  const float* se_w1 = (const float*)d_in[1];
  const float* se_b1 = (const float*)d_in[2];
  const float* se_w2 = (const float*)d_in[3];
  const float* se_b2 = (const float*)d_in[4];
  const float* sd_w1 = (const float*)d_in[5];
  const float* sd_b1 = (const float*)d_in[6];
  const float* sd_w2 = (const float*)d_in[7];
  const float* sd_b2 = (const float*)d_in[8];
  const float* rc_w1 = (const float*)d_in[9];
  const float* rc_b1 = (const float*)d_in[10];
  const float* rc_w2 = (const float*)d_in[11];
  const float* rc_b2 = (const float*)d_in[12];
  const float* rc_w3 = (const float*)d_in[13];
  const float* rc_b3 = (const float*)d_in[14];
  const float* an_w1 = (const float*)d_in[15];
  const float* an_b1 = (const float*)d_in[16];
  const float* an_w2 = (const float*)d_in[17];
  const float* an_b2 = (const float*)d_in[18];
  float* out = (float*)d_out;
  u16* hB   = (u16*)d_ws;
  u16* blob = hB + BLOB_U16;
  float* baseRcG = (float*)d_ws + BASE_RC_F32;
  float* baseAnG = (float*)d_ws + BASE_AN_F32;
  const int do_bases = (ws_size >= WS_NEED_BASES) ? 1 : 0;
  (void)n_in; (void)in_sizes;

  hipMemsetAsync(d_out, 0, (size_t)out_size * sizeof(float), stream);
  enc_prep_kernel<<<464, TPB, 0, stream>>>(s, se_w1, se_b1, se_w2, se_b2,
                                           sd_w1, sd_b1, sd_w2, sd_b2,
                                           rc_w1, rc_b1, rc_w2, rc_w3,
                                           an_w1, an_b1, an_w2,
                                           hB, blob, baseRcG, baseAnG, do_bases, out);
  pair_mfma_kernel<<<8192, TPB, 0, stream>>>(hB, blob, baseRcG, baseAnG, do_bases,
                                             rc_w1, rc_b1, rc_b2, rc_b3,
                                             an_w1, an_b1, an_b2, out);
}